// Round 4
// baseline (1183.275 us; speedup 1.0000x reference)
//
#include <hip/hip_runtime.h>
#include <stdint.h>

// Problem constants
#define N4   4096
#define H0   256
#define SIDE 1024
#define DIN  512
#define HCAT 768      // H0 + DIN
#define H1   128
#define NC   5
#define NUV  16777216ULL   // 4096*4096
#define CAP  1536          // max compacted entries per row

typedef __attribute__((ext_vector_type(8))) short short8;    // 8 bf16
typedef __attribute__((ext_vector_type(4))) float floatx4;

__device__ __forceinline__ unsigned short f2bf(float f) {
    unsigned int u;
    __builtin_memcpy(&u, &f, 4);
    unsigned int r = (u + 0x7FFFu + ((u >> 16) & 1u)) >> 16;   // RNE
    return (unsigned short)r;
}

__device__ __forceinline__ float bf2f(unsigned short b) {
    unsigned int u = (unsigned int)b << 16;
    float f;
    __builtin_memcpy(&f, &u, 4);
    return f;
}

// ---------------------------------------------------------------- k_counts
__global__ __launch_bounds__(256) void k_counts(const int* __restrict__ u,
                                                const int* __restrict__ v,
                                                int* __restrict__ cu,
                                                int* __restrict__ cv) {
    int i = blockIdx.x * 256 + threadIdx.x;   // 4096 threads
    atomicAdd(&cu[u[i]], 1);
    atomicAdd(&cv[v[i]], 1);
}

// ---------------------------------------------------------------- k_code
__global__ __launch_bounds__(256) void k_code(const float* __restrict__ adj,
                                              uchar4* __restrict__ code4) {
    size_t g = (size_t)blockIdx.x * 256 + threadIdx.x;
    size_t base = g * 4;
    uchar4 out = {0, 0, 0, 0};
    #pragma unroll
    for (int c = 0; c < NC; c++) {
        float4 s = *(const float4*)(adj + (size_t)c * NUV + base);
        out.x = (s.x != 0.f) ? (unsigned char)(c + 1) : out.x;
        out.y = (s.y != 0.f) ? (unsigned char)(c + 1) : out.y;
        out.z = (s.z != 0.f) ? (unsigned char)(c + 1) : out.z;
        out.w = (s.w != 0.f) ? (unsigned char)(c + 1) : out.w;
    }
    code4[g] = out;
}

// ---------------------------------------------------------------- k_transpose (byte, 64x64 tiles)
__global__ __launch_bounds__(256) void k_transpose(const uint8_t* __restrict__ src,
                                                   uint8_t* __restrict__ dst) {
    __shared__ __align__(16) uint8_t tile[64][80];
    int t = threadIdx.x;
    int row = t >> 2;
    int seg = (t & 3) * 16;
    int p0 = blockIdx.y * 64, q0 = blockIdx.x * 64;
    uint4 vdat = *(const uint4*)(src + (size_t)(p0 + row) * N4 + q0 + seg);
    *(uint4*)(&tile[row][seg]) = vdat;
    __syncthreads();
    union { uint4 u4; uint8_t b[16]; } o;
    #pragma unroll
    for (int l = 0; l < 16; l++) o.b[l] = tile[seg + l][row];
    *(uint4*)(dst + (size_t)(q0 + row) * N4 + p0 + seg) = o.u4;
}

// ---------------------------------------------------------------- k_wcumsum
// out[r][node][h] = f16( cnt[node] * cumsum_r(w)[r][node][h] )
__global__ __launch_bounds__(256) void k_wcumsum(const float* __restrict__ w,
                                                 const int* __restrict__ cnt,
                                                 unsigned short* __restrict__ out) {
    int node = blockIdx.x, h = threadIdx.x;
    float c = (float)cnt[node];
    float acc = 0.f;
    #pragma unroll
    for (int r = 0; r < NC; r++) {
        size_t idx = ((size_t)r * N4 + node) * H0 + h;
        acc += w[idx];
        union { _Float16 h16; unsigned short s; } cvt;
        cvt.h16 = (_Float16)(acc * c);
        out[idx] = cvt.s;
    }
}

// ---------------------------------------------------------------- k_compact
__global__ __launch_bounds__(256) void k_compact(const uint8_t* __restrict__ codeRows,
                                                 const int* __restrict__ cntOther,
                                                 unsigned short* __restrict__ idx,
                                                 int* __restrict__ nnz,
                                                 float* __restrict__ deg) {
    __shared__ float cw[4096];
    __shared__ int wtot[4];
    __shared__ float wdeg[4];
    __shared__ unsigned short ebuf[CAP];
    int p = blockIdx.x, t = threadIdx.x;
    int lane = t & 63, wv = t >> 6;
    const int4* co4 = (const int4*)cntOther;
    #pragma unroll
    for (int l = 0; l < 4; l++) {
        int4 ci = co4[t + l * 256];
        ((float4*)cw)[t + l * 256] =
            make_float4((float)ci.x, (float)ci.y, (float)ci.z, (float)ci.w);
    }
    uint4 w = ((const uint4*)(codeRows + (size_t)p * N4))[t];
    unsigned char b[16];
    __builtin_memcpy(b, &w, 16);
    int cnt = 0;
    #pragma unroll
    for (int j = 0; j < 16; j++) cnt += (b[j] != 0);
    int sc = cnt;
    #pragma unroll
    for (int off = 1; off < 64; off <<= 1) {
        int up = __shfl_up(sc, off, 64);
        if (lane >= off) sc += up;
    }
    if (lane == 63) wtot[wv] = sc;
    __syncthreads();            // covers cw + wtot
    int wbase = 0;
    #pragma unroll
    for (int ww = 0; ww < 4; ww++) wbase += (ww < wv) ? wtot[ww] : 0;
    int total = wtot[0] + wtot[1] + wtot[2] + wtot[3];
    int pos = wbase + sc - cnt;   // block-exclusive prefix
    float dsum = 0.f;
    #pragma unroll
    for (int j = 0; j < 16; j++) {
        int r = b[j];
        if (r) {
            int q = t * 16 + j;
            if (pos < CAP) ebuf[pos] = (unsigned short)((r - 1) * N4 + q);
            pos++;
            dsum += cw[q];
        }
    }
    #pragma unroll
    for (int off = 32; off; off >>= 1) dsum += __shfl_down(dsum, off, 64);
    if (lane == 0) wdeg[wv] = dsum;
    __syncthreads();            // covers ebuf + wdeg
    int tw = total < CAP ? total : CAP;
    if (t == 0) { deg[p] = wdeg[0] + wdeg[1] + wdeg[2] + wdeg[3]; nnz[p] = tw; }
    for (int e = t; e < tw; e += 256) idx[(size_t)p * CAP + e] = ebuf[e];
}

// ---------------------------------------------------------------- k_gather2
// v4: 16B/lane dwordx4 loads (32 lanes cover one 512B table row), 8 entry
// slots per block, inner loop unrolled x8 -> 8 independent loads in flight
// per thread (batch-issued before any consumption).
__global__ __launch_bounds__(256) void k_gather2(const unsigned short* __restrict__ idx,
                                                 const int* __restrict__ nnz,
                                                 const unsigned short* __restrict__ tbl,
                                                 float* __restrict__ outNN) {
    __shared__ unsigned short sidx[CAP];
    __shared__ float red[8][256];   // [slot][h], 8 KB
    int p = blockIdx.x, t = threadIdx.x;
    int n = nnz[p];
    const unsigned short* rowIdx = idx + (size_t)p * CAP;
    for (int i = t; i < n; i += 256) sidx[i] = rowIdx[i];
    __syncthreads();
    int s = t >> 5;        // entry slot 0..7
    int c = t & 31;        // 16B segment within row
    const char* tb = (const char*)tbl;
    float acc[8] = {0.f, 0.f, 0.f, 0.f, 0.f, 0.f, 0.f, 0.f};
    int nmain = n & ~63;
    for (int e = s; e < nmain; e += 64) {
        uint4 d[8];
        #pragma unroll
        for (int q = 0; q < 8; q++) {
            int o = ((int)sidx[e + q * 8]) << 9;
            d[q] = *(const uint4*)(tb + o + c * 16);
        }
        #pragma unroll
        for (int q = 0; q < 8; q++) {
            union { uint4 u; _Float16 h[8]; } cv;
            cv.u = d[q];
            #pragma unroll
            for (int k = 0; k < 8; k++) acc[k] += (float)cv.h[k];
        }
    }
    for (int e = nmain + s; e < n; e += 8) {
        int o = ((int)sidx[e]) << 9;
        uint4 d = *(const uint4*)(tb + o + c * 16);
        union { uint4 u; _Float16 h[8]; } cv;
        cv.u = d;
        #pragma unroll
        for (int k = 0; k < 8; k++) acc[k] += (float)cv.h[k];
    }
    #pragma unroll
    for (int k = 0; k < 8; k++) red[s][c * 8 + k] = acc[k];
    __syncthreads();
    float sum = 0.f;
    #pragma unroll
    for (int ss = 0; ss < 8; ss++) sum += red[ss][t];
    outNN[(size_t)p * H0 + t] = sum;
}

// ---------------------------------------------------------------- k_reorder
// codeR[i][j] = code[u[i]][v[j]]
__global__ __launch_bounds__(256) void k_reorder(const uint8_t* __restrict__ code,
                                                 const int* __restrict__ u,
                                                 const int* __restrict__ v,
                                                 uint8_t* __restrict__ codeR) {
    __shared__ __align__(16) uint8_t rowbuf[4096];
    int i = blockIdx.x, t = threadIdx.x;
    int urow = u[i];
    ((uint4*)rowbuf)[t] = ((const uint4*)(code + (size_t)urow * N4))[t];
    __syncthreads();
    uint8_t ob[16];
    #pragma unroll
    for (int w = 0; w < 4; w++) {
        int4 vv = ((const int4*)v)[t * 4 + w];
        ob[w * 4 + 0] = rowbuf[vv.x];
        ob[w * 4 + 1] = rowbuf[vv.y];
        ob[w * 4 + 2] = rowbuf[vv.z];
        ob[w * 4 + 3] = rowbuf[vv.w];
    }
    uint4 o;
    __builtin_memcpy(&o, ob, 16);
    ((uint4*)(codeR + (size_t)i * N4))[t] = o;
}

// ---------------------------------------------------------------- k_z (writes bf16 hi/lo cat planes)
__global__ __launch_bounds__(256) void k_z(const float* __restrict__ nn,
                                           const int* __restrict__ idxs,
                                           const int* __restrict__ idxo,
                                           const float* __restrict__ deg,
                                           unsigned short* __restrict__ catHi,
                                           unsigned short* __restrict__ catLo) {
    int i = blockIdx.x, h = threadIdx.x;
    float d = deg[idxo[i]];
    float inv = d > 0.f ? 1.f / d : 0.f;
    float val = fmaxf(nn[(size_t)idxs[i] * H0 + h] * inv, 0.f);
    unsigned short hb = f2bf(val);
    catHi[(size_t)i * HCAT + h] = hb;
    catLo[(size_t)i * HCAT + h] = f2bf(val - bf2f(hb));
}

// ---------------------------------------------------------------- k_split (fp32 -> bf16 hi + lo)
__global__ __launch_bounds__(256) void k_split(const float* __restrict__ src,
                                               unsigned short* __restrict__ hi,
                                               unsigned short* __restrict__ lo) {
    size_t g = ((size_t)blockIdx.x * 256 + threadIdx.x) * 4;
    float4 x = *(const float4*)(src + g);
    float f[4] = {x.x, x.y, x.z, x.w};
    unsigned short hh[4], ll[4];
    #pragma unroll
    for (int k = 0; k < 4; k++) {
        unsigned short hb = f2bf(f[k]);
        hh[k] = hb;
        ll[k] = f2bf(f[k] - bf2f(hb));
    }
    *(ushort4*)(hi + g) = make_ushort4(hh[0], hh[1], hh[2], hh[3]);
    *(ushort4*)(lo + g) = make_ushort4(ll[0], ll[1], ll[2], ll[3]);
}

// ---------------------------------------------------------------- k_l1gemm (MFMA bf16 split GEMM, layer 1)
// cat[i][H0+n] = relu( sum_k A[rowmap[i]][k]*B[n][k] + bias[n] ), K=1024.
// Product = Ah*Bh + Ah*Bl + Al*Bh (~fp32). Output written as bf16 hi/lo.
// Fragment mapping (m89-verified): A row / B col = lane&15 on load;
// D row = (lane>>4)*4 + reg, D col = lane&15.
__global__ __launch_bounds__(256) void k_l1gemm(const unsigned short* __restrict__ Ahi,
                                                const unsigned short* __restrict__ Alo,
                                                const int* __restrict__ rowmap,
                                                const unsigned short* __restrict__ Bhi,
                                                const unsigned short* __restrict__ Blo,
                                                const float* __restrict__ bias,
                                                unsigned short* __restrict__ CHi,
                                                unsigned short* __restrict__ CLo) {
    int t = threadIdx.x;
    int wave = t >> 6, lane = t & 63;
    int lr = lane & 15;
    int lk = lane >> 4;
    int i0 = blockIdx.y * 64 + wave * 16;
    int n0 = blockIdx.x * 64;
    int gi = rowmap[i0 + lr];
    const unsigned short* pah = Ahi + (size_t)gi * SIDE + lk * 8;
    const unsigned short* pal = Alo + (size_t)gi * SIDE + lk * 8;
    floatx4 acc[4];
    #pragma unroll
    for (int jt = 0; jt < 4; jt++) acc[jt] = (floatx4){0.f, 0.f, 0.f, 0.f};
    for (int kc = 0; kc < SIDE / 32; kc++) {
        short8 ah = *(const short8*)(pah + kc * 32);
        short8 al = *(const short8*)(pal + kc * 32);
        #pragma unroll
        for (int jt = 0; jt < 4; jt++) {
            int bc = n0 + jt * 16 + lr;
            short8 bh = *(const short8*)(Bhi + (size_t)bc * SIDE + kc * 32 + lk * 8);
            short8 bl = *(const short8*)(Blo + (size_t)bc * SIDE + kc * 32 + lk * 8);
            acc[jt] = __builtin_amdgcn_mfma_f32_16x16x32_bf16(ah, bh, acc[jt], 0, 0, 0);
            acc[jt] = __builtin_amdgcn_mfma_f32_16x16x32_bf16(ah, bl, acc[jt], 0, 0, 0);
            acc[jt] = __builtin_amdgcn_mfma_f32_16x16x32_bf16(al, bh, acc[jt], 0, 0, 0);
        }
    }
    #pragma unroll
    for (int jt = 0; jt < 4; jt++) {
        int cn = n0 + jt * 16 + lr;
        float b = bias[cn];
        #pragma unroll
        for (int r = 0; r < 4; r++) {
            int ci = i0 + lk * 4 + r;
            float vv = fmaxf(acc[jt][r] + b, 0.f);
            unsigned short hb = f2bf(vv);
            CHi[(size_t)ci * HCAT + cn] = hb;
            CLo[(size_t)ci * HCAT + cn] = f2bf(vv - bf2f(hb));
        }
    }
}

// ---------------------------------------------------------------- k_l2gemm (MFMA bf16 split GEMM, layer 2)
// C[i][n] = relu( sum_k cat[i][k]*W2[n][k] ), K=768, N=128.
template <bool BF16OUT>
__global__ __launch_bounds__(256) void k_l2gemm(const unsigned short* __restrict__ Ahi,
                                                const unsigned short* __restrict__ Alo,
                                                const unsigned short* __restrict__ Bhi,
                                                const unsigned short* __restrict__ Blo,
                                                void* __restrict__ Cout) {
    int t = threadIdx.x;
    int wave = t >> 6, lane = t & 63;
    int lr = lane & 15;
    int lk = lane >> 4;
    int i0 = blockIdx.y * 64 + wave * 16;
    int n0 = blockIdx.x * 64;
    const unsigned short* pah = Ahi + (size_t)(i0 + lr) * HCAT + lk * 8;
    const unsigned short* pal = Alo + (size_t)(i0 + lr) * HCAT + lk * 8;
    floatx4 acc[4];
    #pragma unroll
    for (int jt = 0; jt < 4; jt++) acc[jt] = (floatx4){0.f, 0.f, 0.f, 0.f};
    for (int kc = 0; kc < HCAT / 32; kc++) {
        short8 ah = *(const short8*)(pah + kc * 32);
        short8 al = *(const short8*)(pal + kc * 32);
        #pragma unroll
        for (int jt = 0; jt < 4; jt++) {
            int bc = n0 + jt * 16 + lr;
            short8 bh = *(const short8*)(Bhi + (size_t)bc * HCAT + kc * 32 + lk * 8);
            short8 bl = *(const short8*)(Blo + (size_t)bc * HCAT + kc * 32 + lk * 8);
            acc[jt] = __builtin_amdgcn_mfma_f32_16x16x32_bf16(ah, bh, acc[jt], 0, 0, 0);
            acc[jt] = __builtin_amdgcn_mfma_f32_16x16x32_bf16(ah, bl, acc[jt], 0, 0, 0);
            acc[jt] = __builtin_amdgcn_mfma_f32_16x16x32_bf16(al, bh, acc[jt], 0, 0, 0);
        }
    }
    #pragma unroll
    for (int jt = 0; jt < 4; jt++) {
        int cn = n0 + jt * 16 + lr;
        #pragma unroll
        for (int r = 0; r < 4; r++) {
            int ci = i0 + lk * 4 + r;
            float vv = fmaxf(acc[jt][r], 0.f);
            if (BF16OUT) {
                ((unsigned short*)Cout)[(size_t)ci * H1 + cn] = f2bf(vv);
            } else {
                ((float*)Cout)[(size_t)ci * H1 + cn] = vv;
            }
        }
    }
}

// ---------------------------------------------------------------- generic NT GEMM (fp32 in, fp32 or bf16 out)
template <int TM, int TN, int BK, int RM, int RN, bool GATHER, bool BIAS, bool RELU, bool BF16OUT>
__global__ __launch_bounds__(256) void k_gemm(const float* __restrict__ A, int lda,
                                              const int* __restrict__ rowmap,
                                              const float* __restrict__ B, int ldb,
                                              const float* __restrict__ bias,
                                              float* __restrict__ C, int ldc, int K,
                                              size_t bzs, size_t czs) {
    constexpr int TX = TN / RN;
    constexpr int TY = TM / RM;
    static_assert(TX * TY == 256, "block must be 256");
    __shared__ float As[BK][TM + 4];
    __shared__ float Bs[BK][TN + 4];
    int tid = threadIdx.x;
    int tx = tid % TX, ty = tid / TX;
    int i0 = blockIdx.x * TM, n0 = blockIdx.y * TN;
    const float* Bz = B + (size_t)blockIdx.z * bzs;
    float acc[RM][RN] = {};
    for (int k0 = 0; k0 < K; k0 += BK) {
        for (int g = tid; g < TM * BK / 4; g += 256) {
            int i = g / (BK / 4), kc = g % (BK / 4);
            int row = GATHER ? rowmap[i0 + i] : (i0 + i);
            float4 val = *(const float4*)(A + (size_t)row * lda + k0 + kc * 4);
            As[kc * 4 + 0][i] = val.x; As[kc * 4 + 1][i] = val.y;
            As[kc * 4 + 2][i] = val.z; As[kc * 4 + 3][i] = val.w;
        }
        for (int g = tid; g < TN * BK / 4; g += 256) {
            int n = g / (BK / 4), kc = g % (BK / 4);
            float4 val = *(const float4*)(Bz + (size_t)(n0 + n) * ldb + k0 + kc * 4);
            Bs[kc * 4 + 0][n] = val.x; Bs[kc * 4 + 1][n] = val.y;
            Bs[kc * 4 + 2][n] = val.z; Bs[kc * 4 + 3][n] = val.w;
        }
        __syncthreads();
        #pragma unroll
        for (int k = 0; k < BK; k++) {
            float av[RM], bv[RN];
            #pragma unroll
            for (int m = 0; m < RM; m++) av[m] = As[k][ty * RM + m];
            #pragma unroll
            for (int n = 0; n < RN; n++) bv[n] = Bs[k][tx * RN + n];
            #pragma unroll
            for (int m = 0; m < RM; m++)
                #pragma unroll
                for (int n = 0; n < RN; n++)
                    acc[m][n] = fmaf(av[m], bv[n], acc[m][n]);
        }
        __syncthreads();
    }
    #pragma unroll
    for (int m = 0; m < RM; m++) {
        int ig = i0 + ty * RM + m;
        #pragma unroll
        for (int n = 0; n < RN; n++) {
            float vv = acc[m][n];
            if (BIAS) vv += bias[n0 + tx * RN + n];
            if (RELU) vv = fmaxf(vv, 0.f);
            if (BF16OUT) {
                unsigned short* Cz16 = (unsigned short*)C + (size_t)blockIdx.z * czs;
                Cz16[(size_t)ig * ldc + n0 + tx * RN + n] = f2bf(vv);
            } else {
                float* Cz = C + (size_t)blockIdx.z * czs;
                Cz[(size_t)ig * ldc + n0 + tx * RN + n] = vv;
            }
        }
    }
}

// ---------------------------------------------------------------- k_Pt : Pt[b][e][d] = P[b][d][e]
__global__ __launch_bounds__(256) void k_Pt(const float* __restrict__ P, float* __restrict__ Pt) {
    int tid = blockIdx.x * 256 + threadIdx.x;   // 32768
    int b = tid >> 14;
    int d = (tid >> 7) & 127;
    int e = tid & 127;
    Pt[((size_t)b * 128 + e) * 128 + d] = P[tid];
}

// ---------------------------------------------------------------- k_scores3 (MFMA bf16 decoder + softmax epilogue)
__global__ __launch_bounds__(256) void k_scores3(const unsigned short* __restrict__ tb,  // [2][4096][128] bf16
                                                 const unsigned short* __restrict__ vhb, // [4096][128] bf16
                                                 const uint8_t* __restrict__ codeR,
                                                 const float* __restrict__ a_f,          // [2][5]
                                                 float* __restrict__ mhat,
                                                 float* __restrict__ part) {
    __shared__ float wred[4][3];
    int t = threadIdx.x;
    int wave = t >> 6, lane = t & 63;
    int lr = lane & 15;          // A row / B col / C col
    int lk = lane >> 4;          // k-subgroup & C row-group
    int i0 = blockIdx.y * 64 + wave * 16;
    int j0 = blockIdx.x * 128;
    float sa0[NC], sa1[NC];
    #pragma unroll
    for (int c = 0; c < NC; c++) { sa0[c] = a_f[c]; sa1[c] = a_f[5 + c]; }

    const unsigned short* t0p = tb;
    const unsigned short* t1p = tb + (size_t)N4 * H1;
    short8 a0[4], a1[4];
    #pragma unroll
    for (int kc = 0; kc < 4; kc++) {
        size_t off = (size_t)(i0 + lr) * H1 + kc * 32 + lk * 8;
        a0[kc] = *(const short8*)(t0p + off);
        a1[kc] = *(const short8*)(t1p + off);
    }

    float lsum = 0.f, ssum = 0.f, nobs = 0.f;
    for (int jt = 0; jt < 8; jt++) {
        int jb = j0 + jt * 16;
        int j = jb + lr;
        // hoist codeR loads above the MFMAs so HBM latency overlaps compute
        const uint8_t* crp = codeR + (size_t)(i0 + lk * 4) * N4 + j;
        int cbv[4];
        cbv[0] = crp[0];
        cbv[1] = crp[N4];
        cbv[2] = crp[2 * N4];
        cbv[3] = crp[3 * N4];
        floatx4 C0 = {0.f, 0.f, 0.f, 0.f}, C1 = {0.f, 0.f, 0.f, 0.f};
        #pragma unroll
        for (int kc = 0; kc < 4; kc++) {
            short8 b = *(const short8*)(vhb + (size_t)(jb + lr) * H1 + kc * 32 + lk * 8);
            C0 = __builtin_amdgcn_mfma_f32_16x16x32_bf16(a0[kc], b, C0, 0, 0, 0);
            C1 = __builtin_amdgcn_mfma_f32_16x16x32_bf16(a1[kc], b, C1, 0, 0, 0);
        }
        #pragma unroll
        for (int r = 0; r < 4; r++) {
            int i = i0 + lk * 4 + r;
            float v0 = C0[r], v1 = C1[r];
            float l[NC];
            float mx = -1e30f;
            #pragma unroll
            for (int c = 0; c < NC; c++) {
                l[c] = sa0[c] * v0 + sa1[c] * v1;
                mx = fmaxf(mx, l[c]);
            }
            float den = 0.f, num = 0.f;
            #pragma unroll
            for (int c = 0; c < NC; c++) {
                float e = __expf(l[c] - mx);
                den += e;
                num += (float)(c + 1) * e;
            }
            float mh = num / den;
            mhat[(size_t)i * N4 + j] = mh;
            int cb = cbv[r];
            if (cb) {
                float lse = mx + __logf(den);
                lsum += lse - l[cb - 1];        // = -logp[cb-1]
                float df = mh - (float)cb;
                ssum += df * df;
                nobs += 1.f;
            }
        }
    }
    #pragma unroll
    for (int off = 32; off; off >>= 1) {
        lsum += __shfl_down(lsum, off, 64);
        ssum += __shfl_down(ssum, off, 64);
        nobs += __shfl_down(nobs, off, 64);
    }
    if (lane == 0) { wred[wave][0] = lsum; wred[wave][1] = ssum; wred[wave][2] = nobs; }
    __syncthreads();
    if (t == 0) {
        int bid = blockIdx.y * gridDim.x + blockIdx.x;
        part[bid * 3 + 0] = wred[0][0] + wred[1][0] + wred[2][0] + wred[3][0];
        part[bid * 3 + 1] = wred[0][1] + wred[1][1] + wred[2][1] + wred[3][1];
        part[bid * 3 + 2] = wred[0][2] + wred[1][2] + wred[2][2] + wred[3][2];
    }
}

// ---------------------------------------------------------------- k_finalize (reduce 2048 block partials)
__global__ __launch_bounds__(256) void k_finalize(const float* __restrict__ part,
                                                  float* __restrict__ out) {
    __shared__ float sred[3][4];
    int t = threadIdx.x, lane = t & 63, wv = t >> 6;
    float l = 0.f, s = 0.f, n = 0.f;
    for (int i = t; i < 2048; i += 256) {
        l += part[i * 3 + 0];
        s += part[i * 3 + 1];
        n += part[i * 3 + 2];
    }
    #pragma unroll
    for (int off = 32; off; off >>= 1) {
        l += __shfl_down(l, off, 64);
        s += __shfl_down(s, off, 64);
        n += __shfl_down(n, off, 64);
    }
    if (lane == 0) { sred[0][wv] = l; sred[1][wv] = s; sred[2][wv] = n; }
    __syncthreads();
    if (t == 0) {
        float L = sred[0][0] + sred[0][1] + sred[0][2] + sred[0][3];
        float S = sred[1][0] + sred[1][1] + sred[1][2] + sred[1][3];
        float N = fmaxf(sred[2][0] + sred[2][1] + sred[2][2] + sred[2][3], 1.f);
        out[NUV + 0] = L / N;
        out[NUV + 1] = sqrtf(S / N);
    }
}

// ================================================================ launch
extern "C" void kernel_launch(void* const* d_in, const int* in_sizes, int n_in,
                              void* d_out, int out_size, void* d_ws, size_t ws_size,
                              hipStream_t stream) {
    const int* u = (const int*)d_in[0];
    const int* v = (const int*)d_in[1];
    const float* adj    = (const float*)d_in[3];
    const float* u_feat = (const float*)d_in[4];
    const float* v_feat = (const float*)d_in[5];
    const float* u_w    = (const float*)d_in[6];
    const float* v_w    = (const float*)d_in[7];
    const float* Wu1    = (const float*)d_in[8];
    const float* bu1    = (const float*)d_in[9];
    const float* Wv1    = (const float*)d_in[10];
    const float* bv1    = (const float*)d_in[11];
    const float* Wu2    = (const float*)d_in[12];
    const float* Wv2    = (const float*)d_in[13];
    const float* P      = (const float*)d_in[14];
    const float* a      = (const float*)d_in[15];
    float* out = (float*)d_out;

    char* ws = (char*)d_ws;
    // workspace layout (bytes); total ~100 MB.
    // Overlays: codeT on UCAT (dead after k_compact);
    //           codeR on TAU+TBV (dead after k_gather2);
    //           part on CNTU+CNTV (dead after k_compact);
    //           feature hi/lo splits: FUHI on IDXU, FULO on IDXV (dead after
    //             k_gather2), FVHI/FVLO on CODE (dead after k_reorder);
    //           W1 hi/lo on UNN/VNN (dead after k_z);
    //           W2 hi/lo on UNN (dead after k_l1gemm, which consumed W1 splits);
    //           cat bf16 hi/lo planes on UCAT/VCAT (2 x 6,291,456 each).
    const size_t O_CODE  = 0;                         // 16,777,216 u8
    const size_t O_CNTU  = 16777216;                  // 16,384 i32
    const size_t O_CNTV  = O_CNTU + 16384;            // 16,384 i32
    const size_t O_ACC   = O_CNTV + 16384;            // 256 B (unused)
    const size_t O_TAU   = O_ACC + 256;               // 10,485,760 f16 table (u side)
    const size_t O_TBV   = O_TAU + 10485760;          // 10,485,760 f16 table (v side)
    const size_t O_IDXU  = O_TBV + 10485760;          // 12,582,912 u16 [4096][CAP]
    const size_t O_IDXV  = O_IDXU + 12582912;         // 12,582,912 u16
    const size_t O_NNZU  = O_IDXV + 12582912;         // 16,384 i32
    const size_t O_NNZV  = O_NNZU + 16384;            // 16,384 i32
    const size_t O_RDEG  = O_NNZV + 16384;            // 16,384 f32
    const size_t O_CDEG  = O_RDEG + 16384;            // 16,384 f32
    const size_t O_UNN   = O_CDEG + 16384;            // 4,194,304 f32
    const size_t O_VNN   = O_UNN + 4194304;           // 4,194,304 f32
    const size_t O_UCAT  = O_VNN + 4194304;           // 12,582,912 (now bf16 hi+lo planes)
    const size_t O_VCAT  = O_UCAT + 12582912;         // 12,582,912
    const size_t O_UH    = O_VCAT + 12582912;         // 2,097,152 f32
    const size_t O_VHB   = O_UH + 2097152;            // 1,048,576 bf16 [4096][128]
    const size_t O_PT    = O_VHB + 1048576;           // 131,072 f32
    const size_t O_TB    = O_PT + 131072;             // 2,097,152 bf16 [2][4096][128]
    const size_t O_CODET = O_UCAT;                    // overlay
    const size_t O_CODER = O_TAU;                     // overlay (fits TAU+TBV)
    const size_t O_PART  = O_CNTU;                    // overlay (cnt dead after compact)
    const size_t O_FUHI  = O_IDXU;                    // overlay, 8,388,608 bf16hi
    const size_t O_FULO  = O_IDXV;                    // overlay, 8,388,608 bf16lo
    const size_t O_FVHI  = O_CODE;                    // overlay, 8,388,608
    const size_t O_FVLO  = O_CODE + 8388608;          // overlay, 8,388,608
    const size_t O_WUHI  = O_UNN;                     // overlay, 1,048,576
    const size_t O_WULO  = O_UNN + 1048576;           // overlay, 1,048,576
    const size_t O_WVHI  = O_VNN;                     // overlay, 1,048,576
    const size_t O_WVLO  = O_VNN + 1048576;           // overlay, 1,048,576
    const size_t O_CHIU  = O_UCAT;                    // [4096][768] u16 hi
    const size_t O_CLOU  = O_UCAT + 6291456;          // [4096][768] u16 lo
    const size_t O_CHIV  = O_VCAT;
    const size_t O_CLOV  = O_VCAT + 6291456;
    const size_t O_W2UHI = O_UNN;                     // overlay (W1 splits dead), 196,608 each
    const size_t O_W2ULO = O_UNN + 196608;
    const size_t O_W2VHI = O_UNN + 393216;
    const size_t O_W2VLO = O_UNN + 589824;

    uint8_t* code  = (uint8_t*)(ws + O_CODE);
    uint8_t* codeT = (uint8_t*)(ws + O_CODET);
    uint8_t* codeR = (uint8_t*)(ws + O_CODER);
    int* cnt_u = (int*)(ws + O_CNTU);
    int* cnt_v = (int*)(ws + O_CNTV);
    unsigned short* T_Au = (unsigned short*)(ws + O_TAU);
    unsigned short* T_Bv = (unsigned short*)(ws + O_TBV);
    unsigned short* idxU = (unsigned short*)(ws + O_IDXU);
    unsigned short* idxV = (unsigned short*)(ws + O_IDXV);
    int* nnzU = (int*)(ws + O_NNZU);
    int* nnzV = (int*)(ws + O_NNZV);
    float* rowDeg = (float*)(ws + O_RDEG);
    float* colDeg = (float*)(ws + O_CDEG);
    float* u_nn = (float*)(ws + O_UNN);
    float* v_nn = (float*)(ws + O_VNN);
    float* uh = (float*)(ws + O_UH);
    unsigned short* vhb = (unsigned short*)(ws + O_VHB);
    float* Pt = (float*)(ws + O_PT);
    unsigned short* tb = (unsigned short*)(ws + O_TB);
    float* part = (float*)(ws + O_PART);
    unsigned short* fuhi = (unsigned short*)(ws + O_FUHI);
    unsigned short* fulo = (unsigned short*)(ws + O_FULO);
    unsigned short* fvhi = (unsigned short*)(ws + O_FVHI);
    unsigned short* fvlo = (unsigned short*)(ws + O_FVLO);
    unsigned short* wuhi = (unsigned short*)(ws + O_WUHI);
    unsigned short* wulo = (unsigned short*)(ws + O_WULO);
    unsigned short* wvhi = (unsigned short*)(ws + O_WVHI);
    unsigned short* wvlo = (unsigned short*)(ws + O_WVLO);
    unsigned short* chiU = (unsigned short*)(ws + O_CHIU);
    unsigned short* cloU = (unsigned short*)(ws + O_CLOU);
    unsigned short* chiV = (unsigned short*)(ws + O_CHIV);
    unsigned short* cloV = (unsigned short*)(ws + O_CLOV);
    unsigned short* w2uhi = (unsigned short*)(ws + O_W2UHI);
    unsigned short* w2ulo = (unsigned short*)(ws + O_W2ULO);
    unsigned short* w2vhi = (unsigned short*)(ws + O_W2VHI);
    unsigned short* w2vlo = (unsigned short*)(ws + O_W2VLO);

    hipMemsetAsync(ws + O_CNTU, 0, 16384 + 16384, stream);

    k_counts<<<16, 256, 0, stream>>>(u, v, cnt_u, cnt_v);
    k_code<<<16384, 256, 0, stream>>>(adj, (uchar4*)code);
    k_transpose<<<dim3(64, 64), 256, 0, stream>>>(code, codeT);
    k_wcumsum<<<N4, 256, 0, stream>>>(u_w, cnt_u, T_Au);
    k_wcumsum<<<N4, 256, 0, stream>>>(v_w, cnt_v, T_Bv);
    k_compact<<<N4, 256, 0, stream>>>(code, cnt_v, idxU, nnzU, rowDeg);
    k_compact<<<N4, 256, 0, stream>>>(codeT, cnt_u, idxV, nnzV, colDeg);
    k_gather2<<<N4, 256, 0, stream>>>(idxU, nnzU, T_Bv, u_nn);
    k_gather2<<<N4, 256, 0, stream>>>(idxV, nnzV, T_Au, v_nn);
    // tables now dead -> build codeR over them
    k_reorder<<<N4, 256, 0, stream>>>(code, u, v, codeR);
    k_z<<<N4, 256, 0, stream>>>(u_nn, u, v, colDeg, chiU, cloU);
    k_z<<<N4, 256, 0, stream>>>(v_nn, v, u, rowDeg, chiV, cloV);
    // split fp32 -> bf16 hi/lo (overlay regions now dead)
    k_split<<<4096, 256, 0, stream>>>(u_feat, fuhi, fulo);        // 4096*1024
    k_split<<<4096, 256, 0, stream>>>(v_feat, fvhi, fvlo);
    k_split<<<512, 256, 0, stream>>>(Wu1, wuhi, wulo);            // 512*1024
    k_split<<<512, 256, 0, stream>>>(Wv1, wvhi, wvlo);
    // u_f = relu(u_features[u] @ Wu1^T + bu1) -> cat cols 256..767 via MFMA
    k_l1gemm<<<dim3(8, 64), 256, 0, stream>>>(fuhi, fulo, u, wuhi, wulo, bu1,
                                              chiU + H0, cloU + H0);
    k_l1gemm<<<dim3(8, 64), 256, 0, stream>>>(fvhi, fvlo, v, wvhi, wvlo, bv1,
                                              chiV + H0, cloV + H0);
    // W2 splits (W1 splits now dead)
    k_split<<<96, 256, 0, stream>>>(Wu2, w2uhi, w2ulo);           // 128*768
    k_split<<<96, 256, 0, stream>>>(Wv2, w2vhi, w2vlo);
    // u_h = relu(cat_u @ Wu2^T) -> fp32 ; v_h -> bf16
    k_l2gemm<false><<<dim3(2, 64), 256, 0, stream>>>(chiU, cloU, w2uhi, w2ulo, uh);
    k_l2gemm<true><<<dim3(2, 64), 256, 0, stream>>>(chiV, cloV, w2vhi, w2vlo, vhb);
    k_Pt<<<128, 256, 0, stream>>>(P, Pt);
    // t[b] = uh @ P[b] -> bf16 directly
    k_gemm<64, 32, 16, 4, 2, false, false, false, true>
        <<<dim3(64, 4, 2), 256, 0, stream>>>(uh, H1, nullptr, Pt, H1, nullptr,
                                             (float*)tb, H1, H1,
                                             (size_t)H1 * H1, (size_t)N4 * H1);
    k_scores3<<<dim3(32, 64), 256, 0, stream>>>(tb, vhb, codeR, a, out, part);
    k_finalize<<<1, 256, 0, stream>>>(part, out);
}

// Round 5
// 1012.053 us; speedup vs baseline: 1.1692x; 1.1692x over previous
//
#include <hip/hip_runtime.h>
#include <stdint.h>

// Problem constants
#define N4   4096
#define H0   256
#define SIDE 1024
#define DIN  512
#define HCAT 768      // H0 + DIN
#define H1   128
#define NC   5
#define NUV  16777216ULL   // 4096*4096
#define CAP  1536          // max compacted entries per row

typedef __attribute__((ext_vector_type(8))) short short8;    // 8 bf16
typedef __attribute__((ext_vector_type(4))) float floatx4;

__device__ __forceinline__ unsigned short f2bf(float f) {
    unsigned int u;
    __builtin_memcpy(&u, &f, 4);
    unsigned int r = (u + 0x7FFFu + ((u >> 16) & 1u)) >> 16;   // RNE
    return (unsigned short)r;
}

__device__ __forceinline__ float bf2f(unsigned short b) {
    unsigned int u = (unsigned int)b << 16;
    float f;
    __builtin_memcpy(&f, &u, 4);
    return f;
}

// ---------------------------------------------------------------- k_counts
__global__ __launch_bounds__(256) void k_counts(const int* __restrict__ u,
                                                const int* __restrict__ v,
                                                int* __restrict__ cu,
                                                int* __restrict__ cv) {
    int i = blockIdx.x * 256 + threadIdx.x;   // 4096 threads
    atomicAdd(&cu[u[i]], 1);
    atomicAdd(&cv[v[i]], 1);
}

// ---------------------------------------------------------------- k_code
__global__ __launch_bounds__(256) void k_code(const float* __restrict__ adj,
                                              uchar4* __restrict__ code4) {
    size_t g = (size_t)blockIdx.x * 256 + threadIdx.x;
    size_t base = g * 4;
    uchar4 out = {0, 0, 0, 0};
    #pragma unroll
    for (int c = 0; c < NC; c++) {
        float4 s = *(const float4*)(adj + (size_t)c * NUV + base);
        out.x = (s.x != 0.f) ? (unsigned char)(c + 1) : out.x;
        out.y = (s.y != 0.f) ? (unsigned char)(c + 1) : out.y;
        out.z = (s.z != 0.f) ? (unsigned char)(c + 1) : out.z;
        out.w = (s.w != 0.f) ? (unsigned char)(c + 1) : out.w;
    }
    code4[g] = out;
}

// ---------------------------------------------------------------- k_fuse0: transpose + wcumsum x2
// blocks [0,4096): byte transpose 64x64 tile; [4096,12288): wcumsum (side by range)
__global__ __launch_bounds__(256) void k_fuse0(const uint8_t* __restrict__ code,
                                               uint8_t* __restrict__ codeT,
                                               const float* __restrict__ u_w,
                                               const int* __restrict__ cnt_u,
                                               unsigned short* __restrict__ T_Au,
                                               const float* __restrict__ v_w,
                                               const int* __restrict__ cnt_v,
                                               unsigned short* __restrict__ T_Bv) {
    __shared__ __align__(16) uint8_t tile[64][80];
    int b = blockIdx.x, t = threadIdx.x;
    if (b < 4096) {
        int bx = b & 63, by = b >> 6;
        int row = t >> 2;
        int seg = (t & 3) * 16;
        int p0 = by * 64, q0 = bx * 64;
        uint4 vdat = *(const uint4*)(code + (size_t)(p0 + row) * N4 + q0 + seg);
        *(uint4*)(&tile[row][seg]) = vdat;
        __syncthreads();
        union { uint4 u4; uint8_t bb[16]; } o;
        #pragma unroll
        for (int l = 0; l < 16; l++) o.bb[l] = tile[seg + l][row];
        *(uint4*)(codeT + (size_t)(q0 + row) * N4 + p0 + seg) = o.u4;
    } else {
        int node = (b - 4096) & 4095;
        int side = (b - 4096) >> 12;       // 0: u-table, 1: v-table
        const float* w = side ? v_w : u_w;
        const int* cnt = side ? cnt_v : cnt_u;
        unsigned short* out = side ? T_Bv : T_Au;
        int h = t;
        float c = (float)cnt[node];
        float acc = 0.f;
        #pragma unroll
        for (int r = 0; r < NC; r++) {
            size_t idx = ((size_t)r * N4 + node) * H0 + h;
            acc += w[idx];
            union { _Float16 h16; unsigned short s; } cvt;
            cvt.h16 = (_Float16)(acc * c);
            out[idx] = cvt.s;
        }
    }
}

// ---------------------------------------------------------------- k_compactF (both sides; y = side)
__global__ __launch_bounds__(256) void k_compactF(const uint8_t* __restrict__ code,
                                                  const uint8_t* __restrict__ codeT,
                                                  const int* __restrict__ cnt_u,
                                                  const int* __restrict__ cnt_v,
                                                  unsigned short* __restrict__ idxU,
                                                  int* __restrict__ nnzU,
                                                  float* __restrict__ rowDeg,
                                                  unsigned short* __restrict__ idxV,
                                                  int* __restrict__ nnzV,
                                                  float* __restrict__ colDeg) {
    __shared__ float cw[4096];
    __shared__ int wtot[4];
    __shared__ float wdeg[4];
    __shared__ unsigned short ebuf[CAP];
    int side = blockIdx.y;
    const uint8_t* codeRows = side ? codeT : code;
    const int* cntOther = side ? cnt_u : cnt_v;
    unsigned short* idx = side ? idxV : idxU;
    int* nnz = side ? nnzV : nnzU;
    float* deg = side ? colDeg : rowDeg;

    int p = blockIdx.x, t = threadIdx.x;
    int lane = t & 63, wv = t >> 6;
    const int4* co4 = (const int4*)cntOther;
    #pragma unroll
    for (int l = 0; l < 4; l++) {
        int4 ci = co4[t + l * 256];
        ((float4*)cw)[t + l * 256] =
            make_float4((float)ci.x, (float)ci.y, (float)ci.z, (float)ci.w);
    }
    uint4 w = ((const uint4*)(codeRows + (size_t)p * N4))[t];
    unsigned char b[16];
    __builtin_memcpy(b, &w, 16);
    int cnt = 0;
    #pragma unroll
    for (int j = 0; j < 16; j++) cnt += (b[j] != 0);
    int sc = cnt;
    #pragma unroll
    for (int off = 1; off < 64; off <<= 1) {
        int up = __shfl_up(sc, off, 64);
        if (lane >= off) sc += up;
    }
    if (lane == 63) wtot[wv] = sc;
    __syncthreads();            // covers cw + wtot
    int wbase = 0;
    #pragma unroll
    for (int ww = 0; ww < 4; ww++) wbase += (ww < wv) ? wtot[ww] : 0;
    int total = wtot[0] + wtot[1] + wtot[2] + wtot[3];
    int pos = wbase + sc - cnt;   // block-exclusive prefix
    float dsum = 0.f;
    #pragma unroll
    for (int j = 0; j < 16; j++) {
        int r = b[j];
        if (r) {
            int q = t * 16 + j;
            if (pos < CAP) ebuf[pos] = (unsigned short)((r - 1) * N4 + q);
            pos++;
            dsum += cw[q];
        }
    }
    #pragma unroll
    for (int off = 32; off; off >>= 1) dsum += __shfl_down(dsum, off, 64);
    if (lane == 0) wdeg[wv] = dsum;
    __syncthreads();            // covers ebuf + wdeg
    int tw = total < CAP ? total : CAP;
    if (t == 0) { deg[p] = wdeg[0] + wdeg[1] + wdeg[2] + wdeg[3]; nnz[p] = tw; }
    for (int e = t; e < tw; e += 256) idx[(size_t)p * CAP + e] = ebuf[e];
}

// ---------------------------------------------------------------- k_gatherF
// v5: both sides fused (z = side), 2 blocks per row (y = half: 256B of the
// 512B table row each), 16 entry slots x 16 segments, x4-deep MLP (the
// empirically best inner loop from R2).
__global__ __launch_bounds__(256) void k_gatherF(const unsigned short* __restrict__ idxU,
                                                 const int* __restrict__ nnzU,
                                                 const unsigned short* __restrict__ T_Bv,
                                                 float* __restrict__ u_nn,
                                                 const unsigned short* __restrict__ idxV,
                                                 const int* __restrict__ nnzV,
                                                 const unsigned short* __restrict__ T_Au,
                                                 float* __restrict__ v_nn) {
    __shared__ unsigned short sidx[CAP];
    __shared__ float red[16][132];
    int side = blockIdx.z;
    const unsigned short* idx = side ? idxV : idxU;
    const int* nnz = side ? nnzV : nnzU;
    const char* tb = (const char*)(side ? T_Au : T_Bv);
    float* outNN = side ? v_nn : u_nn;

    int p = blockIdx.x, half = blockIdx.y, t = threadIdx.x;
    int n = nnz[p];
    const unsigned short* rowIdx = idx + (size_t)p * CAP;
    for (int i = t; i < n; i += 256) sidx[i] = rowIdx[i];
    __syncthreads();
    int s = t >> 4;        // entry slot 0..15
    int c = t & 15;        // 16B segment within half-row
    int boff = half * 256 + c * 16;
    float acc[8] = {0.f, 0.f, 0.f, 0.f, 0.f, 0.f, 0.f, 0.f};
    int nmain = n & ~63;
    for (int e = s; e < nmain; e += 64) {
        int o0 = ((int)sidx[e])      << 9;
        int o1 = ((int)sidx[e + 16]) << 9;
        int o2 = ((int)sidx[e + 32]) << 9;
        int o3 = ((int)sidx[e + 48]) << 9;
        uint4 d0 = *(const uint4*)(tb + o0 + boff);
        uint4 d1 = *(const uint4*)(tb + o1 + boff);
        uint4 d2 = *(const uint4*)(tb + o2 + boff);
        uint4 d3 = *(const uint4*)(tb + o3 + boff);
        union { uint4 u; _Float16 h[8]; } cv;
        cv.u = d0;
        #pragma unroll
        for (int k = 0; k < 8; k++) acc[k] += (float)cv.h[k];
        cv.u = d1;
        #pragma unroll
        for (int k = 0; k < 8; k++) acc[k] += (float)cv.h[k];
        cv.u = d2;
        #pragma unroll
        for (int k = 0; k < 8; k++) acc[k] += (float)cv.h[k];
        cv.u = d3;
        #pragma unroll
        for (int k = 0; k < 8; k++) acc[k] += (float)cv.h[k];
    }
    for (int e = nmain + s; e < n; e += 16) {
        int o = ((int)sidx[e]) << 9;
        uint4 d = *(const uint4*)(tb + o + boff);
        union { uint4 u; _Float16 h[8]; } cv;
        cv.u = d;
        #pragma unroll
        for (int k = 0; k < 8; k++) acc[k] += (float)cv.h[k];
    }
    #pragma unroll
    for (int k = 0; k < 8; k++) red[s][c * 8 + k] = acc[k];
    __syncthreads();
    if (t < 128) {
        float sum = 0.f;
        #pragma unroll
        for (int ss = 0; ss < 16; ss++) sum += red[ss][t];
        outNN[(size_t)p * H0 + half * 128 + t] = sum;
    }
}

// ---------------------------------------------------------------- k_fuse1: reorder + z x2 + split(u_feat)
// blocks [0,4096): reorder; [4096,8192): z_u; [8192,12288): z_v;
// [12288,16384): split u_feat -> fuhi/fulo.
__global__ __launch_bounds__(256) void k_fuse1(const uint8_t* __restrict__ code,
                                               const int* __restrict__ u,
                                               const int* __restrict__ v,
                                               uint8_t* __restrict__ codeR,
                                               const float* __restrict__ u_nn,
                                               const float* __restrict__ v_nn,
                                               const float* __restrict__ colDeg,
                                               const float* __restrict__ rowDeg,
                                               unsigned short* __restrict__ chiU,
                                               unsigned short* __restrict__ cloU,
                                               unsigned short* __restrict__ chiV,
                                               unsigned short* __restrict__ cloV,
                                               const float* __restrict__ u_feat,
                                               unsigned short* __restrict__ fuhi,
                                               unsigned short* __restrict__ fulo) {
    __shared__ __align__(16) uint8_t rowbuf[4096];
    int b = blockIdx.x, t = threadIdx.x;
    if (b < 4096) {
        int i = b;
        int urow = u[i];
        ((uint4*)rowbuf)[t] = ((const uint4*)(code + (size_t)urow * N4))[t];
        __syncthreads();
        uint8_t ob[16];
        #pragma unroll
        for (int w = 0; w < 4; w++) {
            int4 vv = ((const int4*)v)[t * 4 + w];
            ob[w * 4 + 0] = rowbuf[vv.x];
            ob[w * 4 + 1] = rowbuf[vv.y];
            ob[w * 4 + 2] = rowbuf[vv.z];
            ob[w * 4 + 3] = rowbuf[vv.w];
        }
        uint4 o;
        __builtin_memcpy(&o, ob, 16);
        ((uint4*)(codeR + (size_t)i * N4))[t] = o;
    } else if (b < 12288) {
        int i = (b - 4096) & 4095;
        int side = (b - 4096) >> 12;       // 0: u, 1: v
        const float* nn = side ? v_nn : u_nn;
        const int* idxs = side ? v : u;
        const int* idxo = side ? u : v;
        const float* deg = side ? rowDeg : colDeg;
        unsigned short* catHi = side ? chiV : chiU;
        unsigned short* catLo = side ? cloV : cloU;
        int h = t;
        float d = deg[idxo[i]];
        float inv = d > 0.f ? 1.f / d : 0.f;
        float val = fmaxf(nn[(size_t)idxs[i] * H0 + h] * inv, 0.f);
        unsigned short hb = f2bf(val);
        catHi[(size_t)i * HCAT + h] = hb;
        catLo[(size_t)i * HCAT + h] = f2bf(val - bf2f(hb));
    } else {
        size_t g = ((size_t)(b - 12288) * 256 + t) * 4;
        float4 x = *(const float4*)(u_feat + g);
        float f[4] = {x.x, x.y, x.z, x.w};
        unsigned short hh[4], ll[4];
        #pragma unroll
        for (int k = 0; k < 4; k++) {
            unsigned short hb = f2bf(f[k]);
            hh[k] = hb;
            ll[k] = f2bf(f[k] - bf2f(hb));
        }
        *(ushort4*)(fuhi + g) = make_ushort4(hh[0], hh[1], hh[2], hh[3]);
        *(ushort4*)(fulo + g) = make_ushort4(ll[0], ll[1], ll[2], ll[3]);
    }
}

// ---------------------------------------------------------------- k_fuse2: split(v_feat, W1u, W1v, W2u, W2v) + Pt
// blocks [0,4096): v_feat; [4096,4608): Wu1; [4608,5120): Wv1;
// [5120,5216): Wu2; [5216,5312): Wv2; [5312,5440): Pt.
__global__ __launch_bounds__(256) void k_fuse2(const float* __restrict__ v_feat,
                                               unsigned short* __restrict__ fvhi,
                                               unsigned short* __restrict__ fvlo,
                                               const float* __restrict__ Wu1,
                                               unsigned short* __restrict__ wuhi,
                                               unsigned short* __restrict__ wulo,
                                               const float* __restrict__ Wv1,
                                               unsigned short* __restrict__ wvhi,
                                               unsigned short* __restrict__ wvlo,
                                               const float* __restrict__ Wu2,
                                               unsigned short* __restrict__ w2uhi,
                                               unsigned short* __restrict__ w2ulo,
                                               const float* __restrict__ Wv2,
                                               unsigned short* __restrict__ w2vhi,
                                               unsigned short* __restrict__ w2vlo,
                                               const float* __restrict__ P,
                                               float* __restrict__ Pt) {
    int b = blockIdx.x, t = threadIdx.x;
    if (b >= 5312) {
        int tid = (b - 5312) * 256 + t;   // 32768
        int bb = tid >> 14;
        int d = (tid >> 7) & 127;
        int e = tid & 127;
        Pt[((size_t)bb * 128 + e) * 128 + d] = P[tid];
        return;
    }
    const float* src;
    unsigned short* hi;
    unsigned short* lo;
    int lb;
    if (b < 4096)      { src = v_feat; hi = fvhi; lo = fvlo; lb = b; }
    else if (b < 4608) { src = Wu1; hi = wuhi; lo = wulo; lb = b - 4096; }
    else if (b < 5120) { src = Wv1; hi = wvhi; lo = wvlo; lb = b - 4608; }
    else if (b < 5216) { src = Wu2; hi = w2uhi; lo = w2ulo; lb = b - 5120; }
    else               { src = Wv2; hi = w2vhi; lo = w2vlo; lb = b - 5216; }
    size_t g = ((size_t)lb * 256 + t) * 4;
    float4 x = *(const float4*)(src + g);
    float f[4] = {x.x, x.y, x.z, x.w};
    unsigned short hh[4], ll[4];
    #pragma unroll
    for (int k = 0; k < 4; k++) {
        unsigned short hb = f2bf(f[k]);
        hh[k] = hb;
        ll[k] = f2bf(f[k] - bf2f(hb));
    }
    *(ushort4*)(hi + g) = make_ushort4(hh[0], hh[1], hh[2], hh[3]);
    *(ushort4*)(lo + g) = make_ushort4(ll[0], ll[1], ll[2], ll[3]);
}

// ---------------------------------------------------------------- k_l1F (MFMA bf16 split GEMM, layer 1, both sides)
// cat[i][H0+n] = relu( sum_k A[rowmap[i]][k]*B[n][k] + bias[n] ), K=1024.
// Product = Ah*Bh + Ah*Bl + Al*Bh (~fp32). z = side.
__global__ __launch_bounds__(256) void k_l1F(const unsigned short* __restrict__ fuhi,
                                             const unsigned short* __restrict__ fulo,
                                             const unsigned short* __restrict__ fvhi,
                                             const unsigned short* __restrict__ fvlo,
                                             const int* __restrict__ u,
                                             const int* __restrict__ v,
                                             const unsigned short* __restrict__ wuhi,
                                             const unsigned short* __restrict__ wulo,
                                             const unsigned short* __restrict__ wvhi,
                                             const unsigned short* __restrict__ wvlo,
                                             const float* __restrict__ bu1,
                                             const float* __restrict__ bv1,
                                             unsigned short* __restrict__ chiU,
                                             unsigned short* __restrict__ cloU,
                                             unsigned short* __restrict__ chiV,
                                             unsigned short* __restrict__ cloV) {
    int side = blockIdx.z;
    const unsigned short* Ahi = side ? fvhi : fuhi;
    const unsigned short* Alo = side ? fvlo : fulo;
    const int* rowmap = side ? v : u;
    const unsigned short* Bhi = side ? wvhi : wuhi;
    const unsigned short* Blo = side ? wvlo : wulo;
    const float* bias = side ? bv1 : bu1;
    unsigned short* CHi = (side ? chiV : chiU) + H0;
    unsigned short* CLo = (side ? cloV : cloU) + H0;

    int t = threadIdx.x;
    int wave = t >> 6, lane = t & 63;
    int lr = lane & 15;
    int lk = lane >> 4;
    int i0 = blockIdx.y * 64 + wave * 16;
    int n0 = blockIdx.x * 64;
    int gi = rowmap[i0 + lr];
    const unsigned short* pah = Ahi + (size_t)gi * SIDE + lk * 8;
    const unsigned short* pal = Alo + (size_t)gi * SIDE + lk * 8;
    floatx4 acc[4];
    #pragma unroll
    for (int jt = 0; jt < 4; jt++) acc[jt] = (floatx4){0.f, 0.f, 0.f, 0.f};
    for (int kc = 0; kc < SIDE / 32; kc++) {
        short8 ah = *(const short8*)(pah + kc * 32);
        short8 al = *(const short8*)(pal + kc * 32);
        #pragma unroll
        for (int jt = 0; jt < 4; jt++) {
            int bc = n0 + jt * 16 + lr;
            short8 bh = *(const short8*)(Bhi + (size_t)bc * SIDE + kc * 32 + lk * 8);
            short8 bl = *(const short8*)(Blo + (size_t)bc * SIDE + kc * 32 + lk * 8);
            acc[jt] = __builtin_amdgcn_mfma_f32_16x16x32_bf16(ah, bh, acc[jt], 0, 0, 0);
            acc[jt] = __builtin_amdgcn_mfma_f32_16x16x32_bf16(ah, bl, acc[jt], 0, 0, 0);
            acc[jt] = __builtin_amdgcn_mfma_f32_16x16x32_bf16(al, bh, acc[jt], 0, 0, 0);
        }
    }
    #pragma unroll
    for (int jt = 0; jt < 4; jt++) {
        int cn = n0 + jt * 16 + lr;
        float b = bias[cn];
        #pragma unroll
        for (int r = 0; r < 4; r++) {
            int ci = i0 + lk * 4 + r;
            float vv = fmaxf(acc[jt][r] + b, 0.f);
            unsigned short hb = f2bf(vv);
            CHi[(size_t)ci * HCAT + cn] = hb;
            CLo[(size_t)ci * HCAT + cn] = f2bf(vv - bf2f(hb));
        }
    }
}

// ---------------------------------------------------------------- k_l2F (MFMA bf16 split GEMM, layer 2, both sides)
// z=0: uh (fp32); z=1: vhb (bf16). K=768, N=128.
__global__ __launch_bounds__(256) void k_l2F(const unsigned short* __restrict__ chiU,
                                             const unsigned short* __restrict__ cloU,
                                             const unsigned short* __restrict__ w2uhi,
                                             const unsigned short* __restrict__ w2ulo,
                                             float* __restrict__ uh,
                                             const unsigned short* __restrict__ chiV,
                                             const unsigned short* __restrict__ cloV,
                                             const unsigned short* __restrict__ w2vhi,
                                             const unsigned short* __restrict__ w2vlo,
                                             unsigned short* __restrict__ vhb) {
    int side = blockIdx.z;
    const unsigned short* Ahi = side ? chiV : chiU;
    const unsigned short* Alo = side ? cloV : cloU;
    const unsigned short* Bhi = side ? w2vhi : w2uhi;
    const unsigned short* Blo = side ? w2vlo : w2ulo;

    int t = threadIdx.x;
    int wave = t >> 6, lane = t & 63;
    int lr = lane & 15;
    int lk = lane >> 4;
    int i0 = blockIdx.y * 64 + wave * 16;
    int n0 = blockIdx.x * 64;
    const unsigned short* pah = Ahi + (size_t)(i0 + lr) * HCAT + lk * 8;
    const unsigned short* pal = Alo + (size_t)(i0 + lr) * HCAT + lk * 8;
    floatx4 acc[4];
    #pragma unroll
    for (int jt = 0; jt < 4; jt++) acc[jt] = (floatx4){0.f, 0.f, 0.f, 0.f};
    for (int kc = 0; kc < HCAT / 32; kc++) {
        short8 ah = *(const short8*)(pah + kc * 32);
        short8 al = *(const short8*)(pal + kc * 32);
        #pragma unroll
        for (int jt = 0; jt < 4; jt++) {
            int bc = n0 + jt * 16 + lr;
            short8 bh = *(const short8*)(Bhi + (size_t)bc * HCAT + kc * 32 + lk * 8);
            short8 bl = *(const short8*)(Blo + (size_t)bc * HCAT + kc * 32 + lk * 8);
            acc[jt] = __builtin_amdgcn_mfma_f32_16x16x32_bf16(ah, bh, acc[jt], 0, 0, 0);
            acc[jt] = __builtin_amdgcn_mfma_f32_16x16x32_bf16(ah, bl, acc[jt], 0, 0, 0);
            acc[jt] = __builtin_amdgcn_mfma_f32_16x16x32_bf16(al, bh, acc[jt], 0, 0, 0);
        }
    }
    #pragma unroll
    for (int jt = 0; jt < 4; jt++) {
        int cn = n0 + jt * 16 + lr;
        #pragma unroll
        for (int r = 0; r < 4; r++) {
            int ci = i0 + lk * 4 + r;
            float vv = fmaxf(acc[jt][r], 0.f);
            if (side) {
                vhb[(size_t)ci * H1 + cn] = f2bf(vv);
            } else {
                uh[(size_t)ci * H1 + cn] = vv;
            }
        }
    }
}

// ---------------------------------------------------------------- generic NT GEMM (fp32 in, bf16 out) — tb GEMM
template <int TM, int TN, int BK, int RM, int RN>
__global__ __launch_bounds__(256) void k_gemm(const float* __restrict__ A, int lda,
                                              const float* __restrict__ B, int ldb,
                                              float* __restrict__ C, int ldc, int K,
                                              size_t bzs, size_t czs) {
    constexpr int TX = TN / RN;
    constexpr int TY = TM / RM;
    static_assert(TX * TY == 256, "block must be 256");
    __shared__ float As[BK][TM + 4];
    __shared__ float Bs[BK][TN + 4];
    int tid = threadIdx.x;
    int tx = tid % TX, ty = tid / TX;
    int i0 = blockIdx.x * TM, n0 = blockIdx.y * TN;
    const float* Bz = B + (size_t)blockIdx.z * bzs;
    float acc[RM][RN] = {};
    for (int k0 = 0; k0 < K; k0 += BK) {
        for (int g = tid; g < TM * BK / 4; g += 256) {
            int i = g / (BK / 4), kc = g % (BK / 4);
            float4 val = *(const float4*)(A + (size_t)(i0 + i) * lda + k0 + kc * 4);
            As[kc * 4 + 0][i] = val.x; As[kc * 4 + 1][i] = val.y;
            As[kc * 4 + 2][i] = val.z; As[kc * 4 + 3][i] = val.w;
        }
        for (int g = tid; g < TN * BK / 4; g += 256) {
            int n = g / (BK / 4), kc = g % (BK / 4);
            float4 val = *(const float4*)(Bz + (size_t)(n0 + n) * ldb + k0 + kc * 4);
            Bs[kc * 4 + 0][n] = val.x; Bs[kc * 4 + 1][n] = val.y;
            Bs[kc * 4 + 2][n] = val.z; Bs[kc * 4 + 3][n] = val.w;
        }
        __syncthreads();
        #pragma unroll
        for (int k = 0; k < BK; k++) {
            float av[RM], bv[RN];
            #pragma unroll
            for (int m = 0; m < RM; m++) av[m] = As[k][ty * RM + m];
            #pragma unroll
            for (int n = 0; n < RN; n++) bv[n] = Bs[k][tx * RN + n];
            #pragma unroll
            for (int m = 0; m < RM; m++)
                #pragma unroll
                for (int n = 0; n < RN; n++)
                    acc[m][n] = fmaf(av[m], bv[n], acc[m][n]);
        }
        __syncthreads();
    }
    #pragma unroll
    for (int m = 0; m < RM; m++) {
        int ig = i0 + ty * RM + m;
        #pragma unroll
        for (int n = 0; n < RN; n++) {
            unsigned short* Cz16 = (unsigned short*)C + (size_t)blockIdx.z * czs;
            Cz16[(size_t)ig * ldc + n0 + tx * RN + n] = f2bf(acc[m][n]);
        }
    }
}

// ---------------------------------------------------------------- k_scores3 (MFMA bf16 decoder + softmax epilogue)
__global__ __launch_bounds__(256) void k_scores3(const unsigned short* __restrict__ tb,  // [2][4096][128] bf16
                                                 const unsigned short* __restrict__ vhb, // [4096][128] bf16
                                                 const uint8_t* __restrict__ codeR,
                                                 const float* __restrict__ a_f,          // [2][5]
                                                 float* __restrict__ mhat,
                                                 float* __restrict__ part) {
    __shared__ float wred[4][3];
    int t = threadIdx.x;
    int wave = t >> 6, lane = t & 63;
    int lr = lane & 15;          // A row / B col / C col
    int lk = lane >> 4;          // k-subgroup & C row-group
    int i0 = blockIdx.y * 64 + wave * 16;
    int j0 = blockIdx.x * 128;
    float sa0[NC], sa1[NC];
    #pragma unroll
    for (int c = 0; c < NC; c++) { sa0[c] = a_f[c]; sa1[c] = a_f[5 + c]; }

    const unsigned short* t0p = tb;
    const unsigned short* t1p = tb + (size_t)N4 * H1;
    short8 a0[4], a1[4];
    #pragma unroll
    for (int kc = 0; kc < 4; kc++) {
        size_t off = (size_t)(i0 + lr) * H1 + kc * 32 + lk * 8;
        a0[kc] = *(const short8*)(t0p + off);
        a1[kc] = *(const short8*)(t1p + off);
    }

    float lsum = 0.f, ssum = 0.f, nobs = 0.f;
    for (int jt = 0; jt < 8; jt++) {
        int jb = j0 + jt * 16;
        int j = jb + lr;
        // hoist codeR loads above the MFMAs so HBM latency overlaps compute
        const uint8_t* crp = codeR + (size_t)(i0 + lk * 4) * N4 + j;
        int cbv[4];
        cbv[0] = crp[0];
        cbv[1] = crp[N4];
        cbv[2] = crp[2 * N4];
        cbv[3] = crp[3 * N4];
        floatx4 C0 = {0.f, 0.f, 0.f, 0.f}, C1 = {0.f, 0.f, 0.f, 0.f};
        #pragma unroll
        for (int kc = 0; kc < 4; kc++) {
            short8 b = *(const short8*)(vhb + (size_t)(jb + lr) * H1 + kc * 32 + lk * 8);
            C0 = __builtin_amdgcn_mfma_f32_16x16x32_bf16(a0[kc], b, C0, 0, 0, 0);
            C1 = __builtin_amdgcn_mfma_f32_16x16x32_bf16(a1[kc], b, C1, 0, 0, 0);
        }
        #pragma unroll
        for (int r = 0; r < 4; r++) {
            int i = i0 + lk * 4 + r;
            float v0 = C0[r], v1 = C1[r];
            float l[NC];
            float mx = -1e30f;
            #pragma unroll
            for (int c = 0; c < NC; c++) {
                l[c] = sa0[c] * v0 + sa1[c] * v1;
                mx = fmaxf(mx, l[c]);
            }
            float den = 0.f, num = 0.f;
            #pragma unroll
            for (int c = 0; c < NC; c++) {
                float e = __expf(l[c] - mx);
                den += e;
                num += (float)(c + 1) * e;
            }
            float mh = num / den;
            mhat[(size_t)i * N4 + j] = mh;
            int cb = cbv[r];
            if (cb) {
                float lse = mx + __logf(den);
                lsum += lse - l[cb - 1];        // = -logp[cb-1]
                float df = mh - (float)cb;
                ssum += df * df;
                nobs += 1.f;
            }
        }
    }
    #pragma unroll
    for (int off = 32; off; off >>= 1) {
        lsum += __shfl_down(lsum, off, 64);
        ssum += __shfl_down(ssum, off, 64);
        nobs += __shfl_down(nobs, off, 64);
    }
    if (lane == 0) { wred[wave][0] = lsum; wred[wave][1] = ssum; wred[wave][2] = nobs; }
    __syncthreads();
    if (t == 0) {
        int bid = blockIdx.y * gridDim.x + blockIdx.x;
        part[bid * 3 + 0] = wred[0][0] + wred[1][0] + wred[2][0] + wred[3][0];
        part[bid * 3 + 1] = wred[0][1] + wred[1][1] + wred[2][1] + wred[3][1];
        part[bid * 3 + 2] = wred[0][2] + wred[1][2] + wred[2][2] + wred[3][2];
    }
}

// ---------------------------------------------------------------- k_finalize (reduce 2048 block partials)
__global__ __launch_bounds__(256) void k_finalize(const float* __restrict__ part,
                                                  float* __restrict__ out) {
    __shared__ float sred[3][4];
    int t = threadIdx.x, lane = t & 63, wv = t >> 6;
    float l = 0.f, s = 0.f, n = 0.f;
    for (int i = t; i < 2048; i += 256) {
        l += part[i * 3 + 0];
        s += part[i * 3 + 1];
        n += part[i * 3 + 2];
    }
    #pragma unroll
    for (int off = 32; off; off >>= 1) {
        l += __shfl_down(l, off, 64);
        s += __shfl_down(s, off, 64);
        n += __shfl_down(n, off, 64);
    }
    if (lane == 0) { sred[0][wv] = l; sred[1][wv] = s; sred[2][wv] = n; }
    __syncthreads();
    if (t == 0) {
        float L = sred[0][0] + sred[0][1] + sred[0][2] + sred[0][3];
        float S = sred[1][0] + sred[1][1] + sred[1][2] + sred[1][3];
        float N = fmaxf(sred[2][0] + sred[2][1] + sred[2][2] + sred[2][3], 1.f);
        out[NUV + 0] = L / N;
        out[NUV + 1] = sqrtf(S / N);
    }
}

// ================================================================ launch
extern "C" void kernel_launch(void* const* d_in, const int* in_sizes, int n_in,
                              void* d_out, int out_size, void* d_ws, size_t ws_size,
                              hipStream_t stream) {
    const int* u = (const int*)d_in[0];
    const int* v = (const int*)d_in[1];
    const float* adj    = (const float*)d_in[3];
    const float* u_feat = (const float*)d_in[4];
    const float* v_feat = (const float*)d_in[5];
    const float* u_w    = (const float*)d_in[6];
    const float* v_w    = (const float*)d_in[7];
    const float* Wu1    = (const float*)d_in[8];
    const float* bu1    = (const float*)d_in[9];
    const float* Wv1    = (const float*)d_in[10];
    const float* bv1    = (const float*)d_in[11];
    const float* Wu2    = (const float*)d_in[12];
    const float* Wv2    = (const float*)d_in[13];
    const float* P      = (const float*)d_in[14];
    const float* a      = (const float*)d_in[15];
    float* out = (float*)d_out;

    char* ws = (char*)d_ws;
    // workspace layout (bytes); total ~100 MB. Overlay audit per fused stage:
    //  codeT on UCAT (dead after compactF); codeR on TAU+TBV (dead after gatherF);
    //  part on CNTU+CNTV (dead after compactF); fuhi/fulo on IDXU/IDXV (dead
    //  after gatherF); fvhi/fvlo on CODE (dead after fuse1's reorder);
    //  W1 splits on UNN/VNN (u_nn/v_nn dead after fuse1's z);
    //  W2 splits on TB (dead until tb GEMM, consumed by l2F first);
    //  cat bf16 hi/lo planes on UCAT/VCAT.
    const size_t O_CODE  = 0;                         // 16,777,216 u8
    const size_t O_CNTU  = 16777216;                  // 16,384 i32
    const size_t O_CNTV  = O_CNTU + 16384;            // 16,384 i32
    const size_t O_ACC   = O_CNTV + 16384;            // 256 B (unused)
    const size_t O_TAU   = O_ACC + 256;               // 10,485,760 f16 table (u side)
    const size_t O_TBV   = O_TAU + 10485760;          // 10,485,760 f16 table (v side)
    const size_t O_IDXU  = O_TBV + 10485760;          // 12,582,912 u16 [4096][CAP]
    const size_t O_IDXV  = O_IDXU + 12582912;         // 12,582,912 u16
    const size_t O_NNZU  = O_IDXV + 12582912;         // 16,384 i32
    const size_t O_NNZV  = O_NNZU + 16384;            // 16,384 i32
    const size_t O_RDEG  = O_NNZV + 16384;            // 16,384 f32
    const size_t O_CDEG  = O_RDEG + 16384;            // 16,384 f32
    const size_t O_UNN   = O_CDEG + 16384;            // 4,194,304 f32
    const size_t O_VNN   = O_UNN + 4194304;           // 4,194,304 f32
    const size_t O_UCAT  = O_VNN + 4194304;           // 12,582,912 (bf16 hi+lo planes)
    const size_t O_VCAT  = O_UCAT + 12582912;         // 12,582,912
    const size_t O_UH    = O_VCAT + 12582912;         // 2,097,152 f32
    const size_t O_VHB   = O_UH + 2097152;            // 1,048,576 bf16 [4096][128]
    const size_t O_PT    = O_VHB + 1048576;           // 131,072 f32
    const size_t O_TB    = O_PT + 131072;             // 2,097,152 bf16 [2][4096][128]
    const size_t O_CODET = O_UCAT;                    // overlay
    const size_t O_CODER = O_TAU;                     // overlay (fits TAU+TBV)
    const size_t O_PART  = O_CNTU;                    // overlay (cnt dead after compact)
    const size_t O_FUHI  = O_IDXU;                    // overlay, 8,388,608
    const size_t O_FULO  = O_IDXV;                    // overlay, 8,388,608
    const size_t O_FVHI  = O_CODE;                    // overlay, 8,388,608
    const size_t O_FVLO  = O_CODE + 8388608;          // overlay, 8,388,608
    const size_t O_WUHI  = O_UNN;                     // overlay, 1,048,576
    const size_t O_WULO  = O_UNN + 1048576;           // overlay, 1,048,576
    const size_t O_WVHI  = O_VNN;                     // overlay, 1,048,576
    const size_t O_WVLO  = O_VNN + 1048576;           // overlay, 1,048,576
    const size_t O_CHIU  = O_UCAT;                    // [4096][768] u16 hi
    const size_t O_CLOU  = O_UCAT + 6291456;          // [4096][768] u16 lo
    const size_t O_CHIV  = O_VCAT;
    const size_t O_CLOV  = O_VCAT + 6291456;
    const size_t O_W2UHI = O_TB;                      // overlay (tb written later), 196,608 each
    const size_t O_W2ULO = O_TB + 196608;
    const size_t O_W2VHI = O_TB + 393216;
    const size_t O_W2VLO = O_TB + 589824;

    uint8_t* code  = (uint8_t*)(ws + O_CODE);
    uint8_t* codeT = (uint8_t*)(ws + O_CODET);
    uint8_t* codeR = (uint8_t*)(ws + O_CODER);
    int* cnt_u = (int*)(ws + O_CNTU);
    int* cnt_v = (int*)(ws + O_CNTV);
    unsigned short* T_Au = (unsigned short*)(ws + O_TAU);
    unsigned short* T_Bv = (unsigned short*)(ws + O_TBV);
    unsigned short* idxU = (unsigned short*)(ws + O_IDXU);
    unsigned short* idxV = (unsigned short*)(ws + O_IDXV);
    int* nnzU = (int*)(ws + O_NNZU);
    int* nnzV = (int*)(ws + O_NNZV);
    float* rowDeg = (float*)(ws + O_RDEG);
    float* colDeg = (float*)(ws + O_CDEG);
    float* u_nn = (float*)(ws + O_UNN);
    float* v_nn = (float*)(ws + O_VNN);
    float* uh = (float*)(ws + O_UH);
    unsigned short* vhb = (unsigned short*)(ws + O_VHB);
    float* Pt = (float*)(ws + O_PT);
    unsigned short* tb = (unsigned short*)(ws + O_TB);
    float* part = (float*)(ws + O_PART);
    unsigned short* fuhi = (unsigned short*)(ws + O_FUHI);
    unsigned short* fulo = (unsigned short*)(ws + O_FULO);
    unsigned short* fvhi = (unsigned short*)(ws + O_FVHI);
    unsigned short* fvlo = (unsigned short*)(ws + O_FVLO);
    unsigned short* wuhi = (unsigned short*)(ws + O_WUHI);
    unsigned short* wulo = (unsigned short*)(ws + O_WULO);
    unsigned short* wvhi = (unsigned short*)(ws + O_WVHI);
    unsigned short* wvlo = (unsigned short*)(ws + O_WVLO);
    unsigned short* w2uhi = (unsigned short*)(ws + O_W2UHI);
    unsigned short* w2ulo = (unsigned short*)(ws + O_W2ULO);
    unsigned short* w2vhi = (unsigned short*)(ws + O_W2VHI);
    unsigned short* w2vlo = (unsigned short*)(ws + O_W2VLO);

    hipMemsetAsync(ws + O_CNTU, 0, 16384 + 16384, stream);

    k_counts<<<16, 256, 0, stream>>>(u, v, cnt_u, cnt_v);
    k_code<<<16384, 256, 0, stream>>>(adj, (uchar4*)code);
    k_fuse0<<<12288, 256, 0, stream>>>(code, codeT, u_w, cnt_u, T_Au, v_w, cnt_v, T_Bv);
    k_compactF<<<dim3(N4, 2), 256, 0, stream>>>(code, codeT, cnt_u, cnt_v,
                                                idxU, nnzU, rowDeg, idxV, nnzV, colDeg);
    k_gatherF<<<dim3(N4, 2, 2), 256, 0, stream>>>(idxU, nnzU, T_Bv, u_nn,
                                                  idxV, nnzV, T_Au, v_nn);
    k_fuse1<<<16384, 256, 0, stream>>>(code, u, v, codeR, u_nn, v_nn, colDeg, rowDeg,
                                       (unsigned short*)(ws + O_CHIU), (unsigned short*)(ws + O_CLOU),
                                       (unsigned short*)(ws + O_CHIV), (unsigned short*)(ws + O_CLOV),
                                       u_feat, fuhi, fulo);
    k_fuse2<<<5440, 256, 0, stream>>>(v_feat, fvhi, fvlo, Wu1, wuhi, wulo,
                                      Wv1, wvhi, wvlo, Wu2, w2uhi, w2ulo,
                                      Wv2, w2vhi, w2vlo, P, Pt);
    k_l1F<<<dim3(8, 64, 2), 256, 0, stream>>>(fuhi, fulo, fvhi, fvlo, u, v,
                                              wuhi, wulo, wvhi, wvlo, bu1, bv1,
                                              (unsigned short*)(ws + O_CHIU), (unsigned short*)(ws + O_CLOU),
                                              (unsigned short*)(ws + O_CHIV), (unsigned short*)(ws + O_CLOV));
    k_l2F<<<dim3(2, 64, 2), 256, 0, stream>>>((unsigned short*)(ws + O_CHIU), (unsigned short*)(ws + O_CLOU),
                                              w2uhi, w2ulo, uh,
                                              (unsigned short*)(ws + O_CHIV), (unsigned short*)(ws + O_CLOV),
                                              w2vhi, w2vlo, vhb);
    // t[b] = uh @ P[b] -> bf16 (overwrites dead W2 splits)
    k_gemm<64, 32, 16, 4, 2>
        <<<dim3(64, 4, 2), 256, 0, stream>>>(uh, H1, Pt, H1,
                                             (float*)tb, H1, H1,
                                             (size_t)H1 * H1, (size_t)N4 * H1);
    k_scores3<<<dim3(32, 64), 256, 0, stream>>>(tb, vhb, codeR, a, out, part);
    k_finalize<<<1, 256, 0, stream>>>(part, out);
}

// Round 6
// 891.844 us; speedup vs baseline: 1.3268x; 1.1348x over previous
//
#include <hip/hip_runtime.h>
#include <stdint.h>

// Problem constants
#define N4   4096
#define H0   256
#define SIDE 1024
#define DIN  512
#define HCAT 768      // H0 + DIN
#define H1   128
#define NC   5
#define NUV  16777216ULL   // 4096*4096
#define CAP  1536          // max compacted entries per row

typedef __attribute__((ext_vector_type(8))) short short8;    // 8 bf16
typedef __attribute__((ext_vector_type(4))) float floatx4;

__device__ __forceinline__ unsigned short f2bf(float f) {
    unsigned int u;
    __builtin_memcpy(&u, &f, 4);
    unsigned int r = (u + 0x7FFFu + ((u >> 16) & 1u)) >> 16;   // RNE
    return (unsigned short)r;
}

__device__ __forceinline__ float bf2f(unsigned short b) {
    unsigned int u = (unsigned int)b << 16;
    float f;
    __builtin_memcpy(&f, &u, 4);
    return f;
}

// ---------------------------------------------------------------- k_codeF: code + counts
// blocks [0,16384): code; [16384,16400): counts
__global__ __launch_bounds__(256) void k_codeF(const float* __restrict__ adj,
                                               uchar4* __restrict__ code4,
                                               const int* __restrict__ u,
                                               const int* __restrict__ v,
                                               int* __restrict__ cu,
                                               int* __restrict__ cv) {
    int b = blockIdx.x, t = threadIdx.x;
    if (b < 16384) {
        size_t g = (size_t)b * 256 + t;
        size_t base = g * 4;
        uchar4 out = {0, 0, 0, 0};
        #pragma unroll
        for (int c = 0; c < NC; c++) {
            float4 s = *(const float4*)(adj + (size_t)c * NUV + base);
            out.x = (s.x != 0.f) ? (unsigned char)(c + 1) : out.x;
            out.y = (s.y != 0.f) ? (unsigned char)(c + 1) : out.y;
            out.z = (s.z != 0.f) ? (unsigned char)(c + 1) : out.z;
            out.w = (s.w != 0.f) ? (unsigned char)(c + 1) : out.w;
        }
        code4[g] = out;
    } else {
        int i = (b - 16384) * 256 + t;   // 4096 threads
        atomicAdd(&cu[u[i]], 1);
        atomicAdd(&cv[v[i]], 1);
    }
}

// ---------------------------------------------------------------- k_fuse0: transpose + wcumsum x2
// blocks [0,4096): byte transpose 64x64 tile; [4096,12288): wcumsum (side by range)
__global__ __launch_bounds__(256) void k_fuse0(const uint8_t* __restrict__ code,
                                               uint8_t* __restrict__ codeT,
                                               const float* __restrict__ u_w,
                                               const int* __restrict__ cnt_u,
                                               unsigned short* __restrict__ T_Au,
                                               const float* __restrict__ v_w,
                                               const int* __restrict__ cnt_v,
                                               unsigned short* __restrict__ T_Bv) {
    __shared__ __align__(16) uint8_t tile[64][80];
    int b = blockIdx.x, t = threadIdx.x;
    if (b < 4096) {
        int bx = b & 63, by = b >> 6;
        int row = t >> 2;
        int seg = (t & 3) * 16;
        int p0 = by * 64, q0 = bx * 64;
        uint4 vdat = *(const uint4*)(code + (size_t)(p0 + row) * N4 + q0 + seg);
        *(uint4*)(&tile[row][seg]) = vdat;
        __syncthreads();
        union { uint4 u4; uint8_t bb[16]; } o;
        #pragma unroll
        for (int l = 0; l < 16; l++) o.bb[l] = tile[seg + l][row];
        *(uint4*)(codeT + (size_t)(q0 + row) * N4 + p0 + seg) = o.u4;
    } else {
        int node = (b - 4096) & 4095;
        int side = (b - 4096) >> 12;       // 0: u-table, 1: v-table
        const float* w = side ? v_w : u_w;
        const int* cnt = side ? cnt_v : cnt_u;
        unsigned short* out = side ? T_Bv : T_Au;
        int h = t;
        float c = (float)cnt[node];
        float acc = 0.f;
        #pragma unroll
        for (int r = 0; r < NC; r++) {
            size_t idx = ((size_t)r * N4 + node) * H0 + h;
            acc += w[idx];
            union { _Float16 h16; unsigned short s; } cvt;
            cvt.h16 = (_Float16)(acc * c);
            out[idx] = cvt.s;
        }
    }
}

// ---------------------------------------------------------------- k_compactF (both sides; y = side)
__global__ __launch_bounds__(256) void k_compactF(const uint8_t* __restrict__ code,
                                                  const uint8_t* __restrict__ codeT,
                                                  const int* __restrict__ cnt_u,
                                                  const int* __restrict__ cnt_v,
                                                  unsigned short* __restrict__ idxU,
                                                  int* __restrict__ nnzU,
                                                  float* __restrict__ rowDeg,
                                                  unsigned short* __restrict__ idxV,
                                                  int* __restrict__ nnzV,
                                                  float* __restrict__ colDeg) {
    __shared__ float cw[4096];
    __shared__ int wtot[4];
    __shared__ float wdeg[4];
    __shared__ unsigned short ebuf[CAP];
    int side = blockIdx.y;
    const uint8_t* codeRows = side ? codeT : code;
    const int* cntOther = side ? cnt_u : cnt_v;
    unsigned short* idx = side ? idxV : idxU;
    int* nnz = side ? nnzV : nnzU;
    float* deg = side ? colDeg : rowDeg;

    int p = blockIdx.x, t = threadIdx.x;
    int lane = t & 63, wv = t >> 6;
    const int4* co4 = (const int4*)cntOther;
    #pragma unroll
    for (int l = 0; l < 4; l++) {
        int4 ci = co4[t + l * 256];
        ((float4*)cw)[t + l * 256] =
            make_float4((float)ci.x, (float)ci.y, (float)ci.z, (float)ci.w);
    }
    uint4 w = ((const uint4*)(codeRows + (size_t)p * N4))[t];
    unsigned char b[16];
    __builtin_memcpy(b, &w, 16);
    int cnt = 0;
    #pragma unroll
    for (int j = 0; j < 16; j++) cnt += (b[j] != 0);
    int sc = cnt;
    #pragma unroll
    for (int off = 1; off < 64; off <<= 1) {
        int up = __shfl_up(sc, off, 64);
        if (lane >= off) sc += up;
    }
    if (lane == 63) wtot[wv] = sc;
    __syncthreads();            // covers cw + wtot
    int wbase = 0;
    #pragma unroll
    for (int ww = 0; ww < 4; ww++) wbase += (ww < wv) ? wtot[ww] : 0;
    int total = wtot[0] + wtot[1] + wtot[2] + wtot[3];
    int pos = wbase + sc - cnt;   // block-exclusive prefix
    float dsum = 0.f;
    #pragma unroll
    for (int j = 0; j < 16; j++) {
        int r = b[j];
        if (r) {
            int q = t * 16 + j;
            if (pos < CAP) ebuf[pos] = (unsigned short)((r - 1) * N4 + q);
            pos++;
            dsum += cw[q];
        }
    }
    #pragma unroll
    for (int off = 32; off; off >>= 1) dsum += __shfl_down(dsum, off, 64);
    if (lane == 0) wdeg[wv] = dsum;
    __syncthreads();            // covers ebuf + wdeg
    int tw = total < CAP ? total : CAP;
    if (t == 0) { deg[p] = wdeg[0] + wdeg[1] + wdeg[2] + wdeg[3]; nnz[p] = tw; }
    for (int e = t; e < tw; e += 256) idx[(size_t)p * CAP + e] = ebuf[e];
}

// ---------------------------------------------------------------- k_gatherF
// v5: both sides fused (z = side), 2 blocks per row (y = half: 256B of the
// 512B table row each), 16 entry slots x 16 segments, x4-deep MLP.
__global__ __launch_bounds__(256) void k_gatherF(const unsigned short* __restrict__ idxU,
                                                 const int* __restrict__ nnzU,
                                                 const unsigned short* __restrict__ T_Bv,
                                                 float* __restrict__ u_nn,
                                                 const unsigned short* __restrict__ idxV,
                                                 const int* __restrict__ nnzV,
                                                 const unsigned short* __restrict__ T_Au,
                                                 float* __restrict__ v_nn) {
    __shared__ unsigned short sidx[CAP];
    __shared__ float red[16][132];
    int side = blockIdx.z;
    const unsigned short* idx = side ? idxV : idxU;
    const int* nnz = side ? nnzV : nnzU;
    const char* tb = (const char*)(side ? T_Au : T_Bv);
    float* outNN = side ? v_nn : u_nn;

    int p = blockIdx.x, half = blockIdx.y, t = threadIdx.x;
    int n = nnz[p];
    const unsigned short* rowIdx = idx + (size_t)p * CAP;
    for (int i = t; i < n; i += 256) sidx[i] = rowIdx[i];
    __syncthreads();
    int s = t >> 4;        // entry slot 0..15
    int c = t & 15;        // 16B segment within half-row
    int boff = half * 256 + c * 16;
    float acc[8] = {0.f, 0.f, 0.f, 0.f, 0.f, 0.f, 0.f, 0.f};
    int nmain = n & ~63;
    for (int e = s; e < nmain; e += 64) {
        int o0 = ((int)sidx[e])      << 9;
        int o1 = ((int)sidx[e + 16]) << 9;
        int o2 = ((int)sidx[e + 32]) << 9;
        int o3 = ((int)sidx[e + 48]) << 9;
        uint4 d0 = *(const uint4*)(tb + o0 + boff);
        uint4 d1 = *(const uint4*)(tb + o1 + boff);
        uint4 d2 = *(const uint4*)(tb + o2 + boff);
        uint4 d3 = *(const uint4*)(tb + o3 + boff);
        union { uint4 u; _Float16 h[8]; } cv;
        cv.u = d0;
        #pragma unroll
        for (int k = 0; k < 8; k++) acc[k] += (float)cv.h[k];
        cv.u = d1;
        #pragma unroll
        for (int k = 0; k < 8; k++) acc[k] += (float)cv.h[k];
        cv.u = d2;
        #pragma unroll
        for (int k = 0; k < 8; k++) acc[k] += (float)cv.h[k];
        cv.u = d3;
        #pragma unroll
        for (int k = 0; k < 8; k++) acc[k] += (float)cv.h[k];
    }
    for (int e = nmain + s; e < n; e += 16) {
        int o = ((int)sidx[e]) << 9;
        uint4 d = *(const uint4*)(tb + o + boff);
        union { uint4 u; _Float16 h[8]; } cv;
        cv.u = d;
        #pragma unroll
        for (int k = 0; k < 8; k++) acc[k] += (float)cv.h[k];
    }
    #pragma unroll
    for (int k = 0; k < 8; k++) red[s][c * 8 + k] = acc[k];
    __syncthreads();
    if (t < 128) {
        float sum = 0.f;
        #pragma unroll
        for (int ss = 0; ss < 16; ss++) sum += red[ss][t];
        outNN[(size_t)p * H0 + half * 128 + t] = sum;
    }
}

// ---------------------------------------------------------------- k_fuse1: reorder + z x2 + ALL splits + Pt
// [0,4096): reorder; [4096,12288): z; [12288,16384): split u_feat;
// [16384,20480): split v_feat; [20480,20992): Wu1; [20992,21504): Wv1;
// [21504,21600): Wu2; [21600,21696): Wv2; [21696,21824): Pt.
// fv/W splits land in d_out scratch (mhat fully overwritten by k_scores3 later).
__global__ __launch_bounds__(256) void k_fuse1(const uint8_t* __restrict__ code,
                                               const int* __restrict__ u,
                                               const int* __restrict__ v,
                                               uint8_t* __restrict__ codeR,
                                               const float* __restrict__ u_nn,
                                               const float* __restrict__ v_nn,
                                               const float* __restrict__ colDeg,
                                               const float* __restrict__ rowDeg,
                                               unsigned short* __restrict__ chiU,
                                               unsigned short* __restrict__ cloU,
                                               unsigned short* __restrict__ chiV,
                                               unsigned short* __restrict__ cloV,
                                               const float* __restrict__ u_feat,
                                               unsigned short* __restrict__ fuhi,
                                               unsigned short* __restrict__ fulo,
                                               const float* __restrict__ v_feat,
                                               unsigned short* __restrict__ fvhi,
                                               unsigned short* __restrict__ fvlo,
                                               const float* __restrict__ Wu1,
                                               unsigned short* __restrict__ wuhi,
                                               unsigned short* __restrict__ wulo,
                                               const float* __restrict__ Wv1,
                                               unsigned short* __restrict__ wvhi,
                                               unsigned short* __restrict__ wvlo,
                                               const float* __restrict__ Wu2,
                                               unsigned short* __restrict__ w2uhi,
                                               unsigned short* __restrict__ w2ulo,
                                               const float* __restrict__ Wv2,
                                               unsigned short* __restrict__ w2vhi,
                                               unsigned short* __restrict__ w2vlo,
                                               const float* __restrict__ P,
                                               float* __restrict__ Pt) {
    __shared__ __align__(16) uint8_t rowbuf[4096];
    int b = blockIdx.x, t = threadIdx.x;
    if (b < 4096) {
        int i = b;
        int urow = u[i];
        ((uint4*)rowbuf)[t] = ((const uint4*)(code + (size_t)urow * N4))[t];
        __syncthreads();
        uint8_t ob[16];
        #pragma unroll
        for (int w = 0; w < 4; w++) {
            int4 vv = ((const int4*)v)[t * 4 + w];
            ob[w * 4 + 0] = rowbuf[vv.x];
            ob[w * 4 + 1] = rowbuf[vv.y];
            ob[w * 4 + 2] = rowbuf[vv.z];
            ob[w * 4 + 3] = rowbuf[vv.w];
        }
        uint4 o;
        __builtin_memcpy(&o, ob, 16);
        ((uint4*)(codeR + (size_t)i * N4))[t] = o;
        return;
    }
    if (b < 12288) {
        int i = (b - 4096) & 4095;
        int side = (b - 4096) >> 12;       // 0: u, 1: v
        const float* nn = side ? v_nn : u_nn;
        const int* idxs = side ? v : u;
        const int* idxo = side ? u : v;
        const float* deg = side ? rowDeg : colDeg;
        unsigned short* catHi = side ? chiV : chiU;
        unsigned short* catLo = side ? cloV : cloU;
        int h = t;
        float d = deg[idxo[i]];
        float inv = d > 0.f ? 1.f / d : 0.f;
        float val = fmaxf(nn[(size_t)idxs[i] * H0 + h] * inv, 0.f);
        unsigned short hb = f2bf(val);
        catHi[(size_t)i * HCAT + h] = hb;
        catLo[(size_t)i * HCAT + h] = f2bf(val - bf2f(hb));
        return;
    }
    if (b >= 21696) {
        int tid = (b - 21696) * 256 + t;   // 32768
        int bb = tid >> 14;
        int d = (tid >> 7) & 127;
        int e = tid & 127;
        Pt[((size_t)bb * 128 + e) * 128 + d] = P[tid];
        return;
    }
    const float* src;
    unsigned short* hi;
    unsigned short* lo;
    int lb;
    if (b < 16384)      { src = u_feat; hi = fuhi; lo = fulo; lb = b - 12288; }
    else if (b < 20480) { src = v_feat; hi = fvhi; lo = fvlo; lb = b - 16384; }
    else if (b < 20992) { src = Wu1; hi = wuhi; lo = wulo; lb = b - 20480; }
    else if (b < 21504) { src = Wv1; hi = wvhi; lo = wvlo; lb = b - 20992; }
    else if (b < 21600) { src = Wu2; hi = w2uhi; lo = w2ulo; lb = b - 21504; }
    else                { src = Wv2; hi = w2vhi; lo = w2vlo; lb = b - 21600; }
    size_t g = ((size_t)lb * 256 + t) * 4;
    float4 x = *(const float4*)(src + g);
    float f[4] = {x.x, x.y, x.z, x.w};
    unsigned short hh[4], ll[4];
    #pragma unroll
    for (int k = 0; k < 4; k++) {
        unsigned short hb = f2bf(f[k]);
        hh[k] = hb;
        ll[k] = f2bf(f[k] - bf2f(hb));
    }
    *(ushort4*)(hi + g) = make_ushort4(hh[0], hh[1], hh[2], hh[3]);
    *(ushort4*)(lo + g) = make_ushort4(ll[0], ll[1], ll[2], ll[3]);
}

// ---------------------------------------------------------------- k_l1F (split MFMA GEMM, LDS-staged B, both sides)
// cat[i][H0+n] = relu( sum_k A[rowmap[i]][k]*B[n][k] + bias[n] ), K=1024.
// B tile [64n][64k] hi+lo staged in LDS (pad to 72 elems), shared by 4 waves.
__global__ __launch_bounds__(256) void k_l1F(const unsigned short* __restrict__ fuhi,
                                             const unsigned short* __restrict__ fulo,
                                             const unsigned short* __restrict__ fvhi,
                                             const unsigned short* __restrict__ fvlo,
                                             const int* __restrict__ u,
                                             const int* __restrict__ v,
                                             const unsigned short* __restrict__ wuhi,
                                             const unsigned short* __restrict__ wulo,
                                             const unsigned short* __restrict__ wvhi,
                                             const unsigned short* __restrict__ wvlo,
                                             const float* __restrict__ bu1,
                                             const float* __restrict__ bv1,
                                             unsigned short* __restrict__ chiU,
                                             unsigned short* __restrict__ cloU,
                                             unsigned short* __restrict__ chiV,
                                             unsigned short* __restrict__ cloV) {
    __shared__ unsigned short Bh[64][72];
    __shared__ unsigned short Bl[64][72];
    int side = blockIdx.z;
    const unsigned short* Ahi = side ? fvhi : fuhi;
    const unsigned short* Alo = side ? fvlo : fulo;
    const int* rowmap = side ? v : u;
    const unsigned short* Bhi = side ? wvhi : wuhi;
    const unsigned short* Blo = side ? wvlo : wulo;
    const float* bias = side ? bv1 : bu1;
    unsigned short* CHi = (side ? chiV : chiU) + H0;
    unsigned short* CLo = (side ? cloV : cloU) + H0;

    int t = threadIdx.x;
    int wave = t >> 6, lane = t & 63;
    int lr = lane & 15;
    int lk = lane >> 4;
    int i0 = blockIdx.y * 64 + wave * 16;
    int n0 = blockIdx.x * 64;
    int gi = rowmap[i0 + lr];
    const unsigned short* pah = Ahi + (size_t)gi * SIDE;
    const unsigned short* pal = Alo + (size_t)gi * SIDE;
    int srow = t >> 2, sseg = (t & 3) * 16;
    floatx4 acc[4];
    #pragma unroll
    for (int jt = 0; jt < 4; jt++) acc[jt] = (floatx4){0.f, 0.f, 0.f, 0.f};
    for (int ks = 0; ks < SIDE / 64; ks++) {
        const unsigned short* sh = Bhi + (size_t)(n0 + srow) * SIDE + ks * 64 + sseg;
        const unsigned short* sl = Blo + (size_t)(n0 + srow) * SIDE + ks * 64 + sseg;
        __syncthreads();
        *(uint4*)(&Bh[srow][sseg]) = *(const uint4*)sh;
        *(uint4*)(&Bh[srow][sseg + 8]) = *(const uint4*)(sh + 8);
        *(uint4*)(&Bl[srow][sseg]) = *(const uint4*)sl;
        *(uint4*)(&Bl[srow][sseg + 8]) = *(const uint4*)(sl + 8);
        __syncthreads();
        #pragma unroll
        for (int kk = 0; kk < 2; kk++) {
            int ko = ks * 64 + kk * 32 + lk * 8;
            short8 ah = *(const short8*)(pah + ko);
            short8 al = *(const short8*)(pal + ko);
            #pragma unroll
            for (int jt = 0; jt < 4; jt++) {
                short8 bh = *(const short8*)(&Bh[jt * 16 + lr][kk * 32 + lk * 8]);
                short8 bl = *(const short8*)(&Bl[jt * 16 + lr][kk * 32 + lk * 8]);
                acc[jt] = __builtin_amdgcn_mfma_f32_16x16x32_bf16(ah, bh, acc[jt], 0, 0, 0);
                acc[jt] = __builtin_amdgcn_mfma_f32_16x16x32_bf16(ah, bl, acc[jt], 0, 0, 0);
                acc[jt] = __builtin_amdgcn_mfma_f32_16x16x32_bf16(al, bh, acc[jt], 0, 0, 0);
            }
        }
    }
    #pragma unroll
    for (int jt = 0; jt < 4; jt++) {
        int cn = n0 + jt * 16 + lr;
        float bb = bias[cn];
        #pragma unroll
        for (int r = 0; r < 4; r++) {
            int ci = i0 + lk * 4 + r;
            float vv = fmaxf(acc[jt][r] + bb, 0.f);
            unsigned short hb = f2bf(vv);
            CHi[(size_t)ci * HCAT + cn] = hb;
            CLo[(size_t)ci * HCAT + cn] = f2bf(vv - bf2f(hb));
        }
    }
}

// ---------------------------------------------------------------- k_l2F (split MFMA GEMM, LDS-staged B, both sides)
// z=0: uh (fp32); z=1: vhb (bf16). K=768, N=128.
__global__ __launch_bounds__(256) void k_l2F(const unsigned short* __restrict__ chiU,
                                             const unsigned short* __restrict__ cloU,
                                             const unsigned short* __restrict__ w2uhi,
                                             const unsigned short* __restrict__ w2ulo,
                                             float* __restrict__ uh,
                                             const unsigned short* __restrict__ chiV,
                                             const unsigned short* __restrict__ cloV,
                                             const unsigned short* __restrict__ w2vhi,
                                             const unsigned short* __restrict__ w2vlo,
                                             unsigned short* __restrict__ vhb) {
    __shared__ unsigned short Bh[64][72];
    __shared__ unsigned short Bl[64][72];
    int side = blockIdx.z;
    const unsigned short* Ahi = side ? chiV : chiU;
    const unsigned short* Alo = side ? cloV : cloU;
    const unsigned short* Bhi = side ? w2vhi : w2uhi;
    const unsigned short* Blo = side ? w2vlo : w2ulo;

    int t = threadIdx.x;
    int wave = t >> 6, lane = t & 63;
    int lr = lane & 15;
    int lk = lane >> 4;
    int i0 = blockIdx.y * 64 + wave * 16;
    int n0 = blockIdx.x * 64;
    const unsigned short* pah = Ahi + (size_t)(i0 + lr) * HCAT;
    const unsigned short* pal = Alo + (size_t)(i0 + lr) * HCAT;
    int srow = t >> 2, sseg = (t & 3) * 16;
    floatx4 acc[4];
    #pragma unroll
    for (int jt = 0; jt < 4; jt++) acc[jt] = (floatx4){0.f, 0.f, 0.f, 0.f};
    for (int ks = 0; ks < HCAT / 64; ks++) {
        const unsigned short* sh = Bhi + (size_t)(n0 + srow) * HCAT + ks * 64 + sseg;
        const unsigned short* sl = Blo + (size_t)(n0 + srow) * HCAT + ks * 64 + sseg;
        __syncthreads();
        *(uint4*)(&Bh[srow][sseg]) = *(const uint4*)sh;
        *(uint4*)(&Bh[srow][sseg + 8]) = *(const uint4*)(sh + 8);
        *(uint4*)(&Bl[srow][sseg]) = *(const uint4*)sl;
        *(uint4*)(&Bl[srow][sseg + 8]) = *(const uint4*)(sl + 8);
        __syncthreads();
        #pragma unroll
        for (int kk = 0; kk < 2; kk++) {
            int ko = ks * 64 + kk * 32 + lk * 8;
            short8 ah = *(const short8*)(pah + ko);
            short8 al = *(const short8*)(pal + ko);
            #pragma unroll
            for (int jt = 0; jt < 4; jt++) {
                short8 bh = *(const short8*)(&Bh[jt * 16 + lr][kk * 32 + lk * 8]);
                short8 bl = *(const short8*)(&Bl[jt * 16 + lr][kk * 32 + lk * 8]);
                acc[jt] = __builtin_amdgcn_mfma_f32_16x16x32_bf16(ah, bh, acc[jt], 0, 0, 0);
                acc[jt] = __builtin_amdgcn_mfma_f32_16x16x32_bf16(ah, bl, acc[jt], 0, 0, 0);
                acc[jt] = __builtin_amdgcn_mfma_f32_16x16x32_bf16(al, bh, acc[jt], 0, 0, 0);
            }
        }
    }
    #pragma unroll
    for (int jt = 0; jt < 4; jt++) {
        int cn = n0 + jt * 16 + lr;
        #pragma unroll
        for (int r = 0; r < 4; r++) {
            int ci = i0 + lk * 4 + r;
            float vv = fmaxf(acc[jt][r], 0.f);
            if (side) {
                vhb[(size_t)ci * H1 + cn] = f2bf(vv);
            } else {
                uh[(size_t)ci * H1 + cn] = vv;
            }
        }
    }
}

// ---------------------------------------------------------------- generic NT GEMM (fp32 in, bf16 out) — tb GEMM
template <int TM, int TN, int BK, int RM, int RN>
__global__ __launch_bounds__(256) void k_gemm(const float* __restrict__ A, int lda,
                                              const float* __restrict__ B, int ldb,
                                              float* __restrict__ C, int ldc, int K,
                                              size_t bzs, size_t czs) {
    constexpr int TX = TN / RN;
    constexpr int TY = TM / RM;
    static_assert(TX * TY == 256, "block must be 256");
    __shared__ float As[BK][TM + 4];
    __shared__ float Bs[BK][TN + 4];
    int tid = threadIdx.x;
    int tx = tid % TX, ty = tid / TX;
    int i0 = blockIdx.x * TM, n0 = blockIdx.y * TN;
    const float* Bz = B + (size_t)blockIdx.z * bzs;
    float acc[RM][RN] = {};
    for (int k0 = 0; k0 < K; k0 += BK) {
        for (int g = tid; g < TM * BK / 4; g += 256) {
            int i = g / (BK / 4), kc = g % (BK / 4);
            float4 val = *(const float4*)(A + (size_t)(i0 + i) * lda + k0 + kc * 4);
            As[kc * 4 + 0][i] = val.x; As[kc * 4 + 1][i] = val.y;
            As[kc * 4 + 2][i] = val.z; As[kc * 4 + 3][i] = val.w;
        }
        for (int g = tid; g < TN * BK / 4; g += 256) {
            int n = g / (BK / 4), kc = g % (BK / 4);
            float4 val = *(const float4*)(Bz + (size_t)(n0 + n) * ldb + k0 + kc * 4);
            Bs[kc * 4 + 0][n] = val.x; Bs[kc * 4 + 1][n] = val.y;
            Bs[kc * 4 + 2][n] = val.z; Bs[kc * 4 + 3][n] = val.w;
        }
        __syncthreads();
        #pragma unroll
        for (int k = 0; k < BK; k++) {
            float av[RM], bv[RN];
            #pragma unroll
            for (int m = 0; m < RM; m++) av[m] = As[k][ty * RM + m];
            #pragma unroll
            for (int n = 0; n < RN; n++) bv[n] = Bs[k][tx * RN + n];
            #pragma unroll
            for (int m = 0; m < RM; m++)
                #pragma unroll
                for (int n = 0; n < RN; n++)
                    acc[m][n] = fmaf(av[m], bv[n], acc[m][n]);
        }
        __syncthreads();
    }
    #pragma unroll
    for (int m = 0; m < RM; m++) {
        int ig = i0 + ty * RM + m;
        #pragma unroll
        for (int n = 0; n < RN; n++) {
            unsigned short* Cz16 = (unsigned short*)C + (size_t)blockIdx.z * czs;
            Cz16[(size_t)ig * ldc + n0 + tx * RN + n] = f2bf(acc[m][n]);
        }
    }
}

// ---------------------------------------------------------------- k_scores3 (MFMA bf16 decoder + softmax epilogue)
// v3: jt+1 B-fragments + codeR bytes prefetched before consuming jt (G7).
__global__ __launch_bounds__(256) void k_scores3(const unsigned short* __restrict__ tb,  // [2][4096][128] bf16
                                                 const unsigned short* __restrict__ vhb, // [4096][128] bf16
                                                 const uint8_t* __restrict__ codeR,
                                                 const float* __restrict__ a_f,          // [2][5]
                                                 float* __restrict__ mhat,
                                                 float* __restrict__ part) {
    __shared__ float wred[4][3];
    int t = threadIdx.x;
    int wave = t >> 6, lane = t & 63;
    int lr = lane & 15;          // A row / B col / C col
    int lk = lane >> 4;          // k-subgroup & C row-group
    int i0 = blockIdx.y * 64 + wave * 16;
    int j0 = blockIdx.x * 128;
    float sa0[NC], sa1[NC];
    #pragma unroll
    for (int c = 0; c < NC; c++) { sa0[c] = a_f[c]; sa1[c] = a_f[5 + c]; }

    const unsigned short* t0p = tb;
    const unsigned short* t1p = tb + (size_t)N4 * H1;
    short8 a0[4], a1[4];
    #pragma unroll
    for (int kc = 0; kc < 4; kc++) {
        size_t off = (size_t)(i0 + lr) * H1 + kc * 32 + lk * 8;
        a0[kc] = *(const short8*)(t0p + off);
        a1[kc] = *(const short8*)(t1p + off);
    }

    const uint8_t* crbase = codeR + (size_t)(i0 + lk * 4) * N4 + lr;
    short8 bcur[4];
    int cbv[4];
    {
        int jb = j0;
        const uint8_t* crp = crbase + jb;
        cbv[0] = crp[0];
        cbv[1] = crp[N4];
        cbv[2] = crp[2 * N4];
        cbv[3] = crp[3 * N4];
        #pragma unroll
        for (int kc = 0; kc < 4; kc++)
            bcur[kc] = *(const short8*)(vhb + (size_t)(jb + lr) * H1 + kc * 32 + lk * 8);
    }

    float lsum = 0.f, ssum = 0.f, nobs = 0.f;
    for (int jt = 0; jt < 8; jt++) {
        int jb = j0 + jt * 16;
        int j = jb + lr;
        short8 bnext[4];
        int cbn[4];
        if (jt < 7) {
            int jb2 = jb + 16;
            const uint8_t* crp = crbase + jb2;
            cbn[0] = crp[0];
            cbn[1] = crp[N4];
            cbn[2] = crp[2 * N4];
            cbn[3] = crp[3 * N4];
            #pragma unroll
            for (int kc = 0; kc < 4; kc++)
                bnext[kc] = *(const short8*)(vhb + (size_t)(jb2 + lr) * H1 + kc * 32 + lk * 8);
        }
        floatx4 C0 = {0.f, 0.f, 0.f, 0.f}, C1 = {0.f, 0.f, 0.f, 0.f};
        #pragma unroll
        for (int kc = 0; kc < 4; kc++) {
            C0 = __builtin_amdgcn_mfma_f32_16x16x32_bf16(a0[kc], bcur[kc], C0, 0, 0, 0);
            C1 = __builtin_amdgcn_mfma_f32_16x16x32_bf16(a1[kc], bcur[kc], C1, 0, 0, 0);
        }
        #pragma unroll
        for (int r = 0; r < 4; r++) {
            int i = i0 + lk * 4 + r;
            float v0 = C0[r], v1 = C1[r];
            float l[NC];
            float mx = -1e30f;
            #pragma unroll
            for (int c = 0; c < NC; c++) {
                l[c] = sa0[c] * v0 + sa1[c] * v1;
                mx = fmaxf(mx, l[c]);
            }
            float den = 0.f, num = 0.f;
            #pragma unroll
            for (int c = 0; c < NC; c++) {
                float e = __expf(l[c] - mx);
                den += e;
                num += (float)(c + 1) * e;
            }
            float mh = num / den;
            mhat[(size_t)i * N4 + j] = mh;
            int cb = cbv[r];
            if (cb) {
                float lse = mx + __logf(den);
                lsum += lse - l[cb - 1];        // = -logp[cb-1]
                float df = mh - (float)cb;
                ssum += df * df;
                nobs += 1.f;
            }
        }
        if (jt < 7) {
            #pragma unroll
            for (int kc = 0; kc < 4; kc++) bcur[kc] = bnext[kc];
            #pragma unroll
            for (int r = 0; r < 4; r++) cbv[r] = cbn[r];
        }
    }
    #pragma unroll
    for (int off = 32; off; off >>= 1) {
        lsum += __shfl_down(lsum, off, 64);
        ssum += __shfl_down(ssum, off, 64);
        nobs += __shfl_down(nobs, off, 64);
    }
    if (lane == 0) { wred[wave][0] = lsum; wred[wave][1] = ssum; wred[wave][2] = nobs; }
    __syncthreads();
    if (t == 0) {
        int bid = blockIdx.y * gridDim.x + blockIdx.x;
        part[bid * 3 + 0] = wred[0][0] + wred[1][0] + wred[2][0] + wred[3][0];
        part[bid * 3 + 1] = wred[0][1] + wred[1][1] + wred[2][1] + wred[3][1];
        part[bid * 3 + 2] = wred[0][2] + wred[1][2] + wred[2][2] + wred[3][2];
    }
}

// ---------------------------------------------------------------- k_finalize (reduce 2048 block partials)
__global__ __launch_bounds__(256) void k_finalize(const float* __restrict__ part,
                                                  float* __restrict__ out) {
    __shared__ float sred[3][4];
    int t = threadIdx.x, lane = t & 63, wv = t >> 6;
    float l = 0.f, s = 0.f, n = 0.f;
    for (int i = t; i < 2048; i += 256) {
        l += part[i * 3 + 0];
        s += part[i * 3 + 1];
        n += part[i * 3 + 2];
    }
    #pragma unroll
    for (int off = 32; off; off >>= 1) {
        l += __shfl_down(l, off, 64);
        s += __shfl_down(s, off, 64);
        n += __shfl_down(n, off, 64);
    }
    if (lane == 0) { sred[0][wv] = l; sred[1][wv] = s; sred[2][wv] = n; }
    __syncthreads();
    if (t == 0) {
        float L = sred[0][0] + sred[0][1] + sred[0][2] + sred[0][3];
        float S = sred[1][0] + sred[1][1] + sred[1][2] + sred[1][3];
        float N = fmaxf(sred[2][0] + sred[2][1] + sred[2][2] + sred[2][3], 1.f);
        out[NUV + 0] = L / N;
        out[NUV + 1] = sqrtf(S / N);
    }
}

// ================================================================ launch
extern "C" void kernel_launch(void* const* d_in, const int* in_sizes, int n_in,
                              void* d_out, int out_size, void* d_ws, size_t ws_size,
                              hipStream_t stream) {
    const int* u = (const int*)d_in[0];
    const int* v = (const int*)d_in[1];
    const float* adj    = (const float*)d_in[3];
    const float* u_feat = (const float*)d_in[4];
    const float* v_feat = (const float*)d_in[5];
    const float* u_w    = (const float*)d_in[6];
    const float* v_w    = (const float*)d_in[7];
    const float* Wu1    = (const float*)d_in[8];
    const float* bu1    = (const float*)d_in[9];
    const float* Wv1    = (const float*)d_in[10];
    const float* bv1    = (const float*)d_in[11];
    const float* Wu2    = (const float*)d_in[12];
    const float* Wv2    = (const float*)d_in[13];
    const float* P      = (const float*)d_in[14];
    const float* a      = (const float*)d_in[15];
    float* out = (float*)d_out;

    char* ws = (char*)d_ws;
    // workspace layout (bytes). Overlays:
    //  codeT on UCAT (dead after compactF); codeR on TAU+TBV (dead after gatherF);
    //  part on CNTU+CNTV (dead after compactF); fuhi/fulo on IDXU/IDXV (dead
    //  after gatherF); cat bf16 hi/lo planes on UCAT/VCAT.
    //  fv/W1/W2 splits live in d_out scratch (mhat fully overwritten by scores3).
    const size_t O_CODE  = 0;                         // 16,777,216 u8
    const size_t O_CNTU  = 16777216;                  // 16,384 i32
    const size_t O_CNTV  = O_CNTU + 16384;            // 16,384 i32
    const size_t O_ACC   = O_CNTV + 16384;            // 256 B (unused)
    const size_t O_TAU   = O_ACC + 256;               // 10,485,760 f16 table (u side)
    const size_t O_TBV   = O_TAU + 10485760;          // 10,485,760 f16 table (v side)
    const size_t O_IDXU  = O_TBV + 10485760;          // 12,582,912 u16 [4096][CAP]
    const size_t O_IDXV  = O_IDXU + 12582912;         // 12,582,912 u16
    const size_t O_NNZU  = O_IDXV + 12582912;         // 16,384 i32
    const size_t O_NNZV  = O_NNZU + 16384;            // 16,384 i32
    const size_t O_RDEG  = O_NNZV + 16384;            // 16,384 f32
    const size_t O_CDEG  = O_RDEG + 16384;            // 16,384 f32
    const size_t O_UNN   = O_CDEG + 16384;            // 4,194,304 f32
    const size_t O_VNN   = O_UNN + 4194304;           // 4,194,304 f32
    const size_t O_UCAT  = O_VNN + 4194304;           // 12,582,912 (bf16 hi+lo planes)
    const size_t O_VCAT  = O_UCAT + 12582912;         // 12,582,912
    const size_t O_UH    = O_VCAT + 12582912;         // 2,097,152 f32
    const size_t O_VHB   = O_UH + 2097152;            // 1,048,576 bf16 [4096][128]
    const size_t O_PT    = O_VHB + 1048576;           // 131,072 f32
    const size_t O_TB    = O_PT + 131072;             // 2,097,152 bf16 [2][4096][128]
    const size_t O_CODET = O_UCAT;                    // overlay
    const size_t O_CODER = O_TAU;                     // overlay (fits TAU+TBV)
    const size_t O_PART  = O_CNTU;                    // overlay (cnt dead after compact)
    const size_t O_FUHI  = O_IDXU;                    // overlay, 8,388,608
    const size_t O_FULO  = O_IDXV;                    // overlay, 8,388,608
    const size_t O_CHIU  = O_UCAT;                    // [4096][768] u16 hi
    const size_t O_CLOU  = O_UCAT + 6291456;          // [4096][768] u16 lo
    const size_t O_CHIV  = O_VCAT;
    const size_t O_CLOV  = O_VCAT + 6291456;
    // d_out scratch offsets (bytes within out; 67 MB available, ~22 MB used)
    const size_t S_FVHI  = 0;
    const size_t S_FVLO  = 8388608;
    const size_t S_WUHI  = 16777216;
    const size_t S_WULO  = S_WUHI + 1048576;
    const size_t S_WVHI  = S_WULO + 1048576;
    const size_t S_WVLO  = S_WVHI + 1048576;
    const size_t S_W2UHI = S_WVLO + 1048576;
    const size_t S_W2ULO = S_W2UHI + 196608;
    const size_t S_W2VHI = S_W2ULO + 196608;
    const size_t S_W2VLO = S_W2VHI + 196608;

    uint8_t* code  = (uint8_t*)(ws + O_CODE);
    uint8_t* codeT = (uint8_t*)(ws + O_CODET);
    uint8_t* codeR = (uint8_t*)(ws + O_CODER);
    int* cnt_u = (int*)(ws + O_CNTU);
    int* cnt_v = (int*)(ws + O_CNTV);
    unsigned short* T_Au = (unsigned short*)(ws + O_TAU);
    unsigned short* T_Bv = (unsigned short*)(ws + O_TBV);
    unsigned short* idxU = (unsigned short*)(ws + O_IDXU);
    unsigned short* idxV = (unsigned short*)(ws + O_IDXV);
    int* nnzU = (int*)(ws + O_NNZU);
    int* nnzV = (int*)(ws + O_NNZV);
    float* rowDeg = (float*)(ws + O_RDEG);
    float* colDeg = (float*)(ws + O_CDEG);
    float* u_nn = (float*)(ws + O_UNN);
    float* v_nn = (float*)(ws + O_VNN);
    float* uh = (float*)(ws + O_UH);
    unsigned short* vhb = (unsigned short*)(ws + O_VHB);
    float* Pt = (float*)(ws + O_PT);
    unsigned short* tb = (unsigned short*)(ws + O_TB);
    float* part = (float*)(ws + O_PART);
    unsigned short* fuhi = (unsigned short*)(ws + O_FUHI);
    unsigned short* fulo = (unsigned short*)(ws + O_FULO);
    unsigned short* chiU = (unsigned short*)(ws + O_CHIU);
    unsigned short* cloU = (unsigned short*)(ws + O_CLOU);
    unsigned short* chiV = (unsigned short*)(ws + O_CHIV);
    unsigned short* cloV = (unsigned short*)(ws + O_CLOV);
    char* outc = (char*)d_out;
    unsigned short* fvhi = (unsigned short*)(outc + S_FVHI);
    unsigned short* fvlo = (unsigned short*)(outc + S_FVLO);
    unsigned short* wuhi = (unsigned short*)(outc + S_WUHI);
    unsigned short* wulo = (unsigned short*)(outc + S_WULO);
    unsigned short* wvhi = (unsigned short*)(outc + S_WVHI);
    unsigned short* wvlo = (unsigned short*)(outc + S_WVLO);
    unsigned short* w2uhi = (unsigned short*)(outc + S_W2UHI);
    unsigned short* w2ulo = (unsigned short*)(outc + S_W2ULO);
    unsigned short* w2vhi = (unsigned short*)(outc + S_W2VHI);
    unsigned short* w2vlo = (unsigned short*)(outc + S_W2VLO);

    hipMemsetAsync(ws + O_CNTU, 0, 16384 + 16384, stream);

    k_codeF<<<16400, 256, 0, stream>>>(adj, (uchar4*)code, u, v, cnt_u, cnt_v);
    k_fuse0<<<12288, 256, 0, stream>>>(code, codeT, u_w, cnt_u, T_Au, v_w, cnt_v, T_Bv);
    k_compactF<<<dim3(N4, 2), 256, 0, stream>>>(code, codeT, cnt_u, cnt_v,
                                                idxU, nnzU, rowDeg, idxV, nnzV, colDeg);
    k_gatherF<<<dim3(N4, 2, 2), 256, 0, stream>>>(idxU, nnzU, T_Bv, u_nn,
                                                  idxV, nnzV, T_Au, v_nn);
    k_fuse1<<<21824, 256, 0, stream>>>(code, u, v, codeR, u_nn, v_nn, colDeg, rowDeg,
                                       chiU, cloU, chiV, cloV,
                                       u_feat, fuhi, fulo,
                                       v_feat, fvhi, fvlo,
                                       Wu1, wuhi, wulo, Wv1, wvhi, wvlo,
                                       Wu2, w2uhi, w2ulo, Wv2, w2vhi, w2vlo,
                                       P, Pt);
    k_l1F<<<dim3(8, 64, 2), 256, 0, stream>>>(fuhi, fulo, fvhi, fvlo, u, v,
                                              wuhi, wulo, wvhi, wvlo, bu1, bv1,
                                              chiU, cloU, chiV, cloV);
    k_l2F<<<dim3(2, 64, 2), 256, 0, stream>>>(chiU, cloU, w2uhi, w2ulo, uh,
                                              chiV, cloV, w2vhi, w2vlo, vhb);
    // t[b] = uh @ P[b] -> bf16
    k_gemm<64, 32, 16, 4, 2>
        <<<dim3(64, 4, 2), 256, 0, stream>>>(uh, H1, Pt, H1,
                                             (float*)tb, H1, H1,
                                             (size_t)H1 * H1, (size_t)N4 * H1);
    k_scores3<<<dim3(32, 64), 256, 0, stream>>>(tb, vhb, codeR, a, out, part);
    k_finalize<<<1, 256, 0, stream>>>(part, out);
}

// Round 8
// 881.837 us; speedup vs baseline: 1.3418x; 1.0113x over previous
//
#include <hip/hip_runtime.h>
#include <stdint.h>

// Problem constants
#define N4   4096
#define H0   256
#define SIDE 1024
#define DIN  512
#define HCAT 768      // H0 + DIN
#define H1   128
#define NC   5
#define NUV  16777216ULL   // 4096*4096
#define CAP  1536          // max compacted entries per row

typedef __attribute__((ext_vector_type(8))) short short8;    // 8 bf16
typedef __attribute__((ext_vector_type(4))) float floatx4;

__device__ __forceinline__ unsigned short f2bf(float f) {
    unsigned int u;
    __builtin_memcpy(&u, &f, 4);
    unsigned int r = (u + 0x7FFFu + ((u >> 16) & 1u)) >> 16;   // RNE
    return (unsigned short)r;
}

__device__ __forceinline__ float bf2f(unsigned short b) {
    unsigned int u = (unsigned int)b << 16;
    float f;
    __builtin_memcpy(&f, &u, 4);
    return f;
}

// ---------------------------------------------------------------- k_codeF: code + counts
// blocks [0,16384): code; [16384,16400): counts
__global__ __launch_bounds__(256) void k_codeF(const float* __restrict__ adj,
                                               uchar4* __restrict__ code4,
                                               const int* __restrict__ u,
                                               const int* __restrict__ v,
                                               int* __restrict__ cu,
                                               int* __restrict__ cv) {
    int b = blockIdx.x, t = threadIdx.x;
    if (b < 16384) {
        size_t g = (size_t)b * 256 + t;
        size_t base = g * 4;
        uchar4 out = {0, 0, 0, 0};
        #pragma unroll
        for (int c = 0; c < NC; c++) {
            float4 s = *(const float4*)(adj + (size_t)c * NUV + base);
            out.x = (s.x != 0.f) ? (unsigned char)(c + 1) : out.x;
            out.y = (s.y != 0.f) ? (unsigned char)(c + 1) : out.y;
            out.z = (s.z != 0.f) ? (unsigned char)(c + 1) : out.z;
            out.w = (s.w != 0.f) ? (unsigned char)(c + 1) : out.w;
        }
        code4[g] = out;
    } else {
        int i = (b - 16384) * 256 + t;   // 4096 threads
        atomicAdd(&cu[u[i]], 1);
        atomicAdd(&cv[v[i]], 1);
    }
}

// ---------------------------------------------------------------- k_fuse0: transpose + wcumsum x2
// blocks [0,4096): byte transpose 64x64 tile; [4096,12288): wcumsum (side by range)
__global__ __launch_bounds__(256) void k_fuse0(const uint8_t* __restrict__ code,
                                               uint8_t* __restrict__ codeT,
                                               const float* __restrict__ u_w,
                                               const int* __restrict__ cnt_u,
                                               unsigned short* __restrict__ T_Au,
                                               const float* __restrict__ v_w,
                                               const int* __restrict__ cnt_v,
                                               unsigned short* __restrict__ T_Bv) {
    __shared__ __align__(16) uint8_t tile[64][80];
    int b = blockIdx.x, t = threadIdx.x;
    if (b < 4096) {
        int bx = b & 63, by = b >> 6;
        int row = t >> 2;
        int seg = (t & 3) * 16;
        int p0 = by * 64, q0 = bx * 64;
        uint4 vdat = *(const uint4*)(code + (size_t)(p0 + row) * N4 + q0 + seg);
        *(uint4*)(&tile[row][seg]) = vdat;
        __syncthreads();
        union { uint4 u4; uint8_t bb[16]; } o;
        #pragma unroll
        for (int l = 0; l < 16; l++) o.bb[l] = tile[seg + l][row];
        *(uint4*)(codeT + (size_t)(q0 + row) * N4 + p0 + seg) = o.u4;
    } else {
        int node = (b - 4096) & 4095;
        int side = (b - 4096) >> 12;       // 0: u-table, 1: v-table
        const float* w = side ? v_w : u_w;
        const int* cnt = side ? cnt_v : cnt_u;
        unsigned short* out = side ? T_Bv : T_Au;
        int h = t;
        float c = (float)cnt[node];
        float acc = 0.f;
        #pragma unroll
        for (int r = 0; r < NC; r++) {
            size_t idx = ((size_t)r * N4 + node) * H0 + h;
            acc += w[idx];
            union { _Float16 h16; unsigned short s; } cvt;
            cvt.h16 = (_Float16)(acc * c);
            out[idx] = cvt.s;
        }
    }
}

// ---------------------------------------------------------------- k_compactF (both sides; y = side)
__global__ __launch_bounds__(256) void k_compactF(const uint8_t* __restrict__ code,
                                                  const uint8_t* __restrict__ codeT,
                                                  const int* __restrict__ cnt_u,
                                                  const int* __restrict__ cnt_v,
                                                  unsigned short* __restrict__ idxU,
                                                  int* __restrict__ nnzU,
                                                  float* __restrict__ rowDeg,
                                                  unsigned short* __restrict__ idxV,
                                                  int* __restrict__ nnzV,
                                                  float* __restrict__ colDeg) {
    __shared__ float cw[4096];
    __shared__ int wtot[4];
    __shared__ float wdeg[4];
    __shared__ __align__(16) unsigned short ebuf[CAP];
    int side = blockIdx.y;
    const uint8_t* codeRows = side ? codeT : code;
    const int* cntOther = side ? cnt_u : cnt_v;
    unsigned short* idx = side ? idxV : idxU;
    int* nnz = side ? nnzV : nnzU;
    float* deg = side ? colDeg : rowDeg;

    int p = blockIdx.x, t = threadIdx.x;
    int lane = t & 63, wv = t >> 6;
    const int4* co4 = (const int4*)cntOther;
    #pragma unroll
    for (int l = 0; l < 4; l++) {
        int4 ci = co4[t + l * 256];
        ((float4*)cw)[t + l * 256] =
            make_float4((float)ci.x, (float)ci.y, (float)ci.z, (float)ci.w);
    }
    uint4 w = ((const uint4*)(codeRows + (size_t)p * N4))[t];
    unsigned char b[16];
    __builtin_memcpy(b, &w, 16);
    int cnt = 0;
    #pragma unroll
    for (int j = 0; j < 16; j++) cnt += (b[j] != 0);
    int sc = cnt;
    #pragma unroll
    for (int off = 1; off < 64; off <<= 1) {
        int up = __shfl_up(sc, off, 64);
        if (lane >= off) sc += up;
    }
    if (lane == 63) wtot[wv] = sc;
    __syncthreads();            // covers cw + wtot
    int wbase = 0;
    #pragma unroll
    for (int ww = 0; ww < 4; ww++) wbase += (ww < wv) ? wtot[ww] : 0;
    int total = wtot[0] + wtot[1] + wtot[2] + wtot[3];
    int pos = wbase + sc - cnt;   // block-exclusive prefix
    float dsum = 0.f;
    #pragma unroll
    for (int j = 0; j < 16; j++) {
        int r = b[j];
        if (r) {
            int q = t * 16 + j;
            if (pos < CAP) ebuf[pos] = (unsigned short)((r - 1) * N4 + q);
            pos++;
            dsum += cw[q];
        }
    }
    #pragma unroll
    for (int off = 32; off; off >>= 1) dsum += __shfl_down(dsum, off, 64);
    if (lane == 0) wdeg[wv] = dsum;
    __syncthreads();            // covers ebuf + wdeg
    int tw = total < CAP ? total : CAP;
    if (t == 0) { deg[p] = wdeg[0] + wdeg[1] + wdeg[2] + wdeg[3]; nnz[p] = tw; }
    for (int e = t; e < tw; e += 256) idx[(size_t)p * CAP + e] = ebuf[e];
}

// ---------------------------------------------------------------- k_gatherE
// v6: epoch-tiled for L2 residency. Entries are q-sorted within each row
// (q = idx & 4095); epoch e covers q in [e*1024,(e+1)*1024) -> per-side table
// slice = 2.5 MB, fits each XCD's 4 MB L2. Grid ordered side-major,
// epoch-next so co-resident blocks share one slice (perf heuristic only).
// Output: epoch partials pnn[side][epoch][p][256] (f32), summed in fuse1's z.
__global__ __launch_bounds__(256) void k_gatherE(const unsigned short* __restrict__ idxU,
                                                 const int* __restrict__ nnzU,
                                                 const unsigned short* __restrict__ T_Bv,
                                                 const unsigned short* __restrict__ idxV,
                                                 const int* __restrict__ nnzV,
                                                 const unsigned short* __restrict__ T_Au,
                                                 float* __restrict__ pnn) {
    __shared__ __align__(16) unsigned short sidx[CAP];
    __shared__ float red[16][132];
    __shared__ int sbnd[2];
    int bid = blockIdx.x;
    int side  = bid >> 15;
    int r1    = bid & 32767;
    int epoch = r1 >> 13;
    int r2    = r1 & 8191;
    int p     = r2 >> 1;
    int half  = r2 & 1;

    const unsigned short* idx = side ? idxV : idxU;
    const int* nnz = side ? nnzV : nnzU;
    const char* tb = (const char*)(side ? T_Au : T_Bv);

    int t = threadIdx.x;
    int n = nnz[p];
    const unsigned short* rowIdx = idx + (size_t)p * CAP;
    int nv = (n + 7) >> 3;
    for (int i = t; i < nv; i += 256)
        ((uint4*)sidx)[i] = ((const uint4*)rowIdx)[i];
    __syncthreads();
    // binary search epoch bounds: first i with q >= qlo / qhi
    if (t < 2) {
        int target = (epoch + t) << 10;
        int lo = 0, hi = n;
        while (lo < hi) {
            int mid = (lo + hi) >> 1;
            int q = sidx[mid] & 4095;
            if (q < target) lo = mid + 1; else hi = mid;
        }
        sbnd[t] = lo;
    }
    __syncthreads();
    int elo = sbnd[0], ehi = sbnd[1];

    int s = t >> 4;        // entry slot 0..15
    int c = t & 15;        // 16B segment within half-row
    int boff = half * 256 + c * 16;
    float acc[8] = {0.f, 0.f, 0.f, 0.f, 0.f, 0.f, 0.f, 0.f};
    int cnt = ehi - elo;
    int nmain = elo + (cnt & ~63);
    for (int e = elo + s; e < nmain; e += 64) {
        int o0 = ((int)sidx[e])      << 9;
        int o1 = ((int)sidx[e + 16]) << 9;
        int o2 = ((int)sidx[e + 32]) << 9;
        int o3 = ((int)sidx[e + 48]) << 9;
        uint4 d0 = *(const uint4*)(tb + o0 + boff);
        uint4 d1 = *(const uint4*)(tb + o1 + boff);
        uint4 d2 = *(const uint4*)(tb + o2 + boff);
        uint4 d3 = *(const uint4*)(tb + o3 + boff);
        union { uint4 u; _Float16 h[8]; } cv;
        cv.u = d0;
        #pragma unroll
        for (int k = 0; k < 8; k++) acc[k] += (float)cv.h[k];
        cv.u = d1;
        #pragma unroll
        for (int k = 0; k < 8; k++) acc[k] += (float)cv.h[k];
        cv.u = d2;
        #pragma unroll
        for (int k = 0; k < 8; k++) acc[k] += (float)cv.h[k];
        cv.u = d3;
        #pragma unroll
        for (int k = 0; k < 8; k++) acc[k] += (float)cv.h[k];
    }
    for (int e = nmain + s; e < ehi; e += 16) {
        int o = ((int)sidx[e]) << 9;
        uint4 d = *(const uint4*)(tb + o + boff);
        union { uint4 u; _Float16 h[8]; } cv;
        cv.u = d;
        #pragma unroll
        for (int k = 0; k < 8; k++) acc[k] += (float)cv.h[k];
    }
    #pragma unroll
    for (int k = 0; k < 8; k++) red[s][c * 8 + k] = acc[k];
    __syncthreads();
    if (t < 128) {
        float sum = 0.f;
        #pragma unroll
        for (int ss = 0; ss < 16; ss++) sum += red[ss][t];
        pnn[(((size_t)(side * 4 + epoch)) * N4 + p) * H0 + half * 128 + t] = sum;
    }
}

// ---------------------------------------------------------------- k_fuse1: reorder + z x2 + ALL splits + Pt
// [0,4096): reorder; [4096,12288): z (sums 4 epoch partials); [12288,16384):
// split u_feat; [16384,20480): split v_feat; [20480,20992): Wu1;
// [20992,21504): Wv1; [21504,21600): Wu2; [21600,21696): Wv2; [21696,21824): Pt.
__global__ __launch_bounds__(256) void k_fuse1(const uint8_t* __restrict__ code,
                                               const int* __restrict__ u,
                                               const int* __restrict__ v,
                                               uint8_t* __restrict__ codeR,
                                               const float* __restrict__ pnn,
                                               const float* __restrict__ colDeg,
                                               const float* __restrict__ rowDeg,
                                               unsigned short* __restrict__ chiU,
                                               unsigned short* __restrict__ cloU,
                                               unsigned short* __restrict__ chiV,
                                               unsigned short* __restrict__ cloV,
                                               const float* __restrict__ u_feat,
                                               unsigned short* __restrict__ fuhi,
                                               unsigned short* __restrict__ fulo,
                                               const float* __restrict__ v_feat,
                                               unsigned short* __restrict__ fvhi,
                                               unsigned short* __restrict__ fvlo,
                                               const float* __restrict__ Wu1,
                                               unsigned short* __restrict__ wuhi,
                                               unsigned short* __restrict__ wulo,
                                               const float* __restrict__ Wv1,
                                               unsigned short* __restrict__ wvhi,
                                               unsigned short* __restrict__ wvlo,
                                               const float* __restrict__ Wu2,
                                               unsigned short* __restrict__ w2uhi,
                                               unsigned short* __restrict__ w2ulo,
                                               const float* __restrict__ Wv2,
                                               unsigned short* __restrict__ w2vhi,
                                               unsigned short* __restrict__ w2vlo,
                                               const float* __restrict__ P,
                                               float* __restrict__ Pt) {
    __shared__ __align__(16) uint8_t rowbuf[4096];
    int b = blockIdx.x, t = threadIdx.x;
    if (b < 4096) {
        int i = b;
        int urow = u[i];
        ((uint4*)rowbuf)[t] = ((const uint4*)(code + (size_t)urow * N4))[t];
        __syncthreads();
        uint8_t ob[16];
        #pragma unroll
        for (int w = 0; w < 4; w++) {
            int4 vv = ((const int4*)v)[t * 4 + w];
            ob[w * 4 + 0] = rowbuf[vv.x];
            ob[w * 4 + 1] = rowbuf[vv.y];
            ob[w * 4 + 2] = rowbuf[vv.z];
            ob[w * 4 + 3] = rowbuf[vv.w];
        }
        uint4 o;
        __builtin_memcpy(&o, ob, 16);
        ((uint4*)(codeR + (size_t)i * N4))[t] = o;
        return;
    }
    if (b < 12288) {
        int i = (b - 4096) & 4095;
        int side = (b - 4096) >> 12;       // 0: u, 1: v
        const int* idxs = side ? v : u;
        const int* idxo = side ? u : v;
        const float* deg = side ? rowDeg : colDeg;
        unsigned short* catHi = side ? chiV : chiU;
        unsigned short* catLo = side ? cloV : cloU;
        int h = t;
        float d = deg[idxo[i]];
        float inv = d > 0.f ? 1.f / d : 0.f;
        int row = idxs[i];
        const float* pr = pnn + ((size_t)side * 4 * N4 + row) * H0 + h;
        float nnv = 0.f;
        #pragma unroll
        for (int e = 0; e < 4; e++) nnv += pr[(size_t)e * N4 * H0];
        float val = fmaxf(nnv * inv, 0.f);
        unsigned short hb = f2bf(val);
        catHi[(size_t)i * HCAT + h] = hb;
        catLo[(size_t)i * HCAT + h] = f2bf(val - bf2f(hb));
        return;
    }
    if (b >= 21696) {
        int tid = (b - 21696) * 256 + t;   // 32768
        int bb = tid >> 14;
        int d = (tid >> 7) & 127;
        int e = tid & 127;
        Pt[((size_t)bb * 128 + e) * 128 + d] = P[tid];
        return;
    }
    const float* src;
    unsigned short* hi;
    unsigned short* lo;
    int lb;
    if (b < 16384)      { src = u_feat; hi = fuhi; lo = fulo; lb = b - 12288; }
    else if (b < 20480) { src = v_feat; hi = fvhi; lo = fvlo; lb = b - 16384; }
    else if (b < 20992) { src = Wu1; hi = wuhi; lo = wulo; lb = b - 20480; }
    else if (b < 21504) { src = Wv1; hi = wvhi; lo = wvlo; lb = b - 20992; }
    else if (b < 21600) { src = Wu2; hi = w2uhi; lo = w2ulo; lb = b - 21504; }
    else                { src = Wv2; hi = w2vhi; lo = w2vlo; lb = b - 21600; }
    size_t g = ((size_t)lb * 256 + t) * 4;
    float4 x = *(const float4*)(src + g);
    float f[4] = {x.x, x.y, x.z, x.w};
    unsigned short hh[4], ll[4];
    #pragma unroll
    for (int k = 0; k < 4; k++) {
        unsigned short hb = f2bf(f[k]);
        hh[k] = hb;
        ll[k] = f2bf(f[k] - bf2f(hb));
    }
    *(ushort4*)(hi + g) = make_ushort4(hh[0], hh[1], hh[2], hh[3]);
    *(ushort4*)(lo + g) = make_ushort4(ll[0], ll[1], ll[2], ll[3]);
}

// ---------------------------------------------------------------- k_l1F (split MFMA GEMM, LDS-staged B, both sides)
__global__ __launch_bounds__(256) void k_l1F(const unsigned short* __restrict__ fuhi,
                                             const unsigned short* __restrict__ fulo,
                                             const unsigned short* __restrict__ fvhi,
                                             const unsigned short* __restrict__ fvlo,
                                             const int* __restrict__ u,
                                             const int* __restrict__ v,
                                             const unsigned short* __restrict__ wuhi,
                                             const unsigned short* __restrict__ wulo,
                                             const unsigned short* __restrict__ wvhi,
                                             const unsigned short* __restrict__ wvlo,
                                             const float* __restrict__ bu1,
                                             const float* __restrict__ bv1,
                                             unsigned short* __restrict__ chiU,
                                             unsigned short* __restrict__ cloU,
                                             unsigned short* __restrict__ chiV,
                                             unsigned short* __restrict__ cloV) {
    __shared__ __align__(16) unsigned short Bh[64][72];
    __shared__ __align__(16) unsigned short Bl[64][72];
    int side = blockIdx.z;
    const unsigned short* Ahi = side ? fvhi : fuhi;
    const unsigned short* Alo = side ? fvlo : fulo;
    const int* rowmap = side ? v : u;
    const unsigned short* Bhi = side ? wvhi : wuhi;
    const unsigned short* Blo = side ? wvlo : wulo;
    const float* bias = side ? bv1 : bu1;
    unsigned short* CHi = (side ? chiV : chiU) + H0;
    unsigned short* CLo = (side ? cloV : cloU) + H0;

    int t = threadIdx.x;
    int wave = t >> 6, lane = t & 63;
    int lr = lane & 15;
    int lk = lane >> 4;
    int i0 = blockIdx.y * 64 + wave * 16;
    int n0 = blockIdx.x * 64;
    int gi = rowmap[i0 + lr];
    const unsigned short* pah = Ahi + (size_t)gi * SIDE;
    const unsigned short* pal = Alo + (size_t)gi * SIDE;
    int srow = t >> 2, sseg = (t & 3) * 16;
    floatx4 acc[4];
    #pragma unroll
    for (int jt = 0; jt < 4; jt++) acc[jt] = (floatx4){0.f, 0.f, 0.f, 0.f};
    for (int ks = 0; ks < SIDE / 64; ks++) {
        const unsigned short* sh = Bhi + (size_t)(n0 + srow) * SIDE + ks * 64 + sseg;
        const unsigned short* sl = Blo + (size_t)(n0 + srow) * SIDE + ks * 64 + sseg;
        __syncthreads();
        *(uint4*)(&Bh[srow][sseg]) = *(const uint4*)sh;
        *(uint4*)(&Bh[srow][sseg + 8]) = *(const uint4*)(sh + 8);
        *(uint4*)(&Bl[srow][sseg]) = *(const uint4*)sl;
        *(uint4*)(&Bl[srow][sseg + 8]) = *(const uint4*)(sl + 8);
        __syncthreads();
        #pragma unroll
        for (int kk = 0; kk < 2; kk++) {
            int ko = ks * 64 + kk * 32 + lk * 8;
            short8 ah = *(const short8*)(pah + ko);
            short8 al = *(const short8*)(pal + ko);
            #pragma unroll
            for (int jt = 0; jt < 4; jt++) {
                short8 bh = *(const short8*)(&Bh[jt * 16 + lr][kk * 32 + lk * 8]);
                short8 bl = *(const short8*)(&Bl[jt * 16 + lr][kk * 32 + lk * 8]);
                acc[jt] = __builtin_amdgcn_mfma_f32_16x16x32_bf16(ah, bh, acc[jt], 0, 0, 0);
                acc[jt] = __builtin_amdgcn_mfma_f32_16x16x32_bf16(ah, bl, acc[jt], 0, 0, 0);
                acc[jt] = __builtin_amdgcn_mfma_f32_16x16x32_bf16(al, bh, acc[jt], 0, 0, 0);
            }
        }
    }
    #pragma unroll
    for (int jt = 0; jt < 4; jt++) {
        int cn = n0 + jt * 16 + lr;
        float bb = bias[cn];
        #pragma unroll
        for (int r = 0; r < 4; r++) {
            int ci = i0 + lk * 4 + r;
            float vv = fmaxf(acc[jt][r] + bb, 0.f);
            unsigned short hb = f2bf(vv);
            CHi[(size_t)ci * HCAT + cn] = hb;
            CLo[(size_t)ci * HCAT + cn] = f2bf(vv - bf2f(hb));
        }
    }
}

// ---------------------------------------------------------------- k_l2F (split MFMA GEMM, LDS-staged B, both sides)
__global__ __launch_bounds__(256) void k_l2F(const unsigned short* __restrict__ chiU,
                                             const unsigned short* __restrict__ cloU,
                                             const unsigned short* __restrict__ w2uhi,
                                             const unsigned short* __restrict__ w2ulo,
                                             float* __restrict__ uh,
                                             const unsigned short* __restrict__ chiV,
                                             const unsigned short* __restrict__ cloV,
                                             const unsigned short* __restrict__ w2vhi,
                                             const unsigned short* __restrict__ w2vlo,
                                             unsigned short* __restrict__ vhb) {
    __shared__ __align__(16) unsigned short Bh[64][72];
    __shared__ __align__(16) unsigned short Bl[64][72];
    int side = blockIdx.z;
    const unsigned short* Ahi = side ? chiV : chiU;
    const unsigned short* Alo = side ? cloV : cloU;
    const unsigned short* Bhi = side ? w2vhi : w2uhi;
    const unsigned short* Blo = side ? w2vlo : w2ulo;

    int t = threadIdx.x;
    int wave = t >> 6, lane = t & 63;
    int lr = lane & 15;
    int lk = lane >> 4;
    int i0 = blockIdx.y * 64 + wave * 16;
    int n0 = blockIdx.x * 64;
    const unsigned short* pah = Ahi + (size_t)(i0 + lr) * HCAT;
    const unsigned short* pal = Alo + (size_t)(i0 + lr) * HCAT;
    int srow = t >> 2, sseg = (t & 3) * 16;
    floatx4 acc[4];
    #pragma unroll
    for (int jt = 0; jt < 4; jt++) acc[jt] = (floatx4){0.f, 0.f, 0.f, 0.f};
    for (int ks = 0; ks < HCAT / 64; ks++) {
        const unsigned short* sh = Bhi + (size_t)(n0 + srow) * HCAT + ks * 64 + sseg;
        const unsigned short* sl = Blo + (size_t)(n0 + srow) * HCAT + ks * 64 + sseg;
        __syncthreads();
        *(uint4*)(&Bh[srow][sseg]) = *(const uint4*)sh;
        *(uint4*)(&Bh[srow][sseg + 8]) = *(const uint4*)(sh + 8);
        *(uint4*)(&Bl[srow][sseg]) = *(const uint4*)sl;
        *(uint4*)(&Bl[srow][sseg + 8]) = *(const uint4*)(sl + 8);
        __syncthreads();
        #pragma unroll
        for (int kk = 0; kk < 2; kk++) {
            int ko = ks * 64 + kk * 32 + lk * 8;
            short8 ah = *(const short8*)(pah + ko);
            short8 al = *(const short8*)(pal + ko);
            #pragma unroll
            for (int jt = 0; jt < 4; jt++) {
                short8 bh = *(const short8*)(&Bh[jt * 16 + lr][kk * 32 + lk * 8]);
                short8 bl = *(const short8*)(&Bl[jt * 16 + lr][kk * 32 + lk * 8]);
                acc[jt] = __builtin_amdgcn_mfma_f32_16x16x32_bf16(ah, bh, acc[jt], 0, 0, 0);
                acc[jt] = __builtin_amdgcn_mfma_f32_16x16x32_bf16(ah, bl, acc[jt], 0, 0, 0);
                acc[jt] = __builtin_amdgcn_mfma_f32_16x16x32_bf16(al, bh, acc[jt], 0, 0, 0);
            }
        }
    }
    #pragma unroll
    for (int jt = 0; jt < 4; jt++) {
        int cn = n0 + jt * 16 + lr;
        #pragma unroll
        for (int r = 0; r < 4; r++) {
            int ci = i0 + lk * 4 + r;
            float vv = fmaxf(acc[jt][r], 0.f);
            if (side) {
                vhb[(size_t)ci * H1 + cn] = f2bf(vv);
            } else {
                uh[(size_t)ci * H1 + cn] = vv;
            }
        }
    }
}

// ---------------------------------------------------------------- generic NT GEMM (fp32 in, bf16 out) — tb GEMM
template <int TM, int TN, int BK, int RM, int RN>
__global__ __launch_bounds__(256) void k_gemm(const float* __restrict__ A, int lda,
                                              const float* __restrict__ B, int ldb,
                                              float* __restrict__ C, int ldc, int K,
                                              size_t bzs, size_t czs) {
    constexpr int TX = TN / RN;
    constexpr int TY = TM / RM;
    static_assert(TX * TY == 256, "block must be 256");
    __shared__ float As[BK][TM + 4];
    __shared__ float Bs[BK][TN + 4];
    int tid = threadIdx.x;
    int tx = tid % TX, ty = tid / TX;
    int i0 = blockIdx.x * TM, n0 = blockIdx.y * TN;
    const float* Bz = B + (size_t)blockIdx.z * bzs;
    float acc[RM][RN] = {};
    for (int k0 = 0; k0 < K; k0 += BK) {
        for (int g = tid; g < TM * BK / 4; g += 256) {
            int i = g / (BK / 4), kc = g % (BK / 4);
            float4 val = *(const float4*)(A + (size_t)(i0 + i) * lda + k0 + kc * 4);
            As[kc * 4 + 0][i] = val.x; As[kc * 4 + 1][i] = val.y;
            As[kc * 4 + 2][i] = val.z; As[kc * 4 + 3][i] = val.w;
        }
        for (int g = tid; g < TN * BK / 4; g += 256) {
            int n = g / (BK / 4), kc = g % (BK / 4);
            float4 val = *(const float4*)(Bz + (size_t)(n0 + n) * ldb + k0 + kc * 4);
            Bs[kc * 4 + 0][n] = val.x; Bs[kc * 4 + 1][n] = val.y;
            Bs[kc * 4 + 2][n] = val.z; Bs[kc * 4 + 3][n] = val.w;
        }
        __syncthreads();
        #pragma unroll
        for (int k = 0; k < BK; k++) {
            float av[RM], bv[RN];
            #pragma unroll
            for (int m = 0; m < RM; m++) av[m] = As[k][ty * RM + m];
            #pragma unroll
            for (int n = 0; n < RN; n++) bv[n] = Bs[k][tx * RN + n];
            #pragma unroll
            for (int m = 0; m < RM; m++)
                #pragma unroll
                for (int n = 0; n < RN; n++)
                    acc[m][n] = fmaf(av[m], bv[n], acc[m][n]);
        }
        __syncthreads();
    }
    #pragma unroll
    for (int m = 0; m < RM; m++) {
        int ig = i0 + ty * RM + m;
        #pragma unroll
        for (int n = 0; n < RN; n++) {
            unsigned short* Cz16 = (unsigned short*)C + (size_t)blockIdx.z * czs;
            Cz16[(size_t)ig * ldc + n0 + tx * RN + n] = f2bf(acc[m][n]);
        }
    }
}

// ---------------------------------------------------------------- k_scores3 (MFMA bf16 decoder + softmax epilogue)
// v3: jt+1 B-fragments + codeR bytes prefetched before consuming jt (G7).
__global__ __launch_bounds__(256) void k_scores3(const unsigned short* __restrict__ tb,  // [2][4096][128] bf16
                                                 const unsigned short* __restrict__ vhb, // [4096][128] bf16
                                                 const uint8_t* __restrict__ codeR,
                                                 const float* __restrict__ a_f,          // [2][5]
                                                 float* __restrict__ mhat,
                                                 float* __restrict__ part) {
    __shared__ float wred[4][3];
    int t = threadIdx.x;
    int wave = t >> 6, lane = t & 63;
    int lr = lane & 15;          // A row / B col / C col
    int lk = lane >> 4;          // k-subgroup & C row-group
    int i0 = blockIdx.y * 64 + wave * 16;
    int j0 = blockIdx.x * 128;
    float sa0[NC], sa1[NC];
    #pragma unroll
    for (int c = 0; c < NC; c++) { sa0[c] = a_f[c]; sa1[c] = a_f[5 + c]; }

    const unsigned short* t0p = tb;
    const unsigned short* t1p = tb + (size_t)N4 * H1;
    short8 a0[4], a1[4];
    #pragma unroll
    for (int kc = 0; kc < 4; kc++) {
        size_t off = (size_t)(i0 + lr) * H1 + kc * 32 + lk * 8;
        a0[kc] = *(const short8*)(t0p + off);
        a1[kc] = *(const short8*)(t1p + off);
    }

    const uint8_t* crbase = codeR + (size_t)(i0 + lk * 4) * N4 + lr;
    short8 bcur[4];
    int cbv[4];
    {
        int jb = j0;
        const uint8_t* crp = crbase + jb;
        cbv[0] = crp[0];
        cbv[1] = crp[N4];
        cbv[2] = crp[2 * N4];
        cbv[3] = crp[3 * N4];
        #pragma unroll
        for (int kc = 0; kc < 4; kc++)
            bcur[kc] = *(const short8*)(vhb + (size_t)(jb + lr) * H1 + kc * 32 + lk * 8);
    }

    float lsum = 0.f, ssum = 0.f, nobs = 0.f;
    for (int jt = 0; jt < 8; jt++) {
        int jb = j0 + jt * 16;
        int j = jb + lr;
        short8 bnext[4];
        int cbn[4];
        if (jt < 7) {
            int jb2 = jb + 16;
            const uint8_t* crp = crbase + jb2;
            cbn[0] = crp[0];
            cbn[1] = crp[N4];
            cbn[2] = crp[2 * N4];
            cbn[3] = crp[3 * N4];
            #pragma unroll
            for (int kc = 0; kc < 4; kc++)
                bnext[kc] = *(const short8*)(vhb + (size_t)(jb2 + lr) * H1 + kc * 32 + lk * 8);
        }
        floatx4 C0 = {0.f, 0.f, 0.f, 0.f}, C1 = {0.f, 0.f, 0.f, 0.f};
        #pragma unroll
        for (int kc = 0; kc < 4; kc++) {
            C0 = __builtin_amdgcn_mfma_f32_16x16x32_bf16(a0[kc], bcur[kc], C0, 0, 0, 0);
            C1 = __builtin_amdgcn_mfma_f32_16x16x32_bf16(a1[kc], bcur[kc], C1, 0, 0, 0);
        }
        #pragma unroll
        for (int r = 0; r < 4; r++) {
            int i = i0 + lk * 4 + r;
            float v0 = C0[r], v1 = C1[r];
            float l[NC];
            float mx = -1e30f;
            #pragma unroll
            for (int c = 0; c < NC; c++) {
                l[c] = sa0[c] * v0 + sa1[c] * v1;
                mx = fmaxf(mx, l[c]);
            }
            float den = 0.f, num = 0.f;
            #pragma unroll
            for (int c = 0; c < NC; c++) {
                float e = __expf(l[c] - mx);
                den += e;
                num += (float)(c + 1) * e;
            }
            float mh = num / den;
            mhat[(size_t)i * N4 + j] = mh;
            int cb = cbv[r];
            if (cb) {
                float lse = mx + __logf(den);
                lsum += lse - l[cb - 1];        // = -logp[cb-1]
                float df = mh - (float)cb;
                ssum += df * df;
                nobs += 1.f;
            }
        }
        if (jt < 7) {
            #pragma unroll
            for (int kc = 0; kc < 4; kc++) bcur[kc] = bnext[kc];
            #pragma unroll
            for (int r = 0; r < 4; r++) cbv[r] = cbn[r];
        }
    }
    #pragma unroll
    for (int off = 32; off; off >>= 1) {
        lsum += __shfl_down(lsum, off, 64);
        ssum += __shfl_down(ssum, off, 64);
        nobs += __shfl_down(nobs, off, 64);
    }
    if (lane == 0) { wred[wave][0] = lsum; wred[wave][1] = ssum; wred[wave][2] = nobs; }
    __syncthreads();
    if (t == 0) {
        int bid = blockIdx.y * gridDim.x + blockIdx.x;
        part[bid * 3 + 0] = wred[0][0] + wred[1][0] + wred[2][0] + wred[3][0];
        part[bid * 3 + 1] = wred[0][1] + wred[1][1] + wred[2][1] + wred[3][1];
        part[bid * 3 + 2] = wred[0][2] + wred[1][2] + wred[2][2] + wred[3][2];
    }
}

// ---------------------------------------------------------------- k_finalize (reduce 2048 block partials)
__global__ __launch_bounds__(256) void k_finalize(const float* __restrict__ part,
                                                  float* __restrict__ out) {
    __shared__ float sred[3][4];
    int t = threadIdx.x, lane = t & 63, wv = t >> 6;
    float l = 0.f, s = 0.f, n = 0.f;
    for (int i = t; i < 2048; i += 256) {
        l += part[i * 3 + 0];
        s += part[i * 3 + 1];
        n += part[i * 3 + 2];
    }
    #pragma unroll
    for (int off = 32; off; off >>= 1) {
        l += __shfl_down(l, off, 64);
        s += __shfl_down(s, off, 64);
        n += __shfl_down(n, off, 64);
    }
    if (lane == 0) { sred[0][wv] = l; sred[1][wv] = s; sred[2][wv] = n; }
    __syncthreads();
    if (t == 0) {
        float L = sred[0][0] + sred[0][1] + sred[0][2] + sred[0][3];
        float S = sred[1][0] + sred[1][1] + sred[1][2] + sred[1][3];
        float N = fmaxf(sred[2][0] + sred[2][1] + sred[2][2] + sred[2][3], 1.f);
        out[NUV + 0] = L / N;
        out[NUV + 1] = sqrtf(S / N);
    }
}

// ================================================================ launch
extern "C" void kernel_launch(void* const* d_in, const int* in_sizes, int n_in,
                              void* d_out, int out_size, void* d_ws, size_t ws_size,
                              hipStream_t stream) {
    const int* u = (const int*)d_in[0];
    const int* v = (const int*)d_in[1];
    const float* adj    = (const float*)d_in[3];
    const float* u_feat = (const float*)d_in[4];
    const float* v_feat = (const float*)d_in[5];
    const float* u_w    = (const float*)d_in[6];
    const float* v_w    = (const float*)d_in[7];
    const float* Wu1    = (const float*)d_in[8];
    const float* bu1    = (const float*)d_in[9];
    const float* Wv1    = (const float*)d_in[10];
    const float* bv1    = (const float*)d_in[11];
    const float* Wu2    = (const float*)d_in[12];
    const float* Wv2    = (const float*)d_in[13];
    const float* P      = (const float*)d_in[14];
    const float* a      = (const float*)d_in[15];
    float* out = (float*)d_out;

    char* ws = (char*)d_ws;
    // workspace layout (bytes). Overlays:
    //  codeT on UCAT (dead after compactF); codeR on TAU+TBV (dead after gatherE);
    //  part on CNTU+CNTV (dead after compactF); fuhi/fulo on IDXU/IDXV (dead
    //  after gatherE); cat bf16 hi/lo planes on UCAT/VCAT.
    //  d_out scratch: fv/W1/W2 splits at [0,22.3M), epoch partials pnn at
    //  [24M,57.7M) — all overwritten by scores3's mhat at the end.
    const size_t O_CODE  = 0;                         // 16,777,216 u8
    const size_t O_CNTU  = 16777216;                  // 16,384 i32
    const size_t O_CNTV  = O_CNTU + 16384;            // 16,384 i32
    const size_t O_ACC   = O_CNTV + 16384;            // 256 B (unused)
    const size_t O_TAU   = O_ACC + 256;               // 10,485,760 f16 table (u side)
    const size_t O_TBV   = O_TAU + 10485760;          // 10,485,760 f16 table (v side)
    const size_t O_IDXU  = O_TBV + 10485760;          // 12,582,912 u16 [4096][CAP]
    const size_t O_IDXV  = O_IDXU + 12582912;         // 12,582,912 u16
    const size_t O_NNZU  = O_IDXV + 12582912;         // 16,384 i32
    const size_t O_NNZV  = O_NNZU + 16384;            // 16,384 i32
    const size_t O_RDEG  = O_NNZV + 16384;            // 16,384 f32
    const size_t O_CDEG  = O_RDEG + 16384;            // 16,384 f32
    const size_t O_UNN   = O_CDEG + 16384;            // 4,194,304 (unused in v6)
    const size_t O_VNN   = O_UNN + 4194304;           // 4,194,304 (unused in v6)
    const size_t O_UCAT  = O_VNN + 4194304;           // 12,582,912 (bf16 hi+lo planes)
    const size_t O_VCAT  = O_UCAT + 12582912;         // 12,582,912
    const size_t O_UH    = O_VCAT + 12582912;         // 2,097,152 f32
    const size_t O_VHB   = O_UH + 2097152;            // 1,048,576 bf16 [4096][128]
    const size_t O_PT    = O_VHB + 1048576;           // 131,072 f32
    const size_t O_TB    = O_PT + 131072;             // 2,097,152 bf16 [2][4096][128]
    const size_t O_CODET = O_UCAT;                    // overlay
    const size_t O_CODER = O_TAU;                    // overlay (fits TAU+TBV)
    const size_t O_PART  = O_CNTU;                    // overlay (cnt dead after compact)
    const size_t O_FUHI  = O_IDXU;                    // overlay, 8,388,608
    const size_t O_FULO  = O_IDXV;                    // overlay, 8,388,608
    const size_t O_CHIU  = O_UCAT;                    // [4096][768] u16 hi
    const size_t O_CLOU  = O_UCAT + 6291456;          // [4096][768] u16 lo
    const size_t O_CHIV  = O_VCAT;
    const size_t O_CLOV  = O_VCAT + 6291456;
    // d_out scratch offsets (67 MB available)
    const size_t S_FVHI  = 0;
    const size_t S_FVLO  = 8388608;
    const size_t S_WUHI  = 16777216;
    const size_t S_WULO  = S_WUHI + 1048576;
    const size_t S_WVHI  = S_WULO + 1048576;
    const size_t S_WVLO  = S_WVHI + 1048576;
    const size_t S_W2UHI = S_WVLO + 1048576;
    const size_t S_W2ULO = S_W2UHI + 196608;
    const size_t S_W2VHI = S_W2ULO + 196608;
    const size_t S_W2VLO = S_W2VHI + 196608;
    const size_t S_PNN   = 25165824;                  // [2][4][4096][256] f32 = 33.6 MB

    uint8_t* code  = (uint8_t*)(ws + O_CODE);
    uint8_t* codeT = (uint8_t*)(ws + O_CODET);
    uint8_t* codeR = (uint8_t*)(ws + O_CODER);
    int* cnt_u = (int*)(ws + O_CNTU);
    int* cnt_v = (int*)(ws + O_CNTV);
    unsigned short* T_Au = (unsigned short*)(ws + O_TAU);
    unsigned short* T_Bv = (unsigned short*)(ws + O_TBV);
    unsigned short* idxU = (unsigned short*)(ws + O_IDXU);
    unsigned short* idxV = (unsigned short*)(ws + O_IDXV);
    int* nnzU = (int*)(ws + O_NNZU);
    int* nnzV = (int*)(ws + O_NNZV);
    float* rowDeg = (float*)(ws + O_RDEG);
    float* colDeg = (float*)(ws + O_CDEG);
    float* uh = (float*)(ws + O_UH);
    unsigned short* vhb = (unsigned short*)(ws + O_VHB);
    float* Pt = (float*)(ws + O_PT);
    unsigned short* tb = (unsigned short*)(ws + O_TB);
    float* part = (float*)(ws + O_PART);
    unsigned short* fuhi = (unsigned short*)(ws + O_FUHI);
    unsigned short* fulo = (unsigned short*)(ws + O_FULO);
    unsigned short* chiU = (unsigned short*)(ws + O_CHIU);
    unsigned short* cloU = (unsigned short*)(ws + O_CLOU);
    unsigned short* chiV = (unsigned short*)(ws + O_CHIV);
    unsigned short* cloV = (unsigned short*)(ws + O_CLOV);
    char* outc = (char*)d_out;
    unsigned short* fvhi = (unsigned short*)(outc + S_FVHI);
    unsigned short* fvlo = (unsigned short*)(outc + S_FVLO);
    unsigned short* wuhi = (unsigned short*)(outc + S_WUHI);
    unsigned short* wulo = (unsigned short*)(outc + S_WULO);
    unsigned short* wvhi = (unsigned short*)(outc + S_WVHI);
    unsigned short* wvlo = (unsigned short*)(outc + S_WVLO);
    unsigned short* w2uhi = (unsigned short*)(outc + S_W2UHI);
    unsigned short* w2ulo = (unsigned short*)(outc + S_W2ULO);
    unsigned short* w2vhi = (unsigned short*)(outc + S_W2VHI);
    unsigned short* w2vlo = (unsigned short*)(outc + S_W2VLO);
    float* pnn = (float*)(outc + S_PNN);

    hipMemsetAsync(ws + O_CNTU, 0, 16384 + 16384, stream);

    k_codeF<<<16400, 256, 0, stream>>>(adj, (uchar4*)code, u, v, cnt_u, cnt_v);
    k_fuse0<<<12288, 256, 0, stream>>>(code, codeT, u_w, cnt_u, T_Au, v_w, cnt_v, T_Bv);
    k_compactF<<<dim3(N4, 2), 256, 0, stream>>>(code, codeT, cnt_u, cnt_v,
                                                idxU, nnzU, rowDeg, idxV, nnzV, colDeg);
    k_gatherE<<<65536, 256, 0, stream>>>(idxU, nnzU, T_Bv, idxV, nnzV, T_Au, pnn);
    k_fuse1<<<21824, 256, 0, stream>>>(code, u, v, codeR, pnn, colDeg, rowDeg,
                                       chiU, cloU, chiV, cloV,
                                       u_feat, fuhi, fulo,
                                       v_feat, fvhi, fvlo,
                                       Wu1, wuhi, wulo, Wv1, wvhi, wvlo,
                                       Wu2, w2uhi, w2ulo, Wv2, w2vhi, w2vlo,
                                       P, Pt);
    k_l1F<<<dim3(8, 64, 2), 256, 0, stream>>>(fuhi, fulo, fvhi, fvlo, u, v,
                                              wuhi, wulo, wvhi, wvlo, bu1, bv1,
                                              chiU, cloU, chiV, cloV);
    k_l2F<<<dim3(2, 64, 2), 256, 0, stream>>>(chiU, cloU, w2uhi, w2ulo, uh,
                                              chiV, cloV, w2vhi, w2vlo, vhb);
    // t[b] = uh @ P[b] -> bf16
    k_gemm<64, 32, 16, 4, 2>
        <<<dim3(64, 4, 2), 256, 0, stream>>>(uh, H1, Pt, H1,
                                             (float*)tb, H1, H1,
                                             (size_t)H1 * H1, (size_t)N4 * H1);
    k_scores3<<<dim3(32, 64), 256, 0, stream>>>(tb, vhb, codeR, a, out, part);
    k_finalize<<<1, 256, 0, stream>>>(part, out);
}

// Round 9
// 874.034 us; speedup vs baseline: 1.3538x; 1.0089x over previous
//
#include <hip/hip_runtime.h>
#include <stdint.h>

// Problem constants
#define N4   4096
#define H0   256
#define SIDE 1024
#define DIN  512
#define HCAT 768      // H0 + DIN
#define H1   128
#define NC   5
#define NUV  16777216ULL   // 4096*4096
#define CAP  1536          // max compacted entries per row

typedef __attribute__((ext_vector_type(8))) short short8;    // 8 bf16
typedef __attribute__((ext_vector_type(4))) float floatx4;

__device__ __forceinline__ unsigned short f2bf(float f) {
    unsigned int u;
    __builtin_memcpy(&u, &f, 4);
    unsigned int r = (u + 0x7FFFu + ((u >> 16) & 1u)) >> 16;   // RNE
    return (unsigned short)r;
}

__device__ __forceinline__ float bf2f(unsigned short b) {
    unsigned int u = (unsigned int)b << 16;
    float f;
    __builtin_memcpy(&f, &u, 4);
    return f;
}

// ---------------------------------------------------------------- k_codeF: code + counts
// blocks [0,16384): code; [16384,16400): counts
__global__ __launch_bounds__(256) void k_codeF(const float* __restrict__ adj,
                                               uchar4* __restrict__ code4,
                                               const int* __restrict__ u,
                                               const int* __restrict__ v,
                                               int* __restrict__ cu,
                                               int* __restrict__ cv) {
    int b = blockIdx.x, t = threadIdx.x;
    if (b < 16384) {
        size_t g = (size_t)b * 256 + t;
        size_t base = g * 4;
        uchar4 out = {0, 0, 0, 0};
        #pragma unroll
        for (int c = 0; c < NC; c++) {
            float4 s = *(const float4*)(adj + (size_t)c * NUV + base);
            out.x = (s.x != 0.f) ? (unsigned char)(c + 1) : out.x;
            out.y = (s.y != 0.f) ? (unsigned char)(c + 1) : out.y;
            out.z = (s.z != 0.f) ? (unsigned char)(c + 1) : out.z;
            out.w = (s.w != 0.f) ? (unsigned char)(c + 1) : out.w;
        }
        code4[g] = out;
    } else {
        int i = (b - 16384) * 256 + t;   // 4096 threads
        atomicAdd(&cu[u[i]], 1);
        atomicAdd(&cv[v[i]], 1);
    }
}

// ---------------------------------------------------------------- k_fuse0: transpose + wcumsum x2
// blocks [0,4096): byte transpose 64x64 tile; [4096,12288): wcumsum (side by range)
__global__ __launch_bounds__(256) void k_fuse0(const uint8_t* __restrict__ code,
                                               uint8_t* __restrict__ codeT,
                                               const float* __restrict__ u_w,
                                               const int* __restrict__ cnt_u,
                                               unsigned short* __restrict__ T_Au,
                                               const float* __restrict__ v_w,
                                               const int* __restrict__ cnt_v,
                                               unsigned short* __restrict__ T_Bv) {
    __shared__ __align__(16) uint8_t tile[64][80];
    int b = blockIdx.x, t = threadIdx.x;
    if (b < 4096) {
        int bx = b & 63, by = b >> 6;
        int row = t >> 2;
        int seg = (t & 3) * 16;
        int p0 = by * 64, q0 = bx * 64;
        uint4 vdat = *(const uint4*)(code + (size_t)(p0 + row) * N4 + q0 + seg);
        *(uint4*)(&tile[row][seg]) = vdat;
        __syncthreads();
        union { uint4 u4; uint8_t bb[16]; } o;
        #pragma unroll
        for (int l = 0; l < 16; l++) o.bb[l] = tile[seg + l][row];
        *(uint4*)(codeT + (size_t)(q0 + row) * N4 + p0 + seg) = o.u4;
    } else {
        int node = (b - 4096) & 4095;
        int side = (b - 4096) >> 12;       // 0: u-table, 1: v-table
        const float* w = side ? v_w : u_w;
        const int* cnt = side ? cnt_v : cnt_u;
        unsigned short* out = side ? T_Bv : T_Au;
        int h = t;
        float c = (float)cnt[node];
        float acc = 0.f;
        #pragma unroll
        for (int r = 0; r < NC; r++) {
            size_t idx = ((size_t)r * N4 + node) * H0 + h;
            acc += w[idx];
            union { _Float16 h16; unsigned short s; } cvt;
            cvt.h16 = (_Float16)(acc * c);
            out[idx] = cvt.s;
        }
    }
}

// ---------------------------------------------------------------- k_prep: compact both sides + ALL splits + Pt
// [0,8192): compact (side = b>>12); [8192,12288): split u_feat;
// [12288,16384): split v_feat; [16384,16896): Wu1; [16896,17408): Wv1;
// [17408,17504): Wu2; [17504,17600): Wv2; [17600,17728): Pt (bf16 hi/lo).
// Heterogeneous: compact is LDS/VALU-bound, splits HBM-bound -> co-scheduled.
__global__ __launch_bounds__(256) void k_prep(const uint8_t* __restrict__ code,
                                              const uint8_t* __restrict__ codeT,
                                              const int* __restrict__ cnt_u,
                                              const int* __restrict__ cnt_v,
                                              unsigned short* __restrict__ idxU,
                                              int* __restrict__ nnzU,
                                              float* __restrict__ rowDeg,
                                              unsigned short* __restrict__ idxV,
                                              int* __restrict__ nnzV,
                                              float* __restrict__ colDeg,
                                              const float* __restrict__ u_feat,
                                              unsigned short* __restrict__ fuhi,
                                              unsigned short* __restrict__ fulo,
                                              const float* __restrict__ v_feat,
                                              unsigned short* __restrict__ fvhi,
                                              unsigned short* __restrict__ fvlo,
                                              const float* __restrict__ Wu1,
                                              unsigned short* __restrict__ wuhi,
                                              unsigned short* __restrict__ wulo,
                                              const float* __restrict__ Wv1,
                                              unsigned short* __restrict__ wvhi,
                                              unsigned short* __restrict__ wvlo,
                                              const float* __restrict__ Wu2,
                                              unsigned short* __restrict__ w2uhi,
                                              unsigned short* __restrict__ w2ulo,
                                              const float* __restrict__ Wv2,
                                              unsigned short* __restrict__ w2vhi,
                                              unsigned short* __restrict__ w2vlo,
                                              const float* __restrict__ P,
                                              unsigned short* __restrict__ pthi,
                                              unsigned short* __restrict__ ptlo) {
    __shared__ float cw[4096];
    __shared__ int wtot[4];
    __shared__ float wdeg[4];
    __shared__ __align__(16) unsigned short ebuf[CAP];
    int b = blockIdx.x, t = threadIdx.x;
    if (b < 8192) {
        int side = b >> 12;
        int p = b & 4095;
        const uint8_t* codeRows = side ? codeT : code;
        const int* cntOther = side ? cnt_u : cnt_v;
        unsigned short* idx = side ? idxV : idxU;
        int* nnz = side ? nnzV : nnzU;
        float* deg = side ? colDeg : rowDeg;

        int lane = t & 63, wv = t >> 6;
        const int4* co4 = (const int4*)cntOther;
        #pragma unroll
        for (int l = 0; l < 4; l++) {
            int4 ci = co4[t + l * 256];
            ((float4*)cw)[t + l * 256] =
                make_float4((float)ci.x, (float)ci.y, (float)ci.z, (float)ci.w);
        }
        uint4 w = ((const uint4*)(codeRows + (size_t)p * N4))[t];
        unsigned char bb[16];
        __builtin_memcpy(bb, &w, 16);
        int cnt = 0;
        #pragma unroll
        for (int j = 0; j < 16; j++) cnt += (bb[j] != 0);
        int sc = cnt;
        #pragma unroll
        for (int off = 1; off < 64; off <<= 1) {
            int up = __shfl_up(sc, off, 64);
            if (lane >= off) sc += up;
        }
        if (lane == 63) wtot[wv] = sc;
        __syncthreads();            // covers cw + wtot
        int wbase = 0;
        #pragma unroll
        for (int ww = 0; ww < 4; ww++) wbase += (ww < wv) ? wtot[ww] : 0;
        int total = wtot[0] + wtot[1] + wtot[2] + wtot[3];
        int pos = wbase + sc - cnt;   // block-exclusive prefix
        float dsum = 0.f;
        #pragma unroll
        for (int j = 0; j < 16; j++) {
            int r = bb[j];
            if (r) {
                int q = t * 16 + j;
                if (pos < CAP) ebuf[pos] = (unsigned short)((r - 1) * N4 + q);
                pos++;
                dsum += cw[q];
            }
        }
        #pragma unroll
        for (int off = 32; off; off >>= 1) dsum += __shfl_down(dsum, off, 64);
        if (lane == 0) wdeg[wv] = dsum;
        __syncthreads();            // covers ebuf + wdeg
        int tw = total < CAP ? total : CAP;
        if (t == 0) { deg[p] = wdeg[0] + wdeg[1] + wdeg[2] + wdeg[3]; nnz[p] = tw; }
        for (int e = t; e < tw; e += 256) idx[(size_t)p * CAP + e] = ebuf[e];
        return;
    }
    if (b >= 17600) {   // Pt -> bf16 hi/lo planes [2][128e][128d]
        int tid = (b - 17600) * 256 + t;   // 32768
        int bb = tid >> 14;
        int d = (tid >> 7) & 127;
        int e = tid & 127;
        float val = P[tid];
        unsigned short hb = f2bf(val);
        size_t o = ((size_t)bb * 128 + e) * 128 + d;
        pthi[o] = hb;
        ptlo[o] = f2bf(val - bf2f(hb));
        return;
    }
    const float* src;
    unsigned short* hi;
    unsigned short* lo;
    int lb;
    if (b < 12288)      { src = u_feat; hi = fuhi; lo = fulo; lb = b - 8192; }
    else if (b < 16384) { src = v_feat; hi = fvhi; lo = fvlo; lb = b - 12288; }
    else if (b < 16896) { src = Wu1; hi = wuhi; lo = wulo; lb = b - 16384; }
    else if (b < 17408) { src = Wv1; hi = wvhi; lo = wvlo; lb = b - 16896; }
    else if (b < 17504) { src = Wu2; hi = w2uhi; lo = w2ulo; lb = b - 17408; }
    else                { src = Wv2; hi = w2vhi; lo = w2vlo; lb = b - 17504; }
    size_t g = ((size_t)lb * 256 + t) * 4;
    float4 x = *(const float4*)(src + g);
    float f[4] = {x.x, x.y, x.z, x.w};
    unsigned short hh[4], ll[4];
    #pragma unroll
    for (int k = 0; k < 4; k++) {
        unsigned short hb = f2bf(f[k]);
        hh[k] = hb;
        ll[k] = f2bf(f[k] - bf2f(hb));
    }
    *(ushort4*)(hi + g) = make_ushort4(hh[0], hh[1], hh[2], hh[3]);
    *(ushort4*)(lo + g) = make_ushort4(ll[0], ll[1], ll[2], ll[3]);
}

// ---------------------------------------------------------------- k_gatherE
// Epoch-tiled gather (entries q-sorted; per-block binary search of epoch
// bounds). Output: epoch partials pnn[side][epoch][p][256] f32.
__global__ __launch_bounds__(256) void k_gatherE(const unsigned short* __restrict__ idxU,
                                                 const int* __restrict__ nnzU,
                                                 const unsigned short* __restrict__ T_Bv,
                                                 const unsigned short* __restrict__ idxV,
                                                 const int* __restrict__ nnzV,
                                                 const unsigned short* __restrict__ T_Au,
                                                 float* __restrict__ pnn) {
    __shared__ __align__(16) unsigned short sidx[CAP];
    __shared__ float red[16][132];
    __shared__ int sbnd[2];
    int bid = blockIdx.x;
    int side  = bid >> 15;
    int r1    = bid & 32767;
    int epoch = r1 >> 13;
    int r2    = r1 & 8191;
    int p     = r2 >> 1;
    int half  = r2 & 1;

    const unsigned short* idx = side ? idxV : idxU;
    const int* nnz = side ? nnzV : nnzU;
    const char* tb = (const char*)(side ? T_Au : T_Bv);

    int t = threadIdx.x;
    int n = nnz[p];
    const unsigned short* rowIdx = idx + (size_t)p * CAP;
    int nv = (n + 7) >> 3;
    for (int i = t; i < nv; i += 256)
        ((uint4*)sidx)[i] = ((const uint4*)rowIdx)[i];
    __syncthreads();
    if (t < 2) {
        int target = (epoch + t) << 10;
        int lo = 0, hi = n;
        while (lo < hi) {
            int mid = (lo + hi) >> 1;
            int q = sidx[mid] & 4095;
            if (q < target) lo = mid + 1; else hi = mid;
        }
        sbnd[t] = lo;
    }
    __syncthreads();
    int elo = sbnd[0], ehi = sbnd[1];

    int s = t >> 4;        // entry slot 0..15
    int c = t & 15;        // 16B segment within half-row
    int boff = half * 256 + c * 16;
    float acc[8] = {0.f, 0.f, 0.f, 0.f, 0.f, 0.f, 0.f, 0.f};
    int cnt = ehi - elo;
    int nmain = elo + (cnt & ~63);
    for (int e = elo + s; e < nmain; e += 64) {
        int o0 = ((int)sidx[e])      << 9;
        int o1 = ((int)sidx[e + 16]) << 9;
        int o2 = ((int)sidx[e + 32]) << 9;
        int o3 = ((int)sidx[e + 48]) << 9;
        uint4 d0 = *(const uint4*)(tb + o0 + boff);
        uint4 d1 = *(const uint4*)(tb + o1 + boff);
        uint4 d2 = *(const uint4*)(tb + o2 + boff);
        uint4 d3 = *(const uint4*)(tb + o3 + boff);
        union { uint4 u; _Float16 h[8]; } cv;
        cv.u = d0;
        #pragma unroll
        for (int k = 0; k < 8; k++) acc[k] += (float)cv.h[k];
        cv.u = d1;
        #pragma unroll
        for (int k = 0; k < 8; k++) acc[k] += (float)cv.h[k];
        cv.u = d2;
        #pragma unroll
        for (int k = 0; k < 8; k++) acc[k] += (float)cv.h[k];
        cv.u = d3;
        #pragma unroll
        for (int k = 0; k < 8; k++) acc[k] += (float)cv.h[k];
    }
    for (int e = nmain + s; e < ehi; e += 16) {
        int o = ((int)sidx[e]) << 9;
        uint4 d = *(const uint4*)(tb + o + boff);
        union { uint4 u; _Float16 h[8]; } cv;
        cv.u = d;
        #pragma unroll
        for (int k = 0; k < 8; k++) acc[k] += (float)cv.h[k];
    }
    #pragma unroll
    for (int k = 0; k < 8; k++) red[s][c * 8 + k] = acc[k];
    __syncthreads();
    if (t < 128) {
        float sum = 0.f;
        #pragma unroll
        for (int ss = 0; ss < 16; ss++) sum += red[ss][t];
        pnn[(((size_t)(side * 4 + epoch)) * N4 + p) * H0 + half * 128 + t] = sum;
    }
}

// ---------------------------------------------------------------- k_l1Z: l1F (MFMA) + z + reorder
// [0,1024): l1F (side=b>>9, rem=b&511: n-blk=rem&7, i-blk=rem>>3);
// [1024,9216): z (sums 4 epoch partials, cat cols 0..255);
// [9216,13312): reorder (codeR).
// MFMA blocks dispatched first; memory-bound z/reorder co-schedule under them.
__global__ __launch_bounds__(256) void k_l1Z(const unsigned short* __restrict__ fuhi,
                                             const unsigned short* __restrict__ fulo,
                                             const unsigned short* __restrict__ fvhi,
                                             const unsigned short* __restrict__ fvlo,
                                             const int* __restrict__ u,
                                             const int* __restrict__ v,
                                             const unsigned short* __restrict__ wuhi,
                                             const unsigned short* __restrict__ wulo,
                                             const unsigned short* __restrict__ wvhi,
                                             const unsigned short* __restrict__ wvlo,
                                             const float* __restrict__ bu1,
                                             const float* __restrict__ bv1,
                                             unsigned short* __restrict__ chiU,
                                             unsigned short* __restrict__ cloU,
                                             unsigned short* __restrict__ chiV,
                                             unsigned short* __restrict__ cloV,
                                             const float* __restrict__ pnn,
                                             const float* __restrict__ colDeg,
                                             const float* __restrict__ rowDeg,
                                             const uint8_t* __restrict__ code,
                                             uint8_t* __restrict__ codeR) {
    __shared__ __align__(16) unsigned short Bh[64][72];
    __shared__ __align__(16) unsigned short Bl[64][72];
    int b = blockIdx.x, t = threadIdx.x;
    if (b < 1024) {
        int side = b >> 9;
        int rem = b & 511;
        const unsigned short* Ahi = side ? fvhi : fuhi;
        const unsigned short* Alo = side ? fvlo : fulo;
        const int* rowmap = side ? v : u;
        const unsigned short* Bhi = side ? wvhi : wuhi;
        const unsigned short* Blo = side ? wvlo : wulo;
        const float* bias = side ? bv1 : bu1;
        unsigned short* CHi = (side ? chiV : chiU) + H0;
        unsigned short* CLo = (side ? cloV : cloU) + H0;

        int wave = t >> 6, lane = t & 63;
        int lr = lane & 15;
        int lk = lane >> 4;
        int i0 = (rem >> 3) * 64 + wave * 16;
        int n0 = (rem & 7) * 64;
        int gi = rowmap[i0 + lr];
        const unsigned short* pah = Ahi + (size_t)gi * SIDE;
        const unsigned short* pal = Alo + (size_t)gi * SIDE;
        int srow = t >> 2, sseg = (t & 3) * 16;
        floatx4 acc[4];
        #pragma unroll
        for (int jt = 0; jt < 4; jt++) acc[jt] = (floatx4){0.f, 0.f, 0.f, 0.f};
        for (int ks = 0; ks < SIDE / 64; ks++) {
            const unsigned short* sh = Bhi + (size_t)(n0 + srow) * SIDE + ks * 64 + sseg;
            const unsigned short* sl = Blo + (size_t)(n0 + srow) * SIDE + ks * 64 + sseg;
            __syncthreads();
            *(uint4*)(&Bh[srow][sseg]) = *(const uint4*)sh;
            *(uint4*)(&Bh[srow][sseg + 8]) = *(const uint4*)(sh + 8);
            *(uint4*)(&Bl[srow][sseg]) = *(const uint4*)sl;
            *(uint4*)(&Bl[srow][sseg + 8]) = *(const uint4*)(sl + 8);
            __syncthreads();
            #pragma unroll
            for (int kk = 0; kk < 2; kk++) {
                int ko = ks * 64 + kk * 32 + lk * 8;
                short8 ah = *(const short8*)(pah + ko);
                short8 al = *(const short8*)(pal + ko);
                #pragma unroll
                for (int jt = 0; jt < 4; jt++) {
                    short8 bh = *(const short8*)(&Bh[jt * 16 + lr][kk * 32 + lk * 8]);
                    short8 bl = *(const short8*)(&Bl[jt * 16 + lr][kk * 32 + lk * 8]);
                    acc[jt] = __builtin_amdgcn_mfma_f32_16x16x32_bf16(ah, bh, acc[jt], 0, 0, 0);
                    acc[jt] = __builtin_amdgcn_mfma_f32_16x16x32_bf16(ah, bl, acc[jt], 0, 0, 0);
                    acc[jt] = __builtin_amdgcn_mfma_f32_16x16x32_bf16(al, bh, acc[jt], 0, 0, 0);
                }
            }
        }
        #pragma unroll
        for (int jt = 0; jt < 4; jt++) {
            int cn = n0 + jt * 16 + lr;
            float bb = bias[cn];
            #pragma unroll
            for (int r = 0; r < 4; r++) {
                int ci = i0 + lk * 4 + r;
                float vv = fmaxf(acc[jt][r] + bb, 0.f);
                unsigned short hb = f2bf(vv);
                CHi[(size_t)ci * HCAT + cn] = hb;
                CLo[(size_t)ci * HCAT + cn] = f2bf(vv - bf2f(hb));
            }
        }
        return;
    }
    if (b < 9216) {
        int idx = b - 1024;
        int side = idx >> 12;
        int i = idx & 4095;
        const int* idxs = side ? v : u;
        const int* idxo = side ? u : v;
        const float* deg = side ? rowDeg : colDeg;
        unsigned short* catHi = side ? chiV : chiU;
        unsigned short* catLo = side ? cloV : cloU;
        int h = t;
        float d = deg[idxo[i]];
        float inv = d > 0.f ? 1.f / d : 0.f;
        int row = idxs[i];
        const float* pr = pnn + ((size_t)side * 4 * N4 + row) * H0 + h;
        float nnv = 0.f;
        #pragma unroll
        for (int e = 0; e < 4; e++) nnv += pr[(size_t)e * N4 * H0];
        float val = fmaxf(nnv * inv, 0.f);
        unsigned short hb = f2bf(val);
        catHi[(size_t)i * HCAT + h] = hb;
        catLo[(size_t)i * HCAT + h] = f2bf(val - bf2f(hb));
        return;
    }
    // reorder: codeR[i][j] = code[u[i]][v[j]]  (rowbuf aliases Bh)
    uint8_t* rowbuf = (uint8_t*)Bh;
    int i = b - 9216;
    int urow = u[i];
    ((uint4*)rowbuf)[t] = ((const uint4*)(code + (size_t)urow * N4))[t];
    __syncthreads();
    uint8_t ob[16];
    #pragma unroll
    for (int w = 0; w < 4; w++) {
        int4 vv = ((const int4*)v)[t * 4 + w];
        ob[w * 4 + 0] = rowbuf[vv.x];
        ob[w * 4 + 1] = rowbuf[vv.y];
        ob[w * 4 + 2] = rowbuf[vv.z];
        ob[w * 4 + 3] = rowbuf[vv.w];
    }
    uint4 o;
    __builtin_memcpy(&o, ob, 16);
    ((uint4*)(codeR + (size_t)i * N4))[t] = o;
}

// ---------------------------------------------------------------- k_l2F (split MFMA GEMM, LDS-staged B, both sides)
// z=0: uh -> bf16 hi/lo planes (feeds k_tb); z=1: vhb (bf16). K=768, N=128.
__global__ __launch_bounds__(256) void k_l2F(const unsigned short* __restrict__ chiU,
                                             const unsigned short* __restrict__ cloU,
                                             const unsigned short* __restrict__ w2uhi,
                                             const unsigned short* __restrict__ w2ulo,
                                             unsigned short* __restrict__ uhhi,
                                             unsigned short* __restrict__ uhlo,
                                             const unsigned short* __restrict__ chiV,
                                             const unsigned short* __restrict__ cloV,
                                             const unsigned short* __restrict__ w2vhi,
                                             const unsigned short* __restrict__ w2vlo,
                                             unsigned short* __restrict__ vhb) {
    __shared__ __align__(16) unsigned short Bh[64][72];
    __shared__ __align__(16) unsigned short Bl[64][72];
    int side = blockIdx.z;
    const unsigned short* Ahi = side ? chiV : chiU;
    const unsigned short* Alo = side ? cloV : cloU;
    const unsigned short* Bhi = side ? w2vhi : w2uhi;
    const unsigned short* Blo = side ? w2vlo : w2ulo;

    int t = threadIdx.x;
    int wave = t >> 6, lane = t & 63;
    int lr = lane & 15;
    int lk = lane >> 4;
    int i0 = blockIdx.y * 64 + wave * 16;
    int n0 = blockIdx.x * 64;
    const unsigned short* pah = Ahi + (size_t)(i0 + lr) * HCAT;
    const unsigned short* pal = Alo + (size_t)(i0 + lr) * HCAT;
    int srow = t >> 2, sseg = (t & 3) * 16;
    floatx4 acc[4];
    #pragma unroll
    for (int jt = 0; jt < 4; jt++) acc[jt] = (floatx4){0.f, 0.f, 0.f, 0.f};
    for (int ks = 0; ks < HCAT / 64; ks++) {
        const unsigned short* sh = Bhi + (size_t)(n0 + srow) * HCAT + ks * 64 + sseg;
        const unsigned short* sl = Blo + (size_t)(n0 + srow) * HCAT + ks * 64 + sseg;
        __syncthreads();
        *(uint4*)(&Bh[srow][sseg]) = *(const uint4*)sh;
        *(uint4*)(&Bh[srow][sseg + 8]) = *(const uint4*)(sh + 8);
        *(uint4*)(&Bl[srow][sseg]) = *(const uint4*)sl;
        *(uint4*)(&Bl[srow][sseg + 8]) = *(const uint4*)(sl + 8);
        __syncthreads();
        #pragma unroll
        for (int kk = 0; kk < 2; kk++) {
            int ko = ks * 64 + kk * 32 + lk * 8;
            short8 ah = *(const short8*)(pah + ko);
            short8 al = *(const short8*)(pal + ko);
            #pragma unroll
            for (int jt = 0; jt < 4; jt++) {
                short8 bh = *(const short8*)(&Bh[jt * 16 + lr][kk * 32 + lk * 8]);
                short8 bl = *(const short8*)(&Bl[jt * 16 + lr][kk * 32 + lk * 8]);
                acc[jt] = __builtin_amdgcn_mfma_f32_16x16x32_bf16(ah, bh, acc[jt], 0, 0, 0);
                acc[jt] = __builtin_amdgcn_mfma_f32_16x16x32_bf16(ah, bl, acc[jt], 0, 0, 0);
                acc[jt] = __builtin_amdgcn_mfma_f32_16x16x32_bf16(al, bh, acc[jt], 0, 0, 0);
            }
        }
    }
    #pragma unroll
    for (int jt = 0; jt < 4; jt++) {
        int cn = n0 + jt * 16 + lr;
        #pragma unroll
        for (int r = 0; r < 4; r++) {
            int ci = i0 + lk * 4 + r;
            float vv = fmaxf(acc[jt][r], 0.f);
            if (side) {
                vhb[(size_t)ci * H1 + cn] = f2bf(vv);
            } else {
                unsigned short hb = f2bf(vv);
                uhhi[(size_t)ci * H1 + cn] = hb;
                uhlo[(size_t)ci * H1 + cn] = f2bf(vv - bf2f(hb));
            }
        }
    }
}

// ---------------------------------------------------------------- k_tb (split MFMA): tb[b] = uh @ P[b]
// A = uh (bf16 hi/lo, [4096][128]); B = Pt planes ([2][128e][128d]); K=128.
__global__ __launch_bounds__(256) void k_tb(const unsigned short* __restrict__ uhhi,
                                            const unsigned short* __restrict__ uhlo,
                                            const unsigned short* __restrict__ pthi,
                                            const unsigned short* __restrict__ ptlo,
                                            unsigned short* __restrict__ tbout) {
    __shared__ __align__(16) unsigned short Bh[64][72];
    __shared__ __align__(16) unsigned short Bl[64][72];
    int bmat = blockIdx.z;
    int t = threadIdx.x;
    int wave = t >> 6, lane = t & 63;
    int lr = lane & 15;
    int lk = lane >> 4;
    int i0 = blockIdx.y * 64 + wave * 16;
    int n0 = blockIdx.x * 64;
    const unsigned short* Bhi = pthi + (size_t)bmat * H1 * H1;
    const unsigned short* Blo = ptlo + (size_t)bmat * H1 * H1;
    const unsigned short* pah = uhhi + (size_t)(i0 + lr) * H1;
    const unsigned short* pal = uhlo + (size_t)(i0 + lr) * H1;
    int srow = t >> 2, sseg = (t & 3) * 16;
    floatx4 acc[4];
    #pragma unroll
    for (int jt = 0; jt < 4; jt++) acc[jt] = (floatx4){0.f, 0.f, 0.f, 0.f};
    for (int ks = 0; ks < H1 / 64; ks++) {
        const unsigned short* sh = Bhi + (size_t)(n0 + srow) * H1 + ks * 64 + sseg;
        const unsigned short* sl = Blo + (size_t)(n0 + srow) * H1 + ks * 64 + sseg;
        __syncthreads();
        *(uint4*)(&Bh[srow][sseg]) = *(const uint4*)sh;
        *(uint4*)(&Bh[srow][sseg + 8]) = *(const uint4*)(sh + 8);
        *(uint4*)(&Bl[srow][sseg]) = *(const uint4*)sl;
        *(uint4*)(&Bl[srow][sseg + 8]) = *(const uint4*)(sl + 8);
        __syncthreads();
        #pragma unroll
        for (int kk = 0; kk < 2; kk++) {
            int ko = ks * 64 + kk * 32 + lk * 8;
            short8 ah = *(const short8*)(pah + ko);
            short8 al = *(const short8*)(pal + ko);
            #pragma unroll
            for (int jt = 0; jt < 4; jt++) {
                short8 bh = *(const short8*)(&Bh[jt * 16 + lr][kk * 32 + lk * 8]);
                short8 bl = *(const short8*)(&Bl[jt * 16 + lr][kk * 32 + lk * 8]);
                acc[jt] = __builtin_amdgcn_mfma_f32_16x16x32_bf16(ah, bh, acc[jt], 0, 0, 0);
                acc[jt] = __builtin_amdgcn_mfma_f32_16x16x32_bf16(ah, bl, acc[jt], 0, 0, 0);
                acc[jt] = __builtin_amdgcn_mfma_f32_16x16x32_bf16(al, bh, acc[jt], 0, 0, 0);
            }
        }
    }
    #pragma unroll
    for (int jt = 0; jt < 4; jt++) {
        int cn = n0 + jt * 16 + lr;
        #pragma unroll
        for (int r = 0; r < 4; r++) {
            int ci = i0 + lk * 4 + r;
            tbout[(size_t)bmat * N4 * H1 + (size_t)ci * H1 + cn] = f2bf(acc[jt][r]);
        }
    }
}

// ---------------------------------------------------------------- k_scores3 (MFMA bf16 decoder + softmax epilogue)
__global__ __launch_bounds__(256) void k_scores3(const unsigned short* __restrict__ tb,  // [2][4096][128] bf16
                                                 const unsigned short* __restrict__ vhb, // [4096][128] bf16
                                                 const uint8_t* __restrict__ codeR,
                                                 const float* __restrict__ a_f,          // [2][5]
                                                 float* __restrict__ mhat,
                                                 float* __restrict__ part) {
    __shared__ float wred[4][3];
    int t = threadIdx.x;
    int wave = t >> 6, lane = t & 63;
    int lr = lane & 15;          // A row / B col / C col
    int lk = lane >> 4;          // k-subgroup & C row-group
    int i0 = blockIdx.y * 64 + wave * 16;
    int j0 = blockIdx.x * 128;
    float sa0[NC], sa1[NC];
    #pragma unroll
    for (int c = 0; c < NC; c++) { sa0[c] = a_f[c]; sa1[c] = a_f[5 + c]; }

    const unsigned short* t0p = tb;
    const unsigned short* t1p = tb + (size_t)N4 * H1;
    short8 a0[4], a1[4];
    #pragma unroll
    for (int kc = 0; kc < 4; kc++) {
        size_t off = (size_t)(i0 + lr) * H1 + kc * 32 + lk * 8;
        a0[kc] = *(const short8*)(t0p + off);
        a1[kc] = *(const short8*)(t1p + off);
    }

    const uint8_t* crbase = codeR + (size_t)(i0 + lk * 4) * N4 + lr;
    short8 bcur[4];
    int cbv[4];
    {
        int jb = j0;
        const uint8_t* crp = crbase + jb;
        cbv[0] = crp[0];
        cbv[1] = crp[N4];
        cbv[2] = crp[2 * N4];
        cbv[3] = crp[3 * N4];
        #pragma unroll
        for (int kc = 0; kc < 4; kc++)
            bcur[kc] = *(const short8*)(vhb + (size_t)(jb + lr) * H1 + kc * 32 + lk * 8);
    }

    float lsum = 0.f, ssum = 0.f, nobs = 0.f;
    for (int jt = 0; jt < 8; jt++) {
        int jb = j0 + jt * 16;
        int j = jb + lr;
        short8 bnext[4];
        int cbn[4];
        if (jt < 7) {
            int jb2 = jb + 16;
            const uint8_t* crp = crbase + jb2;
            cbn[0] = crp[0];
            cbn[1] = crp[N4];
            cbn[2] = crp[2 * N4];
            cbn[3] = crp[3 * N4];
            #pragma unroll
            for (int kc = 0; kc < 4; kc++)
                bnext[kc] = *(const short8*)(vhb + (size_t)(jb2 + lr) * H1 + kc * 32 + lk * 8);
        }
        floatx4 C0 = {0.f, 0.f, 0.f, 0.f}, C1 = {0.f, 0.f, 0.f, 0.f};
        #pragma unroll
        for (int kc = 0; kc < 4; kc++) {
            C0 = __builtin_amdgcn_mfma_f32_16x16x32_bf16(a0[kc], bcur[kc], C0, 0, 0, 0);
            C1 = __builtin_amdgcn_mfma_f32_16x16x32_bf16(a1[kc], bcur[kc], C1, 0, 0, 0);
        }
        #pragma unroll
        for (int r = 0; r < 4; r++) {
            int i = i0 + lk * 4 + r;
            float v0 = C0[r], v1 = C1[r];
            float l[NC];
            float mx = -1e30f;
            #pragma unroll
            for (int c = 0; c < NC; c++) {
                l[c] = sa0[c] * v0 + sa1[c] * v1;
                mx = fmaxf(mx, l[c]);
            }
            float den = 0.f, num = 0.f;
            #pragma unroll
            for (int c = 0; c < NC; c++) {
                float e = __expf(l[c] - mx);
                den += e;
                num += (float)(c + 1) * e;
            }
            float mh = num / den;
            mhat[(size_t)i * N4 + j] = mh;
            int cb = cbv[r];
            if (cb) {
                float lse = mx + __logf(den);
                lsum += lse - l[cb - 1];        // = -logp[cb-1]
                float df = mh - (float)cb;
                ssum += df * df;
                nobs += 1.f;
            }
        }
        if (jt < 7) {
            #pragma unroll
            for (int kc = 0; kc < 4; kc++) bcur[kc] = bnext[kc];
            #pragma unroll
            for (int r = 0; r < 4; r++) cbv[r] = cbn[r];
        }
    }
    #pragma unroll
    for (int off = 32; off; off >>= 1) {
        lsum += __shfl_down(lsum, off, 64);
        ssum += __shfl_down(ssum, off, 64);
        nobs += __shfl_down(nobs, off, 64);
    }
    if (lane == 0) { wred[wave][0] = lsum; wred[wave][1] = ssum; wred[wave][2] = nobs; }
    __syncthreads();
    if (t == 0) {
        int bid = blockIdx.y * gridDim.x + blockIdx.x;
        part[bid * 3 + 0] = wred[0][0] + wred[1][0] + wred[2][0] + wred[3][0];
        part[bid * 3 + 1] = wred[0][1] + wred[1][1] + wred[2][1] + wred[3][1];
        part[bid * 3 + 2] = wred[0][2] + wred[1][2] + wred[2][2] + wred[3][2];
    }
}

// ---------------------------------------------------------------- k_finalize (reduce 2048 block partials)
__global__ __launch_bounds__(256) void k_finalize(const float* __restrict__ part,
                                                  float* __restrict__ out) {
    __shared__ float sred[3][4];
    int t = threadIdx.x, lane = t & 63, wv = t >> 6;
    float l = 0.f, s = 0.f, n = 0.f;
    for (int i = t; i < 2048; i += 256) {
        l += part[i * 3 + 0];
        s += part[i * 3 + 1];
        n += part[i * 3 + 2];
    }
    #pragma unroll
    for (int off = 32; off; off >>= 1) {
        l += __shfl_down(l, off, 64);
        s += __shfl_down(s, off, 64);
        n += __shfl_down(n, off, 64);
    }
    if (lane == 0) { sred[0][wv] = l; sred[1][wv] = s; sred[2][wv] = n; }
    __syncthreads();
    if (t == 0) {
        float L = sred[0][0] + sred[0][1] + sred[0][2] + sred[0][3];
        float S = sred[1][0] + sred[1][1] + sred[1][2] + sred[1][3];
        float N = fmaxf(sred[2][0] + sred[2][1] + sred[2][2] + sred[2][3], 1.f);
        out[NUV + 0] = L / N;
        out[NUV + 1] = sqrtf(S / N);
    }
}

// ================================================================ launch
extern "C" void kernel_launch(void* const* d_in, const int* in_sizes, int n_in,
                              void* d_out, int out_size, void* d_ws, size_t ws_size,
                              hipStream_t stream) {
    const int* u = (const int*)d_in[0];
    const int* v = (const int*)d_in[1];
    const float* adj    = (const float*)d_in[3];
    const float* u_feat = (const float*)d_in[4];
    const float* v_feat = (const float*)d_in[5];
    const float* u_w    = (const float*)d_in[6];
    const float* v_w    = (const float*)d_in[7];
    const float* Wu1    = (const float*)d_in[8];
    const float* bu1    = (const float*)d_in[9];
    const float* Wv1    = (const float*)d_in[10];
    const float* bv1    = (const float*)d_in[11];
    const float* Wu2    = (const float*)d_in[12];
    const float* Wv2    = (const float*)d_in[13];
    const float* P      = (const float*)d_in[14];
    const float* a      = (const float*)d_in[15];
    float* out = (float*)d_out;

    char* ws = (char*)d_ws;
    // workspace layout (bytes). Overlays (audited per launch):
    //  codeT on UCAT (dead after k_prep's compact); codeR on TAU+TBV (written
    //  in l1Z, after gather consumed tables); part on CNTU+CNTV (cnt dead
    //  after k_prep); fulo spans UNN+VNN (8.39 MB, z no longer uses them);
    //  cat bf16 hi/lo planes on UCAT/VCAT; uh hi/lo on UH; Pt hi/lo on PT.
    //  d_out scratch: fvhi/fvlo [0,16.78M), W1/W2 splits [16.78M,21.76M),
    //  pnn [25.17M,58.72M), fuhi [58.72M,67.11M) — all consumed before
    //  scores3's mhat overwrites d_out; loss scalars live past 67,108,864.
    const size_t O_CODE  = 0;                         // 16,777,216 u8
    const size_t O_CNTU  = 16777216;                  // 16,384 i32
    const size_t O_CNTV  = O_CNTU + 16384;            // 16,384 i32
    const size_t O_ACC   = O_CNTV + 16384;            // 256 B (unused)
    const size_t O_TAU   = O_ACC + 256;               // 10,485,760 f16 table (u side)
    const size_t O_TBV   = O_TAU + 10485760;          // 10,485,760 f16 table (v side)
    const size_t O_IDXU  = O_TBV + 10485760;          // 12,582,912 u16 [4096][CAP]
    const size_t O_IDXV  = O_IDXU + 12582912;         // 12,582,912 u16
    const size_t O_NNZU  = O_IDXV + 12582912;         // 16,384 i32
    const size_t O_NNZV  = O_NNZU + 16384;            // 16,384 i32
    const size_t O_RDEG  = O_NNZV + 16384;            // 16,384 f32
    const size_t O_CDEG  = O_RDEG + 16384;            // 16,384 f32
    const size_t O_UNN   = O_CDEG + 16384;            // 4,194,304
    const size_t O_VNN   = O_UNN + 4194304;           // 4,194,304 (fulo spans UNN+VNN)
    const size_t O_UCAT  = O_VNN + 4194304;           // 12,582,912 (bf16 hi+lo planes)
    const size_t O_VCAT  = O_UCAT + 12582912;         // 12,582,912
    const size_t O_UH    = O_VCAT + 12582912;         // 2,097,152 (uh hi/lo bf16)
    const size_t O_VHB   = O_UH + 2097152;            // 1,048,576 bf16 [4096][128]
    const size_t O_PT    = O_VHB + 1048576;           // 131,072 (Pt hi/lo bf16)
    const size_t O_TB    = O_PT + 131072;             // 2,097,152 bf16 [2][4096][128]
    const size_t O_CODET = O_UCAT;                    // overlay
    const size_t O_CODER = O_TAU;                     // overlay (fits TAU+TBV)
    const size_t O_PART  = O_CNTU;                    // overlay (cnt dead after prep)
    const size_t O_FULO  = O_UNN;                     // overlay, 8,388,608 (UNN+VNN)
    const size_t O_CHIU  = O_UCAT;                    // [4096][768] u16 hi
    const size_t O_CLOU  = O_UCAT + 6291456;          // [4096][768] u16 lo
    const size_t O_CHIV  = O_VCAT;
    const size_t O_CLOV  = O_VCAT + 6291456;
    // d_out scratch offsets (67,108,872 B total)
    const size_t S_FVHI  = 0;
    const size_t S_FVLO  = 8388608;
    const size_t S_WUHI  = 16777216;
    const size_t S_WULO  = S_WUHI + 1048576;
    const size_t S_WVHI  = S_WULO + 1048576;
    const size_t S_WVLO  = S_WVHI + 1048576;
    const size_t S_W2UHI = S_WVLO + 1048576;
    const size_t S_W2ULO = S_W2UHI + 196608;
    const size_t S_W2VHI = S_W2ULO + 196608;
    const size_t S_W2VLO = S_W2VHI + 196608;
    const size_t S_PNN   = 25165824;                  // [2][4][4096][256] f32 = 33,554,432
    const size_t S_FUHI  = 58720256;                  // 8,388,608 -> ends 67,108,864

    uint8_t* code  = (uint8_t*)(ws + O_CODE);
    uint8_t* codeT = (uint8_t*)(ws + O_CODET);
    uint8_t* codeR = (uint8_t*)(ws + O_CODER);
    int* cnt_u = (int*)(ws + O_CNTU);
    int* cnt_v = (int*)(ws + O_CNTV);
    unsigned short* T_Au = (unsigned short*)(ws + O_TAU);
    unsigned short* T_Bv = (unsigned short*)(ws + O_TBV);
    unsigned short* idxU = (unsigned short*)(ws + O_IDXU);
    unsigned short* idxV = (unsigned short*)(ws + O_IDXV);
    int* nnzU = (int*)(ws + O_NNZU);
    int* nnzV = (int*)(ws + O_NNZV);
    float* rowDeg = (float*)(ws + O_RDEG);
    float* colDeg = (float*)(ws + O_CDEG);
    unsigned short* uhhi = (unsigned short*)(ws + O_UH);
    unsigned short* uhlo = (unsigned short*)(ws + O_UH + 1048576);
    unsigned short* vhb = (unsigned short*)(ws + O_VHB);
    unsigned short* pthi = (unsigned short*)(ws + O_PT);
    unsigned short* ptlo = (unsigned short*)(ws + O_PT + 65536);
    unsigned short* tb = (unsigned short*)(ws + O_TB);
    float* part = (float*)(ws + O_PART);
    unsigned short* fulo = (unsigned short*)(ws + O_FULO);
    unsigned short* chiU = (unsigned short*)(ws + O_CHIU);
    unsigned short* cloU = (unsigned short*)(ws + O_CLOU);
    unsigned short* chiV = (unsigned short*)(ws + O_CHIV);
    unsigned short* cloV = (unsigned short*)(ws + O_CLOV);
    char* outc = (char*)d_out;
    unsigned short* fuhi = (unsigned short*)(outc + S_FUHI);
    unsigned short* fvhi = (unsigned short*)(outc + S_FVHI);
    unsigned short* fvlo = (unsigned short*)(outc + S_FVLO);
    unsigned short* wuhi = (unsigned short*)(outc + S_WUHI);
    unsigned short* wulo = (unsigned short*)(outc + S_WULO);
    unsigned short* wvhi = (unsigned short*)(outc + S_WVHI);
    unsigned short* wvlo = (unsigned short*)(outc + S_WVLO);
    unsigned short* w2uhi = (unsigned short*)(outc + S_W2UHI);
    unsigned short* w2ulo = (unsigned short*)(outc + S_W2ULO);
    unsigned short* w2vhi = (unsigned short*)(outc + S_W2VHI);
    unsigned short* w2vlo = (unsigned short*)(outc + S_W2VLO);
    float* pnn = (float*)(outc + S_PNN);

    hipMemsetAsync(ws + O_CNTU, 0, 16384 + 16384, stream);

    k_codeF<<<16400, 256, 0, stream>>>(adj, (uchar4*)code, u, v, cnt_u, cnt_v);
    k_fuse0<<<12288, 256, 0, stream>>>(code, codeT, u_w, cnt_u, T_Au, v_w, cnt_v, T_Bv);
    k_prep<<<17728, 256, 0, stream>>>(code, codeT, cnt_u, cnt_v,
                                      idxU, nnzU, rowDeg, idxV, nnzV, colDeg,
                                      u_feat, fuhi, fulo,
                                      v_feat, fvhi, fvlo,
                                      Wu1, wuhi, wulo, Wv1, wvhi, wvlo,
                                      Wu2, w2uhi, w2ulo, Wv2, w2vhi, w2vlo,
                                      P, pthi, ptlo);
    k_gatherE<<<65536, 256, 0, stream>>>(idxU, nnzU, T_Bv, idxV, nnzV, T_Au, pnn);
    k_l1Z<<<13312, 256, 0, stream>>>(fuhi, fulo, fvhi, fvlo, u, v,
                                     wuhi, wulo, wvhi, wvlo, bu1, bv1,
                                     chiU, cloU, chiV, cloV,
                                     pnn, colDeg, rowDeg, code, codeR);
    k_l2F<<<dim3(2, 64, 2), 256, 0, stream>>>(chiU, cloU, w2uhi, w2ulo, uhhi, uhlo,
                                              chiV, cloV, w2vhi, w2vlo, vhb);
    k_tb<<<dim3(2, 64, 2), 256, 0, stream>>>(uhhi, uhlo, pthi, ptlo, tb);
    k_scores3<<<dim3(32, 64), 256, 0, stream>>>(tb, vhb, codeR, a, out, part);
    k_finalize<<<1, 256, 0, stream>>>(part, out);
}